// Round 1
// baseline (955.405 us; speedup 1.0000x reference)
//
#include <hip/hip_runtime.h>
#include <hip/hip_bf16.h>
#include <math.h>

#define FIN 512
#define NHID 32
#define LAT 16

// ---------------------------------------------------------------------------
// GEMM1: [n,512] @ [512,32] -> [n,32].  W in LDS (64KB). Each wave handles one
// row: lanes 0-31 accumulate k=0..255, lanes 32-63 k=256..511, shfl_xor(32)
// combines. Feature row read as broadcast float4 (L1-friendly, read once).
// ---------------------------------------------------------------------------
__global__ __launch_bounds__(256) void gemm_fin(const float* __restrict__ feat,
                                                const float* __restrict__ W,
                                                float* __restrict__ out, int n) {
    __shared__ float wl[FIN * NHID];  // 64 KB
    {
        const float4* w4 = reinterpret_cast<const float4*>(W);
        float4* wl4 = reinterpret_cast<float4*>(wl);
        for (int i = threadIdx.x; i < FIN * NHID / 4; i += 256) wl4[i] = w4[i];
    }
    __syncthreads();
    const int lane = threadIdx.x & 63;
    const int c = lane & 31;
    const int kh = lane >> 5;  // 0 or 1: which k-half
    const int gwave = blockIdx.x * 4 + (threadIdx.x >> 6);
    const int nw = gridDim.x * 4;
    for (int r = gwave; r < n; r += nw) {
        const float* row = feat + (size_t)r * FIN + kh * 256;
        float acc = 0.f;
#pragma unroll 8
        for (int j = 0; j < 256; j += 4) {
            float4 f = *reinterpret_cast<const float4*>(row + j);
            const float* wp = &wl[(kh * 256 + j) * NHID + c];
            acc = fmaf(f.x, wp[0], acc);
            acc = fmaf(f.y, wp[NHID], acc);
            acc = fmaf(f.z, wp[2 * NHID], acc);
            acc = fmaf(f.w, wp[3 * NHID], acc);
        }
        acc += __shfl_xor(acc, 32);
        if (kh == 0) out[(size_t)r * NHID + c] = acc;
    }
}

// ---------------------------------------------------------------------------
// Sparse aggregation (scatter with HW fp32 atomics): out[dst] += s[src]*w.
// Thread = (edge, col). Gather reads are contiguous per edge (64/128B);
// source array is 3.2-6.4MB -> L2/L3 resident.
// ---------------------------------------------------------------------------
template <int D>
__global__ __launch_bounds__(256) void agg_scatter(const float* __restrict__ s,
                                                   const int* __restrict__ src,
                                                   const int* __restrict__ dst,
                                                   const float* __restrict__ w,
                                                   float* __restrict__ out, int e) {
    int idx = blockIdx.x * 256 + threadIdx.x;
    int ei = idx / D;
    int c = idx % D;
    if (ei < e) {
        int se = src[ei];
        float val = s[(size_t)se * D + c] * w[ei];
        unsafeAtomicAdd(&out[(size_t)dst[ei] * D + c], val);
    }
}

// ---------------------------------------------------------------------------
// Elementwise tanh (+ optional residual add)
// ---------------------------------------------------------------------------
template <bool RES>
__global__ __launch_bounds__(256) void ew_tanh(const float* __restrict__ in,
                                               const float* __restrict__ res,
                                               float* __restrict__ out, int n) {
    int i = blockIdx.x * 256 + threadIdx.x;
    if (i < n) {
        float v = tanhf(in[i]);
        if (RES) v += res[i];
        out[i] = v;
    }
}

// ---------------------------------------------------------------------------
// Small GEMM: [n,K] @ [K,C] -> [n,C], K,C in {16,32}. W in LDS.
// Thread = (row, col), 256/C rows per block. Optional tanh + residual.
// ---------------------------------------------------------------------------
template <int K, int C, bool TANH, bool RES>
__global__ __launch_bounds__(256) void gemm_small(const float* __restrict__ in,
                                                  const float* __restrict__ W,
                                                  const float* __restrict__ res,
                                                  float* __restrict__ out, int n) {
    __shared__ float wl[K * C];
    for (int i = threadIdx.x; i < K * C; i += 256) wl[i] = W[i];
    __syncthreads();
    constexpr int ROWS = 256 / C;
    int r = blockIdx.x * ROWS + threadIdx.x / C;
    int c = threadIdx.x % C;
    if (r < n) {
        const float* row = in + (size_t)r * K;
        float acc = 0.f;
#pragma unroll
        for (int k = 0; k < K; ++k) acc = fmaf(row[k], wl[k * C + c], acc);
        if (TANH) acc = tanhf(acc);
        if (RES) acc += res[(size_t)r * C + c];
        out[(size_t)r * C + c] = acc;
    }
}

// ---------------------------------------------------------------------------
// GEMM6: [n,32] @ [32,512] -> sigmoid -> [n,512]. W6 in LDS (64KB).
// Block handles 8 rows; thread computes 2 adjacent cols (float2 LDS reads,
// float2 coalesced stores).
// ---------------------------------------------------------------------------
__global__ __launch_bounds__(256) void gemm_fout(const float* __restrict__ a,
                                                 const float* __restrict__ W,
                                                 float* __restrict__ out, int n) {
    __shared__ float wl[NHID * FIN];  // 64 KB
    __shared__ float ar[8][NHID];
    {
        const float4* w4 = reinterpret_cast<const float4*>(W);
        float4* wl4 = reinterpret_cast<float4*>(wl);
        for (int i = threadIdx.x; i < NHID * FIN / 4; i += 256) wl4[i] = w4[i];
    }
    int r0 = blockIdx.x * 8;
    {
        int rr = threadIdx.x >> 5, cc = threadIdx.x & 31;
        int r = r0 + rr;
        ar[rr][cc] = (r < n) ? a[(size_t)r * NHID + cc] : 0.f;
    }
    __syncthreads();
    int t = threadIdx.x;
    for (int rr = 0; rr < 8; ++rr) {
        int r = r0 + rr;
        if (r >= n) break;
        float accx = 0.f, accy = 0.f;
#pragma unroll
        for (int k = 0; k < NHID; ++k) {
            float av = ar[rr][k];
            float2 wv = *reinterpret_cast<const float2*>(&wl[k * FIN + 2 * t]);
            accx = fmaf(av, wv.x, accx);
            accy = fmaf(av, wv.y, accy);
        }
        float2 o;
        o.x = 1.f / (1.f + expf(-accx));
        o.y = 1.f / (1.f + expf(-accy));
        *reinterpret_cast<float2*>(&out[(size_t)r * FIN + 2 * t]) = o;
    }
}

// ---------------------------------------------------------------------------
// Row softmax over 16 classes, one thread per row.
// ---------------------------------------------------------------------------
__global__ __launch_bounds__(256) void softmax16(const float* __restrict__ z,
                                                 float* __restrict__ out, int n) {
    int r = blockIdx.x * 256 + threadIdx.x;
    if (r >= n) return;
    const float4* zp = reinterpret_cast<const float4*>(z + (size_t)r * 16);
    float4 v[4];
    v[0] = zp[0]; v[1] = zp[1]; v[2] = zp[2]; v[3] = zp[3];
    float* f = reinterpret_cast<float*>(v);
    float m = -1e30f;
#pragma unroll
    for (int i = 0; i < 16; ++i) m = fmaxf(m, f[i]);
    float s = 0.f;
#pragma unroll
    for (int i = 0; i < 16; ++i) { f[i] = expf(f[i] - m); s += f[i]; }
    float inv = 1.f / s;
#pragma unroll
    for (int i = 0; i < 16; ++i) f[i] *= inv;
    float4* op = reinterpret_cast<float4*>(out + (size_t)r * 16);
    op[0] = v[0]; op[1] = v[1]; op[2] = v[2]; op[3] = v[3];
}

extern "C" void kernel_launch(void* const* d_in, const int* in_sizes, int n_in,
                              void* d_out, int out_size, void* d_ws, size_t ws_size,
                              hipStream_t stream) {
    const float* feat = (const float*)d_in[0];
    const int* esrc = (const int*)d_in[1];
    const int* edst = (const int*)d_in[2];
    const float* ewt = (const float*)d_in[3];
    const float* W1 = (const float*)d_in[4];
    const float* W2 = (const float*)d_in[5];
    const float* W3 = (const float*)d_in[6];
    const float* W4 = (const float*)d_in[7];
    const float* W5 = (const float*)d_in[8];
    const float* W6 = (const float*)d_in[9];
    const int n = in_sizes[0] / FIN;
    const int e = in_sizes[1];

    float* out = (float*)d_out;
    float* recon = out;                          // [n,512]
    float* zout = out + (size_t)n * FIN;         // [n,16]
    float* pred = zout + (size_t)n * 16;         // [n,16]

    // Workspace layout (floats): aggregation buffers (zeroed) then scratch.
    float* ws = (float*)d_ws;
    float* A1 = ws;                       // n*32
    float* A2 = A1 + (size_t)n * 32;      // n*16
    float* A3 = A2 + (size_t)n * 16;      // n*16
    float* A4 = A3 + (size_t)n * 16;      // n*16
    float* A5 = A4 + (size_t)n * 16;      // n*16
    float* A6 = A5 + (size_t)n * 16;      // n*32
    float* S  = A6 + (size_t)n * 32;      // n*32 scratch (gemm outputs, z2)
    float* X1 = S + (size_t)n * 32;       // n*32 (residual for z1)
    float* X2 = X1 + (size_t)n * 32;      // n*16 (residual for z2)

    // Zero all aggregation buffers (n*128 floats) once per launch.
    hipMemsetAsync(ws, 0, (size_t)n * 128 * sizeof(float), stream);

    const int g16 = (n * 16 + 255) / 256;
    const int g32 = (n * 32 + 255) / 256;
    const int ge16 = (e * 16 + 255) / 256;
    const int ge32 = (e * 32 + 255) / 256;

    // conv1: s1 = feat@W1 ; x1 = tanh(Â s1)
    gemm_fin<<<2048, 256, 0, stream>>>(feat, W1, S, n);
    agg_scatter<32><<<ge32, 256, 0, stream>>>(S, esrc, edst, ewt, A1, e);
    ew_tanh<false><<<g32, 256, 0, stream>>>(A1, nullptr, X1, n * 32);
    // conv2: x2 = tanh(Â (x1@W2))
    gemm_small<32, 16, false, false><<<(n + 15) / 16, 256, 0, stream>>>(X1, W2, nullptr, S, n);
    agg_scatter<16><<<ge16, 256, 0, stream>>>(S, esrc, edst, ewt, A2, e);
    ew_tanh<false><<<g16, 256, 0, stream>>>(A2, nullptr, X2, n * 16);
    // conv3: z = tanh(Â (x2@W3))  -> written directly to output slot
    gemm_small<16, 16, false, false><<<(n + 15) / 16, 256, 0, stream>>>(X2, W3, nullptr, S, n);
    agg_scatter<16><<<ge16, 256, 0, stream>>>(S, esrc, edst, ewt, A3, e);
    ew_tanh<false><<<g16, 256, 0, stream>>>(A3, nullptr, zout, n * 16);
    // conv4: z2 = tanh(Â (z@W4)) + x2   (z2 -> S)
    gemm_small<16, 16, false, false><<<(n + 15) / 16, 256, 0, stream>>>(zout, W4, nullptr, S, n);
    agg_scatter<16><<<ge16, 256, 0, stream>>>(S, esrc, edst, ewt, A4, e);
    ew_tanh<true><<<g16, 256, 0, stream>>>(A4, X2, S, n * 16);
    // conv5 (reassociated): z1 = tanh((Â z2)@W5) + x1   (z1 -> A1, free now)
    agg_scatter<16><<<ge16, 256, 0, stream>>>(S, esrc, edst, ewt, A5, e);
    gemm_small<16, 32, true, true><<<(n + 7) / 8, 256, 0, stream>>>(A5, W5, X1, A1, n);
    // conv6 (reassociated): recon = sigmoid((Â z1)@W6)
    agg_scatter<32><<<ge32, 256, 0, stream>>>(A1, esrc, edst, ewt, A6, e);
    gemm_fout<<<(n + 7) / 8, 256, 0, stream>>>(A6, W6, recon, n);
    // pred = softmax(z)
    softmax16<<<(n + 255) / 256, 256, 0, stream>>>(zout, pred, n);
}

// Round 2
// 794.327 us; speedup vs baseline: 1.2028x; 1.2028x over previous
//
#include <hip/hip_runtime.h>
#include <hip/hip_bf16.h>
#include <math.h>

#define FIN 512
#define NHID 32
#define LAT 16

// ---------------------------------------------------------------------------
// GEMM1: [n,512] @ [512,32] -> [n,32].  W in LDS (64KB). Each wave handles one
// row: lanes 0-31 accumulate k=0..255, lanes 32-63 k=256..511, shfl_xor(32)
// combines.
// ---------------------------------------------------------------------------
__global__ __launch_bounds__(256) void gemm_fin(const float* __restrict__ feat,
                                                const float* __restrict__ W,
                                                float* __restrict__ out, int n) {
    __shared__ float wl[FIN * NHID];  // 64 KB
    {
        const float4* w4 = reinterpret_cast<const float4*>(W);
        float4* wl4 = reinterpret_cast<float4*>(wl);
        for (int i = threadIdx.x; i < FIN * NHID / 4; i += 256) wl4[i] = w4[i];
    }
    __syncthreads();
    const int lane = threadIdx.x & 63;
    const int c = lane & 31;
    const int kh = lane >> 5;
    const int gwave = blockIdx.x * 4 + (threadIdx.x >> 6);
    const int nw = gridDim.x * 4;
    for (int r = gwave; r < n; r += nw) {
        const float* row = feat + (size_t)r * FIN + kh * 256;
        float acc = 0.f;
#pragma unroll 8
        for (int j = 0; j < 256; j += 4) {
            float4 f = *reinterpret_cast<const float4*>(row + j);
            const float* wp = &wl[(kh * 256 + j) * NHID + c];
            acc = fmaf(f.x, wp[0], acc);
            acc = fmaf(f.y, wp[NHID], acc);
            acc = fmaf(f.z, wp[2 * NHID], acc);
            acc = fmaf(f.w, wp[3 * NHID], acc);
        }
        acc += __shfl_xor(acc, 32);
        if (kh == 0) out[(size_t)r * NHID + c] = acc;
    }
}

// ---------------------------------------------------------------------------
// CSR build: histogram -> scan -> edge scatter into (src,w) 8B records.
// ---------------------------------------------------------------------------
__global__ __launch_bounds__(256) void hist_deg(const int* __restrict__ dst,
                                                int* __restrict__ deg, int e) {
    int i = blockIdx.x * 256 + threadIdx.x;
    if (i < e) atomicAdd(&deg[dst[i]], 1);
}

__global__ __launch_bounds__(1024) void scan_rowptr(const int* __restrict__ deg,
                                                    int* __restrict__ rowptr,
                                                    int* __restrict__ cursor, int n) {
    __shared__ int part[1024];
    const int t = threadIdx.x;
    const int C = (n + 1023) / 1024;
    const int lo = t * C;
    const int hi = min(lo + C, n);
    int s = 0;
    for (int i = lo; i < hi; ++i) s += deg[i];
    part[t] = s;
    __syncthreads();
    for (int off = 1; off < 1024; off <<= 1) {
        int v = (t >= off) ? part[t - off] : 0;
        __syncthreads();
        part[t] += v;
        __syncthreads();
    }
    int run = (t == 0) ? 0 : part[t - 1];
    for (int i = lo; i < hi; ++i) {
        rowptr[i] = run;
        cursor[i] = run;
        run += deg[i];
    }
    if (t == 1023) rowptr[n] = part[1023];
}

__global__ __launch_bounds__(256) void build_rec(const int* __restrict__ src,
                                                 const int* __restrict__ dst,
                                                 const float* __restrict__ w,
                                                 int* __restrict__ cursor,
                                                 unsigned long long* __restrict__ rec,
                                                 int e) {
    int i = blockIdx.x * 256 + threadIdx.x;
    if (i < e) {
        int pos = atomicAdd(&cursor[dst[i]], 1);
        unsigned long long r =
            ((unsigned long long)__float_as_uint(w[i]) << 32) | (unsigned)src[i];
        rec[pos] = r;
    }
}

// ---------------------------------------------------------------------------
// CSR aggregation: D lanes per dst node. Edge record loads are uniform across
// the lane group (HW broadcast); gathers are contiguous D*4B lines, L2/L3
// resident. Fused epilogue: tanh / residual / 16-wide softmax (conv3).
// ---------------------------------------------------------------------------
template <int D, bool TANH, bool RES, bool SMAX>
__global__ __launch_bounds__(256) void agg_csr(const float* __restrict__ s,
                                               const unsigned long long* __restrict__ rec,
                                               const int* __restrict__ rowptr,
                                               const float* __restrict__ res,
                                               float* __restrict__ out,
                                               float* __restrict__ pred, int n) {
    constexpr int NPB = 256 / D;
    int node = blockIdx.x * NPB + threadIdx.x / D;
    int c = threadIdx.x % D;
    if (node >= n) return;
    int i = rowptr[node];
    const int end = rowptr[node + 1];
    float acc = 0.f;
    for (; i + 1 < end; i += 2) {  // 2-way unroll: two gathers in flight
        unsigned long long r0 = rec[i];
        unsigned long long r1 = rec[i + 1];
        int s0 = (int)(r0 & 0xffffffffu);
        int s1 = (int)(r1 & 0xffffffffu);
        float w0 = __uint_as_float((unsigned)(r0 >> 32));
        float w1 = __uint_as_float((unsigned)(r1 >> 32));
        float v0 = s[(size_t)s0 * D + c];
        float v1 = s[(size_t)s1 * D + c];
        acc = fmaf(v0, w0, acc);
        acc = fmaf(v1, w1, acc);
    }
    if (i < end) {
        unsigned long long r0 = rec[i];
        int s0 = (int)(r0 & 0xffffffffu);
        float w0 = __uint_as_float((unsigned)(r0 >> 32));
        acc = fmaf(s[(size_t)s0 * D + c], w0, acc);
    }
    float v = TANH ? tanhf(acc) : acc;
    if (RES) v += res[(size_t)node * D + c];
    out[(size_t)node * D + c] = v;
    if (SMAX) {  // 16-wide group softmax on v (D==16)
        float m = v;
#pragma unroll
        for (int mk = 8; mk >= 1; mk >>= 1) m = fmaxf(m, __shfl_xor(m, mk, 16));
        float ev = expf(v - m);
        float sum = ev;
#pragma unroll
        for (int mk = 8; mk >= 1; mk >>= 1) sum += __shfl_xor(sum, mk, 16);
        pred[(size_t)node * D + c] = ev / sum;
    }
}

// ---------------------------------------------------------------------------
// Small GEMM: [n,K] @ [K,C] -> [n,C]. W in LDS. Optional tanh + residual.
// ---------------------------------------------------------------------------
template <int K, int C, bool TANH, bool RES>
__global__ __launch_bounds__(256) void gemm_small(const float* __restrict__ in,
                                                  const float* __restrict__ W,
                                                  const float* __restrict__ res,
                                                  float* __restrict__ out, int n) {
    __shared__ float wl[K * C];
    for (int i = threadIdx.x; i < K * C; i += 256) wl[i] = W[i];
    __syncthreads();
    constexpr int ROWS = 256 / C;
    int r = blockIdx.x * ROWS + threadIdx.x / C;
    int c = threadIdx.x % C;
    if (r < n) {
        const float* row = in + (size_t)r * K;
        float acc = 0.f;
#pragma unroll
        for (int k = 0; k < K; ++k) acc = fmaf(row[k], wl[k * C + c], acc);
        if (TANH) acc = tanhf(acc);
        if (RES) acc += res[(size_t)r * C + c];
        out[(size_t)r * C + c] = acc;
    }
}

// ---------------------------------------------------------------------------
// GEMM6: [n,32] @ [32,512] -> sigmoid -> [n,512]. W6 in LDS (64KB).
// ---------------------------------------------------------------------------
__global__ __launch_bounds__(256) void gemm_fout(const float* __restrict__ a,
                                                 const float* __restrict__ W,
                                                 float* __restrict__ out, int n) {
    __shared__ float wl[NHID * FIN];  // 64 KB
    __shared__ float ar[8][NHID];
    {
        const float4* w4 = reinterpret_cast<const float4*>(W);
        float4* wl4 = reinterpret_cast<float4*>(wl);
        for (int i = threadIdx.x; i < NHID * FIN / 4; i += 256) wl4[i] = w4[i];
    }
    int r0 = blockIdx.x * 8;
    {
        int rr = threadIdx.x >> 5, cc = threadIdx.x & 31;
        int r = r0 + rr;
        ar[rr][cc] = (r < n) ? a[(size_t)r * NHID + cc] : 0.f;
    }
    __syncthreads();
    int t = threadIdx.x;
    for (int rr = 0; rr < 8; ++rr) {
        int r = r0 + rr;
        if (r >= n) break;
        float accx = 0.f, accy = 0.f;
#pragma unroll
        for (int k = 0; k < NHID; ++k) {
            float av = ar[rr][k];
            float2 wv = *reinterpret_cast<const float2*>(&wl[k * FIN + 2 * t]);
            accx = fmaf(av, wv.x, accx);
            accy = fmaf(av, wv.y, accy);
        }
        float2 o;
        o.x = 1.f / (1.f + expf(-accx));
        o.y = 1.f / (1.f + expf(-accy));
        *reinterpret_cast<float2*>(&out[(size_t)r * FIN + 2 * t]) = o;
    }
}

extern "C" void kernel_launch(void* const* d_in, const int* in_sizes, int n_in,
                              void* d_out, int out_size, void* d_ws, size_t ws_size,
                              hipStream_t stream) {
    const float* feat = (const float*)d_in[0];
    const int* esrc = (const int*)d_in[1];
    const int* edst = (const int*)d_in[2];
    const float* ewt = (const float*)d_in[3];
    const float* W1 = (const float*)d_in[4];
    const float* W2 = (const float*)d_in[5];
    const float* W3 = (const float*)d_in[6];
    const float* W4 = (const float*)d_in[7];
    const float* W5 = (const float*)d_in[8];
    const float* W6 = (const float*)d_in[9];
    const int n = in_sizes[0] / FIN;
    const int e = in_sizes[1];

    float* out = (float*)d_out;
    float* recon = out;                   // [n,512]
    float* zout = out + (size_t)n * FIN;  // [n,16]
    float* pred = zout + (size_t)n * 16;  // [n,16]

    // Workspace layout: rec (8B aligned, first) | int ptrs | float buffers.
    char* wsb = (char*)d_ws;
    unsigned long long* rec = (unsigned long long*)wsb;          // e * 8B
    int* deg = (int*)(wsb + (size_t)e * 8);                      // n
    int* rowptr = deg + n;                                       // n+1
    int* cursor = rowptr + n + 1;                                // n
    float* P0 = (float*)(cursor + n);                            // n*32 (gemm out / reuse)
    float* P1 = P0 + (size_t)n * 32;                             // n*32 (x1)
    float* P2 = P1 + (size_t)n * 32;                             // n*16 (x2)
    float* P3 = P2 + (size_t)n * 16;                             // n*16 (z2)
    float* P4 = P3 + (size_t)n * 16;                             // n*32 (z1)

    const int ge = (e + 255) / 256;
    const int gn32 = (n + 7) / 8;    // agg D=32: 8 nodes/block
    const int gn16 = (n + 15) / 16;  // agg D=16: 16 nodes/block

    // ---- CSR build (reused by all 6 aggregations) ----
    hipMemsetAsync(deg, 0, (size_t)n * sizeof(int), stream);
    hist_deg<<<ge, 256, 0, stream>>>(edst, deg, e);
    scan_rowptr<<<1, 1024, 0, stream>>>(deg, rowptr, cursor, n);
    build_rec<<<ge, 256, 0, stream>>>(esrc, edst, ewt, cursor, rec, e);

    // conv1: x1 = tanh(A (feat@W1))
    gemm_fin<<<2048, 256, 0, stream>>>(feat, W1, P0, n);
    agg_csr<32, true, false, false><<<gn32, 256, 0, stream>>>(P0, rec, rowptr, nullptr, P1, nullptr, n);
    // conv2: x2 = tanh(A (x1@W2))
    gemm_small<32, 16, false, false><<<gn16, 256, 0, stream>>>(P1, W2, nullptr, P0, n);
    agg_csr<16, true, false, false><<<gn16, 256, 0, stream>>>(P0, rec, rowptr, nullptr, P2, nullptr, n);
    // conv3: z = tanh(A (x2@W3)); pred = softmax(z)  [fused]
    gemm_small<16, 16, false, false><<<gn16, 256, 0, stream>>>(P2, W3, nullptr, P0, n);
    agg_csr<16, true, false, true><<<gn16, 256, 0, stream>>>(P0, rec, rowptr, nullptr, zout, pred, n);
    // conv4: z2 = tanh(A (z@W4)) + x2
    gemm_small<16, 16, false, false><<<gn16, 256, 0, stream>>>(zout, W4, nullptr, P0, n);
    agg_csr<16, true, true, false><<<gn16, 256, 0, stream>>>(P0, rec, rowptr, P2, P3, nullptr, n);
    // conv5 (reassociated): z1 = tanh((A z2)@W5) + x1
    agg_csr<16, false, false, false><<<gn16, 256, 0, stream>>>(P3, rec, rowptr, nullptr, P0, nullptr, n);
    gemm_small<16, 32, true, true><<<gn32, 256, 0, stream>>>(P0, W5, P1, P4, n);
    // conv6 (reassociated): recon = sigmoid((A z1)@W6)
    agg_csr<32, false, false, false><<<gn32, 256, 0, stream>>>(P4, rec, rowptr, nullptr, P0, nullptr, n);
    gemm_fout<<<gn32, 256, 0, stream>>>(P0, W6, recon, n);
}

// Round 3
// 728.229 us; speedup vs baseline: 1.3120x; 1.0908x over previous
//
#include <hip/hip_runtime.h>
#include <hip/hip_bf16.h>
#include <math.h>

#define FIN 512
#define NHID 32
#define LAT 16

// ---------------------------------------------------------------------------
// GEMM1: [n,512] @ [512,32] -> [n,32]. Register-blocked LDS GEMM.
// Block: 128 rows x 32 cols, K-chunks of 64. 256 threads, 4x4 reg tiles.
// x staged TRANSPOSED xT[k][row] (pad 132 -> all-32-bank b128 reads);
// W chunk [64][32] (8 float4 groups cover banks 0..31 once: conflict-free).
// ---------------------------------------------------------------------------
#define BR 128
#define KC 64
__global__ __launch_bounds__(256) void gemm_fin(const float* __restrict__ feat,
                                                const float* __restrict__ W,
                                                float* __restrict__ out, int n) {
    __shared__ float xT[KC][BR + 4];  // 64 x 132 floats = 33.8 KB
    __shared__ float Wc[KC][NHID];    // 8 KB
    const int tid = threadIdx.x;
    const int r0 = blockIdx.x * BR;
    const int rt = tid >> 3;  // 0..31 row-tile (4 rows each)
    const int ct = tid & 7;   // 0..7  col-tile (4 cols each)
    const int srow = tid >> 4;  // 0..15 staging row
    const int sc4 = tid & 15;   // 0..15 staging k-float4
    float acc[4][4] = {{0.f}};

    for (int kc = 0; kc < FIN; kc += KC) {
        // stage W chunk: 2048 floats = 512 float4, 2 per thread
        {
            const float4* wg = reinterpret_cast<const float4*>(W + kc * NHID);
            float4* wl = reinterpret_cast<float4*>(&Wc[0][0]);
            wl[tid] = wg[tid];
            wl[tid + 256] = wg[tid + 256];
        }
        // stage x transposed: rows r0+srow+16i, k = kc+sc4*4..+3
#pragma unroll
        for (int i = 0; i < 8; ++i) {
            int rr = srow + 16 * i;
            int r = r0 + rr;
            float4 v;
            if (r < n)
                v = *reinterpret_cast<const float4*>(feat + (size_t)r * FIN + kc + sc4 * 4);
            else
                v.x = v.y = v.z = v.w = 0.f;
            xT[sc4 * 4 + 0][rr] = v.x;
            xT[sc4 * 4 + 1][rr] = v.y;
            xT[sc4 * 4 + 2][rr] = v.z;
            xT[sc4 * 4 + 3][rr] = v.w;
        }
        __syncthreads();
#pragma unroll 4
        for (int k = 0; k < KC; ++k) {
            float4 xv = *reinterpret_cast<const float4*>(&xT[k][rt * 4]);
            float4 wv = *reinterpret_cast<const float4*>(&Wc[k][ct * 4]);
            acc[0][0] = fmaf(xv.x, wv.x, acc[0][0]);
            acc[0][1] = fmaf(xv.x, wv.y, acc[0][1]);
            acc[0][2] = fmaf(xv.x, wv.z, acc[0][2]);
            acc[0][3] = fmaf(xv.x, wv.w, acc[0][3]);
            acc[1][0] = fmaf(xv.y, wv.x, acc[1][0]);
            acc[1][1] = fmaf(xv.y, wv.y, acc[1][1]);
            acc[1][2] = fmaf(xv.y, wv.z, acc[1][2]);
            acc[1][3] = fmaf(xv.y, wv.w, acc[1][3]);
            acc[2][0] = fmaf(xv.z, wv.x, acc[2][0]);
            acc[2][1] = fmaf(xv.z, wv.y, acc[2][1]);
            acc[2][2] = fmaf(xv.z, wv.z, acc[2][2]);
            acc[2][3] = fmaf(xv.z, wv.w, acc[2][3]);
            acc[3][0] = fmaf(xv.w, wv.x, acc[3][0]);
            acc[3][1] = fmaf(xv.w, wv.y, acc[3][1]);
            acc[3][2] = fmaf(xv.w, wv.z, acc[3][2]);
            acc[3][3] = fmaf(xv.w, wv.w, acc[3][3]);
        }
        __syncthreads();
    }
#pragma unroll
    for (int i = 0; i < 4; ++i) {
        int r = r0 + rt * 4 + i;
        if (r < n) {
            float4 o;
            o.x = acc[i][0]; o.y = acc[i][1]; o.z = acc[i][2]; o.w = acc[i][3];
            *reinterpret_cast<float4*>(out + (size_t)r * NHID + ct * 4) = o;
        }
    }
}

// ---------------------------------------------------------------------------
// CSR build: histogram -> scan -> edge scatter into (src,w) 8B records.
// ---------------------------------------------------------------------------
__global__ __launch_bounds__(256) void hist_deg(const int* __restrict__ dst,
                                                int* __restrict__ deg, int e) {
    int i = blockIdx.x * 256 + threadIdx.x;
    if (i < e) atomicAdd(&deg[dst[i]], 1);
}

__global__ __launch_bounds__(1024) void scan_rowptr(const int* __restrict__ deg,
                                                    int* __restrict__ rowptr,
                                                    int* __restrict__ cursor, int n) {
    __shared__ int part[1024];
    const int t = threadIdx.x;
    const int C = (n + 1023) / 1024;
    const int lo = t * C;
    const int hi = min(lo + C, n);
    int s = 0;
    for (int i = lo; i < hi; ++i) s += deg[i];
    part[t] = s;
    __syncthreads();
    for (int off = 1; off < 1024; off <<= 1) {
        int v = (t >= off) ? part[t - off] : 0;
        __syncthreads();
        part[t] += v;
        __syncthreads();
    }
    int run = (t == 0) ? 0 : part[t - 1];
    for (int i = lo; i < hi; ++i) {
        rowptr[i] = run;
        cursor[i] = run;
        run += deg[i];
    }
    if (t == 1023) rowptr[n] = part[1023];
}

__global__ __launch_bounds__(256) void build_rec(const int* __restrict__ src,
                                                 const int* __restrict__ dst,
                                                 const float* __restrict__ w,
                                                 int* __restrict__ cursor,
                                                 unsigned long long* __restrict__ rec,
                                                 int e) {
    int i = blockIdx.x * 256 + threadIdx.x;
    if (i < e) {
        int pos = atomicAdd(&cursor[dst[i]], 1);
        unsigned long long r =
            ((unsigned long long)__float_as_uint(w[i]) << 32) | (unsigned)src[i];
        rec[pos] = r;
    }
}

// ---------------------------------------------------------------------------
// CSR aggregation: D lanes per dst node; fused tanh / residual / softmax.
// ---------------------------------------------------------------------------
template <int D, bool TANH, bool RES, bool SMAX>
__global__ __launch_bounds__(256) void agg_csr(const float* __restrict__ s,
                                               const unsigned long long* __restrict__ rec,
                                               const int* __restrict__ rowptr,
                                               const float* __restrict__ res,
                                               float* __restrict__ out,
                                               float* __restrict__ pred, int n) {
    constexpr int NPB = 256 / D;
    int node = blockIdx.x * NPB + threadIdx.x / D;
    int c = threadIdx.x % D;
    if (node >= n) return;
    int i = rowptr[node];
    const int end = rowptr[node + 1];
    float acc = 0.f;
    for (; i + 1 < end; i += 2) {
        unsigned long long r0 = rec[i];
        unsigned long long r1 = rec[i + 1];
        int s0 = (int)(r0 & 0xffffffffu);
        int s1 = (int)(r1 & 0xffffffffu);
        float w0 = __uint_as_float((unsigned)(r0 >> 32));
        float w1 = __uint_as_float((unsigned)(r1 >> 32));
        float v0 = s[(size_t)s0 * D + c];
        float v1 = s[(size_t)s1 * D + c];
        acc = fmaf(v0, w0, acc);
        acc = fmaf(v1, w1, acc);
    }
    if (i < end) {
        unsigned long long r0 = rec[i];
        int s0 = (int)(r0 & 0xffffffffu);
        float w0 = __uint_as_float((unsigned)(r0 >> 32));
        acc = fmaf(s[(size_t)s0 * D + c], w0, acc);
    }
    float v = TANH ? tanhf(acc) : acc;
    if (RES) v += res[(size_t)node * D + c];
    out[(size_t)node * D + c] = v;
    if (SMAX) {
        float m = v;
#pragma unroll
        for (int mk = 8; mk >= 1; mk >>= 1) m = fmaxf(m, __shfl_xor(m, mk, 16));
        float ev = expf(v - m);
        float sum = ev;
#pragma unroll
        for (int mk = 8; mk >= 1; mk >>= 1) sum += __shfl_xor(sum, mk, 16);
        pred[(size_t)node * D + c] = ev / sum;
    }
}

// ---------------------------------------------------------------------------
// Small GEMM: [n,K] @ [K,C] -> [n,C]. W in LDS. Optional tanh + residual.
// ---------------------------------------------------------------------------
template <int K, int C, bool TANH, bool RES>
__global__ __launch_bounds__(256) void gemm_small(const float* __restrict__ in,
                                                  const float* __restrict__ W,
                                                  const float* __restrict__ res,
                                                  float* __restrict__ out, int n) {
    __shared__ float wl[K * C];
    for (int i = threadIdx.x; i < K * C; i += 256) wl[i] = W[i];
    __syncthreads();
    constexpr int ROWS = 256 / C;
    int r = blockIdx.x * ROWS + threadIdx.x / C;
    int c = threadIdx.x % C;
    if (r < n) {
        const float* row = in + (size_t)r * K;
        float acc = 0.f;
#pragma unroll
        for (int k = 0; k < K; ++k) acc = fmaf(row[k], wl[k * C + c], acc);
        if (TANH) acc = tanhf(acc);
        if (RES) acc += res[(size_t)r * C + c];
        out[(size_t)r * C + c] = acc;
    }
}

// ---------------------------------------------------------------------------
// GEMM6: [n,32] @ [32,512] -> sigmoid -> [n,512]. W6 in LDS (64KB).
// ---------------------------------------------------------------------------
__global__ __launch_bounds__(256) void gemm_fout(const float* __restrict__ a,
                                                 const float* __restrict__ W,
                                                 float* __restrict__ out, int n) {
    __shared__ float wl[NHID * FIN];  // 64 KB
    __shared__ float ar[8][NHID];
    {
        const float4* w4 = reinterpret_cast<const float4*>(W);
        float4* wl4 = reinterpret_cast<float4*>(wl);
        for (int i = threadIdx.x; i < NHID * FIN / 4; i += 256) wl4[i] = w4[i];
    }
    int r0 = blockIdx.x * 8;
    {
        int rr = threadIdx.x >> 5, cc = threadIdx.x & 31;
        int r = r0 + rr;
        ar[rr][cc] = (r < n) ? a[(size_t)r * NHID + cc] : 0.f;
    }
    __syncthreads();
    int t = threadIdx.x;
    for (int rr = 0; rr < 8; ++rr) {
        int r = r0 + rr;
        if (r >= n) break;
        float accx = 0.f, accy = 0.f;
#pragma unroll
        for (int k = 0; k < NHID; ++k) {
            float av = ar[rr][k];
            float2 wv = *reinterpret_cast<const float2*>(&wl[k * FIN + 2 * t]);
            accx = fmaf(av, wv.x, accx);
            accy = fmaf(av, wv.y, accy);
        }
        float2 o;
        o.x = 1.f / (1.f + expf(-accx));
        o.y = 1.f / (1.f + expf(-accy));
        *reinterpret_cast<float2*>(&out[(size_t)r * FIN + 2 * t]) = o;
    }
}

extern "C" void kernel_launch(void* const* d_in, const int* in_sizes, int n_in,
                              void* d_out, int out_size, void* d_ws, size_t ws_size,
                              hipStream_t stream) {
    const float* feat = (const float*)d_in[0];
    const int* esrc = (const int*)d_in[1];
    const int* edst = (const int*)d_in[2];
    const float* ewt = (const float*)d_in[3];
    const float* W1 = (const float*)d_in[4];
    const float* W2 = (const float*)d_in[5];
    const float* W3 = (const float*)d_in[6];
    const float* W4 = (const float*)d_in[7];
    const float* W5 = (const float*)d_in[8];
    const float* W6 = (const float*)d_in[9];
    const int n = in_sizes[0] / FIN;
    const int e = in_sizes[1];

    float* out = (float*)d_out;
    float* recon = out;                   // [n,512]
    float* zout = out + (size_t)n * FIN;  // [n,16]
    float* pred = zout + (size_t)n * 16;  // [n,16]

    // Workspace layout: rec (8B aligned, first) | int ptrs | float buffers.
    char* wsb = (char*)d_ws;
    unsigned long long* rec = (unsigned long long*)wsb;  // e * 8B
    int* deg = (int*)(wsb + (size_t)e * 8);              // n
    int* rowptr = deg + n;                               // n+1
    int* cursor = rowptr + n + 1;                        // n
    float* P0 = (float*)(cursor + n);                    // n*32
    float* P1 = P0 + (size_t)n * 32;                     // n*32 (x1)
    float* P2 = P1 + (size_t)n * 32;                     // n*16 (x2)
    float* P3 = P2 + (size_t)n * 16;                     // n*16 (z2)
    float* P4 = P3 + (size_t)n * 16;                     // n*32 (z1)

    const int ge = (e + 255) / 256;
    const int gn32 = (n + 7) / 8;
    const int gn16 = (n + 15) / 16;

    // ---- CSR build (reused by all 6 aggregations) ----
    hipMemsetAsync(deg, 0, (size_t)n * sizeof(int), stream);
    hist_deg<<<ge, 256, 0, stream>>>(edst, deg, e);
    scan_rowptr<<<1, 1024, 0, stream>>>(deg, rowptr, cursor, n);
    build_rec<<<ge, 256, 0, stream>>>(esrc, edst, ewt, cursor, rec, e);

    // conv1: x1 = tanh(A (feat@W1))
    gemm_fin<<<(n + BR - 1) / BR, 256, 0, stream>>>(feat, W1, P0, n);
    agg_csr<32, true, false, false><<<gn32, 256, 0, stream>>>(P0, rec, rowptr, nullptr, P1, nullptr, n);
    // conv2: x2 = tanh(A (x1@W2))
    gemm_small<32, 16, false, false><<<gn16, 256, 0, stream>>>(P1, W2, nullptr, P0, n);
    agg_csr<16, true, false, false><<<gn16, 256, 0, stream>>>(P0, rec, rowptr, nullptr, P2, nullptr, n);
    // conv3: z = tanh(A (x2@W3)); pred = softmax(z)  [fused]
    gemm_small<16, 16, false, false><<<gn16, 256, 0, stream>>>(P2, W3, nullptr, P0, n);
    agg_csr<16, true, false, true><<<gn16, 256, 0, stream>>>(P0, rec, rowptr, nullptr, zout, pred, n);
    // conv4: z2 = tanh(A (z@W4)) + x2
    gemm_small<16, 16, false, false><<<gn16, 256, 0, stream>>>(zout, W4, nullptr, P0, n);
    agg_csr<16, true, true, false><<<gn16, 256, 0, stream>>>(P0, rec, rowptr, P2, P3, nullptr, n);
    // conv5 (reassociated): z1 = tanh((A z2)@W5) + x1
    agg_csr<16, false, false, false><<<gn16, 256, 0, stream>>>(P3, rec, rowptr, nullptr, P0, nullptr, n);
    gemm_small<16, 32, true, true><<<gn32, 256, 0, stream>>>(P0, W5, P1, P4, n);
    // conv6 (reassociated): recon = sigmoid((A z1)@W6)
    agg_csr<32, false, false, false><<<gn32, 256, 0, stream>>>(P4, rec, rowptr, nullptr, P0, nullptr, n);
    gemm_fout<<<gn32, 256, 0, stream>>>(P0, W6, recon, n);
}

// Round 4
// 695.543 us; speedup vs baseline: 1.3736x; 1.0470x over previous
//
#include <hip/hip_runtime.h>
#include <hip/hip_bf16.h>
#include <math.h>

#define FIN 512
#define NHID 32
#define LAT 16

// ---------------------------------------------------------------------------
// GEMM1: [n,512] @ [512,32] -> [n,32]. Register-blocked LDS GEMM (unchanged).
// ---------------------------------------------------------------------------
#define BR 128
#define KC 64
__global__ __launch_bounds__(256) void gemm_fin(const float* __restrict__ feat,
                                                const float* __restrict__ W,
                                                float* __restrict__ out, int n) {
    __shared__ float xT[KC][BR + 4];
    __shared__ float Wc[KC][NHID];
    const int tid = threadIdx.x;
    const int r0 = blockIdx.x * BR;
    const int rt = tid >> 3;
    const int ct = tid & 7;
    const int srow = tid >> 4;
    const int sc4 = tid & 15;
    float acc[4][4] = {{0.f}};

    for (int kc = 0; kc < FIN; kc += KC) {
        {
            const float4* wg = reinterpret_cast<const float4*>(W + kc * NHID);
            float4* wl = reinterpret_cast<float4*>(&Wc[0][0]);
            wl[tid] = wg[tid];
            wl[tid + 256] = wg[tid + 256];
        }
#pragma unroll
        for (int i = 0; i < 8; ++i) {
            int rr = srow + 16 * i;
            int r = r0 + rr;
            float4 v;
            if (r < n)
                v = *reinterpret_cast<const float4*>(feat + (size_t)r * FIN + kc + sc4 * 4);
            else
                v.x = v.y = v.z = v.w = 0.f;
            xT[sc4 * 4 + 0][rr] = v.x;
            xT[sc4 * 4 + 1][rr] = v.y;
            xT[sc4 * 4 + 2][rr] = v.z;
            xT[sc4 * 4 + 3][rr] = v.w;
        }
        __syncthreads();
#pragma unroll 4
        for (int k = 0; k < KC; ++k) {
            float4 xv = *reinterpret_cast<const float4*>(&xT[k][rt * 4]);
            float4 wv = *reinterpret_cast<const float4*>(&Wc[k][ct * 4]);
            acc[0][0] = fmaf(xv.x, wv.x, acc[0][0]);
            acc[0][1] = fmaf(xv.x, wv.y, acc[0][1]);
            acc[0][2] = fmaf(xv.x, wv.z, acc[0][2]);
            acc[0][3] = fmaf(xv.x, wv.w, acc[0][3]);
            acc[1][0] = fmaf(xv.y, wv.x, acc[1][0]);
            acc[1][1] = fmaf(xv.y, wv.y, acc[1][1]);
            acc[1][2] = fmaf(xv.y, wv.z, acc[1][2]);
            acc[1][3] = fmaf(xv.y, wv.w, acc[1][3]);
            acc[2][0] = fmaf(xv.z, wv.x, acc[2][0]);
            acc[2][1] = fmaf(xv.z, wv.y, acc[2][1]);
            acc[2][2] = fmaf(xv.z, wv.z, acc[2][2]);
            acc[2][3] = fmaf(xv.z, wv.w, acc[2][3]);
            acc[3][0] = fmaf(xv.w, wv.x, acc[3][0]);
            acc[3][1] = fmaf(xv.w, wv.y, acc[3][1]);
            acc[3][2] = fmaf(xv.w, wv.z, acc[3][2]);
            acc[3][3] = fmaf(xv.w, wv.w, acc[3][3]);
        }
        __syncthreads();
    }
#pragma unroll
    for (int i = 0; i < 4; ++i) {
        int r = r0 + rt * 4 + i;
        if (r < n) {
            float4 o;
            o.x = acc[i][0]; o.y = acc[i][1]; o.z = acc[i][2]; o.w = acc[i][3];
            *reinterpret_cast<float4*>(out + (size_t)r * NHID + ct * 4) = o;
        }
    }
}

// ---------------------------------------------------------------------------
// CSR build, stage 1: per-node degree histogram (counters spread over 200KB).
// ---------------------------------------------------------------------------
__global__ __launch_bounds__(256) void hist_deg(const int* __restrict__ dst,
                                                int* __restrict__ deg, int e) {
    int i = blockIdx.x * 256 + threadIdx.x;
    if (i < e) atomicAdd(&deg[dst[i]], 1);
}

// ---------------------------------------------------------------------------
// Parallel 3-phase exclusive scan of deg -> rowptr (+ cursor, bucket cursor).
// ---------------------------------------------------------------------------
__global__ __launch_bounds__(256) void scan_part(const int* __restrict__ deg,
                                                 int* __restrict__ exs,
                                                 int* __restrict__ bsum, int n) {
    __shared__ int sh[256];
    int t = threadIdx.x;
    int i = blockIdx.x * 256 + t;
    int v = (i < n) ? deg[i] : 0;
    sh[t] = v;
    __syncthreads();
    for (int off = 1; off < 256; off <<= 1) {
        int x = (t >= off) ? sh[t - off] : 0;
        __syncthreads();
        sh[t] += x;
        __syncthreads();
    }
    if (i < n) exs[i] = sh[t] - v;
    if (t == 255) bsum[blockIdx.x] = sh[t];
}

__global__ __launch_bounds__(256) void scan_bsum(int* __restrict__ bsum, int nb) {
    __shared__ int sh[256];
    int t = threadIdx.x;
    int v = (t < nb) ? bsum[t] : 0;
    sh[t] = v;
    __syncthreads();
    for (int off = 1; off < 256; off <<= 1) {
        int x = (t >= off) ? sh[t - off] : 0;
        __syncthreads();
        sh[t] += x;
        __syncthreads();
    }
    if (t < nb) bsum[t] = sh[t] - v;  // exclusive, in place
}

__global__ __launch_bounds__(256) void scan_final(const int* __restrict__ exs,
                                                  const int* __restrict__ bsum,
                                                  int* __restrict__ rowptr,
                                                  int* __restrict__ cursor,
                                                  int* __restrict__ bcursor,
                                                  int n, int e) {
    int i = blockIdx.x * 256 + threadIdx.x;
    if (i < n) {
        int r = exs[i] + bsum[i >> 8];
        rowptr[i] = r;
        cursor[i] = r;
        if ((i & 15) == 0) bcursor[i >> 4] = r;  // bucket base = rowptr[16b]
    }
    if (i == 0) rowptr[n] = e;
}

// ---------------------------------------------------------------------------
// CSR build, stage 2: bucketed scatter (bucket = 16 dst nodes). Hot set =
// 3125 cursors + 1 active line/bucket (~200KB) -> L2 merges lines before
// writeback. Record packs (w:32 | dst:16 | src:16)  [n < 65536].
// ---------------------------------------------------------------------------
__global__ __launch_bounds__(256) void build_pass_a(const int* __restrict__ src,
                                                    const int* __restrict__ dst,
                                                    const float* __restrict__ w,
                                                    int* __restrict__ bcursor,
                                                    unsigned long long* __restrict__ rec2,
                                                    int e) {
    int i = blockIdx.x * 256 + threadIdx.x;
    if (i < e) {
        int d = dst[i];
        int pos = atomicAdd(&bcursor[d >> 4], 1);
        unsigned lo = (unsigned)src[i] | ((unsigned)d << 16);
        rec2[pos] = ((unsigned long long)__float_as_uint(w[i]) << 32) | lo;
    }
}

// Stage 3: within-bucket fine scatter to exact CSR slot. Reads sequential;
// each write lands in its bucket's ~4KB CSR region (L2-hot, dense lines).
__global__ __launch_bounds__(256) void build_pass_b(const unsigned long long* __restrict__ rec2,
                                                    int* __restrict__ cursor,
                                                    unsigned long long* __restrict__ rec,
                                                    int e) {
    int i = blockIdx.x * 256 + threadIdx.x;
    if (i < e) {
        unsigned long long r = rec2[i];
        unsigned lo = (unsigned)r;
        int d = (int)(lo >> 16);
        unsigned s = lo & 0xffffu;
        int pos = atomicAdd(&cursor[d], 1);
        rec[pos] = (r & 0xffffffff00000000ull) | s;  // final format: (w | src)
    }
}

// ---------------------------------------------------------------------------
// CSR aggregation with fused epilogues. D lanes per dst node.
// MODE 1: out0 = tanh(acc) [D]; out1 = out0 @ Wn [C]   (+ optional softmax)
// MODE 2: out0 = tanh(acc) + res [D]
// MODE 3: out0 = tanh(accRow @ Wn) + res [C=32, D=16]
// MODE 4: out0 = acc [D]
// ---------------------------------------------------------------------------
template <int D, int C, int MODE, bool SMAX>
__global__ __launch_bounds__(256) void agg_fused(const float* __restrict__ s,
                                                 const unsigned long long* __restrict__ rec,
                                                 const int* __restrict__ rowptr,
                                                 const float* __restrict__ Wn,
                                                 const float* __restrict__ res,
                                                 float* __restrict__ out0,
                                                 float* __restrict__ out1,
                                                 float* __restrict__ pred, int n) {
    __shared__ float wl[(MODE == 1 || MODE == 3) ? D * C : 1];
    if (MODE == 1 || MODE == 3) {
        for (int i = threadIdx.x; i < D * C; i += 256) wl[i] = Wn[i];
        __syncthreads();
    }
    constexpr int NPB = 256 / D;
    const int node = blockIdx.x * NPB + threadIdx.x / D;
    const int c = threadIdx.x % D;
    float acc = 0.f;
    if (node < n) {
        int i = rowptr[node];
        const int end = rowptr[node + 1];
        for (; i + 1 < end; i += 2) {
            unsigned long long r0 = rec[i];
            unsigned long long r1 = rec[i + 1];
            int s0 = (int)(r0 & 0xffffffffu);
            int s1 = (int)(r1 & 0xffffffffu);
            float w0 = __uint_as_float((unsigned)(r0 >> 32));
            float w1 = __uint_as_float((unsigned)(r1 >> 32));
            float v0 = s[(size_t)s0 * D + c];
            float v1 = s[(size_t)s1 * D + c];
            acc = fmaf(v0, w0, acc);
            acc = fmaf(v1, w1, acc);
        }
        if (i < end) {
            unsigned long long r0 = rec[i];
            int s0 = (int)(r0 & 0xffffffffu);
            float w0 = __uint_as_float((unsigned)(r0 >> 32));
            acc = fmaf(s[(size_t)s0 * D + c], w0, acc);
        }
    }
    if (MODE == 1) {
        float v = tanhf(acc);
        if (node < n) out0[(size_t)node * D + c] = v;
        if (SMAX) {
            float m = v;
#pragma unroll
            for (int mk = 8; mk >= 1; mk >>= 1) m = fmaxf(m, __shfl_xor(m, mk, 16));
            float ev = expf(v - m);
            float sum = ev;
#pragma unroll
            for (int mk = 8; mk >= 1; mk >>= 1) sum += __shfl_xor(sum, mk, 16);
            if (node < n) pred[(size_t)node * 16 + c] = ev / sum;
        }
        // next-layer gemm: out1[node][c] = sum_k v_k * Wn[k][c]
        int cc = c & (C - 1);
        float g = 0.f;
#pragma unroll
        for (int k = 0; k < D; ++k) g = fmaf(__shfl(v, k, D), wl[k * C + cc], g);
        if (node < n && c < C) out1[(size_t)node * C + c] = g;
    } else if (MODE == 2) {
        if (node < n) out0[(size_t)node * D + c] = tanhf(acc) + res[(size_t)node * D + c];
    } else if (MODE == 3) {
        float g0 = 0.f, g1 = 0.f;
#pragma unroll
        for (int k = 0; k < 16; ++k) {
            float vk = __shfl(acc, k, 16);
            g0 = fmaf(vk, wl[k * 32 + c], g0);
            g1 = fmaf(vk, wl[k * 32 + c + 16], g1);
        }
        if (node < n) {
            out0[(size_t)node * 32 + c] = tanhf(g0) + res[(size_t)node * 32 + c];
            out0[(size_t)node * 32 + c + 16] = tanhf(g1) + res[(size_t)node * 32 + c + 16];
        }
    } else {  // MODE 4
        if (node < n) out0[(size_t)node * D + c] = acc;
    }
}

// ---------------------------------------------------------------------------
// GEMM6: [n,32] @ [32,512] -> sigmoid -> [n,512]. W6 in LDS (unchanged).
// ---------------------------------------------------------------------------
__global__ __launch_bounds__(256) void gemm_fout(const float* __restrict__ a,
                                                 const float* __restrict__ W,
                                                 float* __restrict__ out, int n) {
    __shared__ float wl[NHID * FIN];
    __shared__ float ar[8][NHID];
    {
        const float4* w4 = reinterpret_cast<const float4*>(W);
        float4* wl4 = reinterpret_cast<float4*>(wl);
        for (int i = threadIdx.x; i < NHID * FIN / 4; i += 256) wl4[i] = w4[i];
    }
    int r0 = blockIdx.x * 8;
    {
        int rr = threadIdx.x >> 5, cc = threadIdx.x & 31;
        int r = r0 + rr;
        ar[rr][cc] = (r < n) ? a[(size_t)r * NHID + cc] : 0.f;
    }
    __syncthreads();
    int t = threadIdx.x;
    for (int rr = 0; rr < 8; ++rr) {
        int r = r0 + rr;
        if (r >= n) break;
        float accx = 0.f, accy = 0.f;
#pragma unroll
        for (int k = 0; k < NHID; ++k) {
            float av = ar[rr][k];
            float2 wv = *reinterpret_cast<const float2*>(&wl[k * FIN + 2 * t]);
            accx = fmaf(av, wv.x, accx);
            accy = fmaf(av, wv.y, accy);
        }
        float2 o;
        o.x = 1.f / (1.f + expf(-accx));
        o.y = 1.f / (1.f + expf(-accy));
        *reinterpret_cast<float2*>(&out[(size_t)r * FIN + 2 * t]) = o;
    }
}

extern "C" void kernel_launch(void* const* d_in, const int* in_sizes, int n_in,
                              void* d_out, int out_size, void* d_ws, size_t ws_size,
                              hipStream_t stream) {
    const float* feat = (const float*)d_in[0];
    const int* esrc = (const int*)d_in[1];
    const int* edst = (const int*)d_in[2];
    const float* ewt = (const float*)d_in[3];
    const float* W1 = (const float*)d_in[4];
    const float* W2 = (const float*)d_in[5];
    const float* W3 = (const float*)d_in[6];
    const float* W4 = (const float*)d_in[7];
    const float* W5 = (const float*)d_in[8];
    const float* W6 = (const float*)d_in[9];
    const int n = in_sizes[0] / FIN;
    const int e = in_sizes[1];
    const int nb16 = (n + 15) / 16;  // buckets of 16 nodes

    float* out = (float*)d_out;
    float* recon = out;                   // [n,512]
    float* zout = out + (size_t)n * FIN;  // [n,16]
    float* pred = zout + (size_t)n * 16;  // [n,16]

    // Workspace: rec | ints | float buffers (rec2 aliases S_a/S_b, used only
    // during build which completes before S_a/S_b are written).
    char* wsb = (char*)d_ws;
    unsigned long long* rec = (unsigned long long*)wsb;  // e * 8B
    int* deg = (int*)(wsb + (size_t)e * 8);              // n
    int* rowptr = deg + n;                               // n+1
    int* cursor = rowptr + n + 1;                        // n
    int* exs = cursor + n;                               // n
    int* bcursor = exs + n;                              // nb16
    int* bsum = bcursor + nb16;                          // 256
    size_t foff = (size_t)(bsum + 256 - (int*)wsb);
    foff = (foff + 3) & ~(size_t)3;  // align to 16B in ints
    float* S_a = (float*)wsb + foff;      // n*32
    float* S_b = S_a + (size_t)n * 32;    // n*32
    float* X1 = S_b + (size_t)n * 32;     // n*32 (x1)
    float* X2 = X1 + (size_t)n * 32;      // n*16 (x2)
    unsigned long long* rec2 = (unsigned long long*)S_a;  // e*8B alias

    const int ge = (e + 255) / 256;
    const int gn = (n + 255) / 256;   // 196
    const int gn32 = (n + 7) / 8;
    const int gn16 = (n + 15) / 16;

    // ---- CSR build ----
    hipMemsetAsync(deg, 0, (size_t)n * sizeof(int), stream);
    hist_deg<<<ge, 256, 0, stream>>>(edst, deg, e);
    scan_part<<<gn, 256, 0, stream>>>(deg, exs, bsum, n);
    scan_bsum<<<1, 256, 0, stream>>>(bsum, gn);
    scan_final<<<gn, 256, 0, stream>>>(exs, bsum, rowptr, cursor, bcursor, n, e);
    build_pass_a<<<ge, 256, 0, stream>>>(esrc, edst, ewt, bcursor, rec2, e);
    build_pass_b<<<ge, 256, 0, stream>>>(rec2, cursor, rec, e);

    // conv1: x1 = tanh(A(feat@W1)) -> X1 ; s2 = x1@W2 -> S_b
    gemm_fin<<<(n + BR - 1) / BR, 256, 0, stream>>>(feat, W1, S_a, n);
    agg_fused<32, 16, 1, false><<<gn32, 256, 0, stream>>>(S_a, rec, rowptr, W2, nullptr, X1, S_b, nullptr, n);
    // conv2: x2 = tanh(A s2) -> X2 ; s3 = x2@W3 -> S_a
    agg_fused<16, 16, 1, false><<<gn16, 256, 0, stream>>>(S_b, rec, rowptr, W3, nullptr, X2, S_a, nullptr, n);
    // conv3: z = tanh(A s3) -> zout ; pred = softmax(z) ; s4 = z@W4 -> S_b
    agg_fused<16, 16, 1, true><<<gn16, 256, 0, stream>>>(S_a, rec, rowptr, W4, nullptr, zout, S_b, pred, n);
    // conv4: z2 = tanh(A s4) + x2 -> S_a
    agg_fused<16, 16, 2, false><<<gn16, 256, 0, stream>>>(S_b, rec, rowptr, nullptr, X2, S_a, nullptr, nullptr, n);
    // conv5: z1 = tanh((A z2)@W5) + x1 -> S_b
    agg_fused<16, 32, 3, false><<<gn16, 256, 0, stream>>>(S_a, rec, rowptr, W5, X1, S_b, nullptr, nullptr, n);
    // conv6: recon = sigmoid((A z1)@W6)
    agg_fused<32, 32, 4, false><<<gn32, 256, 0, stream>>>(S_b, rec, rowptr, nullptr, nullptr, S_a, nullptr, nullptr, n);
    gemm_fout<<<gn32, 256, 0, stream>>>(S_a, W6, recon, n);
}

// Round 5
// 497.190 us; speedup vs baseline: 1.9216x; 1.3989x over previous
//
#include <hip/hip_runtime.h>
#include <hip/hip_bf16.h>
#include <math.h>

#define FIN 512
#define NHID 32
#define LAT 16

// ---------------------------------------------------------------------------
// GEMM1: [n,512] @ [512,32] -> [n,32]. Register-blocked LDS GEMM (unchanged).
// ---------------------------------------------------------------------------
#define BR 128
#define KC 64
__global__ __launch_bounds__(256) void gemm_fin(const float* __restrict__ feat,
                                                const float* __restrict__ W,
                                                float* __restrict__ out, int n) {
    __shared__ float xT[KC][BR + 4];
    __shared__ float Wc[KC][NHID];
    const int tid = threadIdx.x;
    const int r0 = blockIdx.x * BR;
    const int rt = tid >> 3;
    const int ct = tid & 7;
    const int srow = tid >> 4;
    const int sc4 = tid & 15;
    float acc[4][4] = {{0.f}};

    for (int kc = 0; kc < FIN; kc += KC) {
        {
            const float4* wg = reinterpret_cast<const float4*>(W + kc * NHID);
            float4* wl = reinterpret_cast<float4*>(&Wc[0][0]);
            wl[tid] = wg[tid];
            wl[tid + 256] = wg[tid + 256];
        }
#pragma unroll
        for (int i = 0; i < 8; ++i) {
            int rr = srow + 16 * i;
            int r = r0 + rr;
            float4 v;
            if (r < n)
                v = *reinterpret_cast<const float4*>(feat + (size_t)r * FIN + kc + sc4 * 4);
            else
                v.x = v.y = v.z = v.w = 0.f;
            xT[sc4 * 4 + 0][rr] = v.x;
            xT[sc4 * 4 + 1][rr] = v.y;
            xT[sc4 * 4 + 2][rr] = v.z;
            xT[sc4 * 4 + 3][rr] = v.w;
        }
        __syncthreads();
#pragma unroll 4
        for (int k = 0; k < KC; ++k) {
            float4 xv = *reinterpret_cast<const float4*>(&xT[k][rt * 4]);
            float4 wv = *reinterpret_cast<const float4*>(&Wc[k][ct * 4]);
            acc[0][0] = fmaf(xv.x, wv.x, acc[0][0]);
            acc[0][1] = fmaf(xv.x, wv.y, acc[0][1]);
            acc[0][2] = fmaf(xv.x, wv.z, acc[0][2]);
            acc[0][3] = fmaf(xv.x, wv.w, acc[0][3]);
            acc[1][0] = fmaf(xv.y, wv.x, acc[1][0]);
            acc[1][1] = fmaf(xv.y, wv.y, acc[1][1]);
            acc[1][2] = fmaf(xv.y, wv.z, acc[1][2]);
            acc[1][3] = fmaf(xv.y, wv.w, acc[1][3]);
            acc[2][0] = fmaf(xv.z, wv.x, acc[2][0]);
            acc[2][1] = fmaf(xv.z, wv.y, acc[2][1]);
            acc[2][2] = fmaf(xv.z, wv.z, acc[2][2]);
            acc[2][3] = fmaf(xv.z, wv.w, acc[2][3]);
            acc[3][0] = fmaf(xv.w, wv.x, acc[3][0]);
            acc[3][1] = fmaf(xv.w, wv.y, acc[3][1]);
            acc[3][2] = fmaf(xv.w, wv.z, acc[3][2]);
            acc[3][3] = fmaf(xv.w, wv.w, acc[3][3]);
        }
        __syncthreads();
    }
#pragma unroll
    for (int i = 0; i < 4; ++i) {
        int r = r0 + rt * 4 + i;
        if (r < n) {
            float4 o;
            o.x = acc[i][0]; o.y = acc[i][1]; o.z = acc[i][2]; o.w = acc[i][3];
            *reinterpret_cast<float4*>(out + (size_t)r * NHID + ct * 4) = o;
        }
    }
}

// ---------------------------------------------------------------------------
// CSR build. Bucket = 256 consecutive dst nodes (nb = ceil(n/256) = 196).
// bhist: per-block LDS histogram of bucket occupancy -> ~196 global atomics
// per block (not per edge).
// ---------------------------------------------------------------------------
__global__ __launch_bounds__(256) void bhist(const int* __restrict__ dst,
                                             int* __restrict__ btot, int e) {
    __shared__ int h[256];
    const int tid = threadIdx.x;
    h[tid] = 0;
    __syncthreads();
    const int i0 = blockIdx.x * 4096;
#pragma unroll
    for (int k = 0; k < 16; ++k) {
        int j = i0 + k * 256 + tid;
        if (j < e) atomicAdd(&h[dst[j] >> 8], 1);
    }
    __syncthreads();
    if (h[tid]) atomicAdd(&btot[tid], h[tid]);
}

// Tiny 1-block scan of bucket totals -> bucket bases (= CSR bucket bases).
__global__ __launch_bounds__(256) void bscan(const int* __restrict__ btot,
                                             int* __restrict__ bbase,
                                             int* __restrict__ bcursor,
                                             int* __restrict__ rowptr,
                                             int nb, int n, int e) {
    __shared__ int sh[256];
    const int t = threadIdx.x;
    int v = (t < nb) ? btot[t] : 0;
    sh[t] = v;
    __syncthreads();
    for (int off = 1; off < 256; off <<= 1) {
        int x = (t >= off) ? sh[t - off] : 0;
        __syncthreads();
        sh[t] += x;
        __syncthreads();
    }
    int ex = sh[t] - v;
    if (t < nb) {
        bbase[t] = ex;
        bcursor[t] = ex;
    }
    if (t == 0) {
        bbase[nb] = e;
        rowptr[n] = e;
    }
}

// build_a: chunk of 4096 edges/block. LDS-count per bucket, ONE global
// atomicAdd per (block,bucket) to reserve a contiguous run, then write the
// run. Lines have a single writer except at run boundaries -> dense
// writeback (fixes the cross-XCD line-bouncing of the previous version).
// Record: (w:32 | dst:16 | src:16), n < 65536.
__global__ __launch_bounds__(256) void build_a(const int* __restrict__ src,
                                               const int* __restrict__ dst,
                                               const float* __restrict__ w,
                                               int* __restrict__ bcursor,
                                               unsigned long long* __restrict__ rec2,
                                               int e, int nb) {
    __shared__ int cnt[256];
    __shared__ int gb[256];
    const int tid = threadIdx.x;
    const int i0 = blockIdx.x * 4096;
    cnt[tid] = 0;
    __syncthreads();
    unsigned long long rc[16];
    int rkbk[16];
#pragma unroll
    for (int k = 0; k < 16; ++k) {
        int j = i0 + k * 256 + tid;
        rkbk[k] = -1;
        if (j < e) {
            int d = dst[j];
            int b = d >> 8;
            int rk = atomicAdd(&cnt[b], 1);
            rkbk[k] = (rk << 8) | b;
            rc[k] = ((unsigned long long)__float_as_uint(w[j]) << 32) |
                    ((unsigned)d << 16) | (unsigned)src[j];
        }
    }
    __syncthreads();
    if (tid < nb && cnt[tid] > 0) gb[tid] = atomicAdd(&bcursor[tid], cnt[tid]);
    __syncthreads();
#pragma unroll
    for (int k = 0; k < 16; ++k) {
        if (rkbk[k] >= 0) {
            int b = rkbk[k] & 255;
            int rk = rkbk[k] >> 8;
            rec2[gb[b] + rk] = rc[k];
        }
    }
}

// build_b: one block OWNS one bucket (256 nodes, ~65KB CSR region).
// LDS node-histogram -> LDS scan -> rowptr written directly -> LDS-cursor
// scatter to final CSR. Single writer per region, all fine atomics in LDS.
__global__ __launch_bounds__(256) void build_b(const unsigned long long* __restrict__ rec2,
                                               const int* __restrict__ bbase,
                                               int* __restrict__ rowptr,
                                               unsigned long long* __restrict__ rec,
                                               int n) {
    __shared__ int cnt[256];
    __shared__ int cur[256];
    const int t = threadIdx.x;
    const int b = blockIdx.x;
    const int lo = bbase[b];
    const int hi = bbase[b + 1];
    cnt[t] = 0;
    __syncthreads();
    for (int i = lo + t; i < hi; i += 256)
        atomicAdd(&cnt[((unsigned)rec2[i] >> 16) & 255], 1);
    __syncthreads();
    int v = cnt[t];
    cur[t] = v;
    __syncthreads();
    for (int off = 1; off < 256; off <<= 1) {
        int x = (t >= off) ? cur[t - off] : 0;
        __syncthreads();
        cur[t] += x;
        __syncthreads();
    }
    int ex = cur[t] - v;  // exclusive scan
    int node = b * 256 + t;
    if (node < n) rowptr[node] = lo + ex;
    __syncthreads();
    cur[t] = ex;  // per-node cursor
    __syncthreads();
    for (int i = lo + t; i < hi; i += 256) {
        unsigned long long r = rec2[i];
        unsigned lo32 = (unsigned)r;
        int ln = (lo32 >> 16) & 255;
        int p = atomicAdd(&cur[ln], 1);
        rec[lo + p] = (r & 0xffffffff00000000ull) | (lo32 & 0xffffu);
    }
}

// ---------------------------------------------------------------------------
// CSR aggregation with fused epilogues. D lanes per dst node.
// MODE 1: out0 = tanh(acc) [D]; out1 = out0 @ Wn [C]   (+ optional softmax)
// MODE 2: out0 = tanh(acc) + res [D]
// MODE 3: out0 = tanh(accRow @ Wn) + res [C=32, D=16]
// MODE 4: out0 = acc [D]
// ---------------------------------------------------------------------------
template <int D, int C, int MODE, bool SMAX>
__global__ __launch_bounds__(256) void agg_fused(const float* __restrict__ s,
                                                 const unsigned long long* __restrict__ rec,
                                                 const int* __restrict__ rowptr,
                                                 const float* __restrict__ Wn,
                                                 const float* __restrict__ res,
                                                 float* __restrict__ out0,
                                                 float* __restrict__ out1,
                                                 float* __restrict__ pred, int n) {
    __shared__ float wl[(MODE == 1 || MODE == 3) ? D * C : 1];
    if (MODE == 1 || MODE == 3) {
        for (int i = threadIdx.x; i < D * C; i += 256) wl[i] = Wn[i];
        __syncthreads();
    }
    constexpr int NPB = 256 / D;
    const int node = blockIdx.x * NPB + threadIdx.x / D;
    const int c = threadIdx.x % D;
    float acc = 0.f;
    if (node < n) {
        int i = rowptr[node];
        const int end = rowptr[node + 1];
        for (; i + 1 < end; i += 2) {
            unsigned long long r0 = rec[i];
            unsigned long long r1 = rec[i + 1];
            int s0 = (int)(r0 & 0xffffffffu);
            int s1 = (int)(r1 & 0xffffffffu);
            float w0 = __uint_as_float((unsigned)(r0 >> 32));
            float w1 = __uint_as_float((unsigned)(r1 >> 32));
            float v0 = s[(size_t)s0 * D + c];
            float v1 = s[(size_t)s1 * D + c];
            acc = fmaf(v0, w0, acc);
            acc = fmaf(v1, w1, acc);
        }
        if (i < end) {
            unsigned long long r0 = rec[i];
            int s0 = (int)(r0 & 0xffffffffu);
            float w0 = __uint_as_float((unsigned)(r0 >> 32));
            acc = fmaf(s[(size_t)s0 * D + c], w0, acc);
        }
    }
    if (MODE == 1) {
        float v = tanhf(acc);
        if (node < n) out0[(size_t)node * D + c] = v;
        if (SMAX) {
            float m = v;
#pragma unroll
            for (int mk = 8; mk >= 1; mk >>= 1) m = fmaxf(m, __shfl_xor(m, mk, 16));
            float ev = expf(v - m);
            float sum = ev;
#pragma unroll
            for (int mk = 8; mk >= 1; mk >>= 1) sum += __shfl_xor(sum, mk, 16);
            if (node < n) pred[(size_t)node * 16 + c] = ev / sum;
        }
        int cc = c & (C - 1);
        float g = 0.f;
#pragma unroll
        for (int k = 0; k < D; ++k) g = fmaf(__shfl(v, k, D), wl[k * C + cc], g);
        if (node < n && c < C) out1[(size_t)node * C + c] = g;
    } else if (MODE == 2) {
        if (node < n) out0[(size_t)node * D + c] = tanhf(acc) + res[(size_t)node * D + c];
    } else if (MODE == 3) {
        float g0 = 0.f, g1 = 0.f;
#pragma unroll
        for (int k = 0; k < 16; ++k) {
            float vk = __shfl(acc, k, 16);
            g0 = fmaf(vk, wl[k * 32 + c], g0);
            g1 = fmaf(vk, wl[k * 32 + c + 16], g1);
        }
        if (node < n) {
            out0[(size_t)node * 32 + c] = tanhf(g0) + res[(size_t)node * 32 + c];
            out0[(size_t)node * 32 + c + 16] = tanhf(g1) + res[(size_t)node * 32 + c + 16];
        }
    } else {  // MODE 4
        if (node < n) out0[(size_t)node * D + c] = acc;
    }
}

// ---------------------------------------------------------------------------
// GEMM6: [n,32] @ [32,512] -> sigmoid -> [n,512]. W6 in LDS (unchanged).
// ---------------------------------------------------------------------------
__global__ __launch_bounds__(256) void gemm_fout(const float* __restrict__ a,
                                                 const float* __restrict__ W,
                                                 float* __restrict__ out, int n) {
    __shared__ float wl[NHID * FIN];
    __shared__ float ar[8][NHID];
    {
        const float4* w4 = reinterpret_cast<const float4*>(W);
        float4* wl4 = reinterpret_cast<float4*>(wl);
        for (int i = threadIdx.x; i < NHID * FIN / 4; i += 256) wl4[i] = w4[i];
    }
    int r0 = blockIdx.x * 8;
    {
        int rr = threadIdx.x >> 5, cc = threadIdx.x & 31;
        int r = r0 + rr;
        ar[rr][cc] = (r < n) ? a[(size_t)r * NHID + cc] : 0.f;
    }
    __syncthreads();
    int t = threadIdx.x;
    for (int rr = 0; rr < 8; ++rr) {
        int r = r0 + rr;
        if (r >= n) break;
        float accx = 0.f, accy = 0.f;
#pragma unroll
        for (int k = 0; k < NHID; ++k) {
            float av = ar[rr][k];
            float2 wv = *reinterpret_cast<const float2*>(&wl[k * FIN + 2 * t]);
            accx = fmaf(av, wv.x, accx);
            accy = fmaf(av, wv.y, accy);
        }
        float2 o;
        o.x = 1.f / (1.f + expf(-accx));
        o.y = 1.f / (1.f + expf(-accy));
        *reinterpret_cast<float2*>(&out[(size_t)r * FIN + 2 * t]) = o;
    }
}

extern "C" void kernel_launch(void* const* d_in, const int* in_sizes, int n_in,
                              void* d_out, int out_size, void* d_ws, size_t ws_size,
                              hipStream_t stream) {
    const float* feat = (const float*)d_in[0];
    const int* esrc = (const int*)d_in[1];
    const int* edst = (const int*)d_in[2];
    const float* ewt = (const float*)d_in[3];
    const float* W1 = (const float*)d_in[4];
    const float* W2 = (const float*)d_in[5];
    const float* W3 = (const float*)d_in[6];
    const float* W4 = (const float*)d_in[7];
    const float* W5 = (const float*)d_in[8];
    const float* W6 = (const float*)d_in[9];
    const int n = in_sizes[0] / FIN;
    const int e = in_sizes[1];
    const int nb = (n + 255) >> 8;  // 196 buckets of 256 nodes

    float* out = (float*)d_out;
    float* recon = out;                   // [n,512]
    float* zout = out + (size_t)n * FIN;  // [n,16]
    float* pred = zout + (size_t)n * 16;  // [n,16]

    // Workspace: rec | rowptr | btot/bbase/bcursor | float buffers.
    // rec2 aliases S_a+S_b (exactly e*8 bytes), consumed before they're used.
    char* wsb = (char*)d_ws;
    unsigned long long* rec = (unsigned long long*)wsb;  // e * 8B
    int* rowptr = (int*)(wsb + (size_t)e * 8);           // n+1
    int* btot = rowptr + n + 1;                          // 256
    int* bbase = btot + 256;                             // nb+1
    int* bcursor = bbase + nb + 1;                       // nb
    size_t foff = ((size_t)(bcursor + nb - (int*)wsb) + 3) & ~(size_t)3;
    float* S_a = (float*)wsb + foff;    // n*32
    float* S_b = S_a + (size_t)n * 32;  // n*32
    float* X1 = S_b + (size_t)n * 32;   // n*32 (x1)
    float* X2 = X1 + (size_t)n * 32;    // n*16 (x2)
    unsigned long long* rec2 = (unsigned long long*)S_a;  // e*8B alias

    const int geb = (e + 4095) / 4096;  // 391
    const int gn32 = (n + 7) / 8;
    const int gn16 = (n + 15) / 16;

    // ---- CSR build ----
    hipMemsetAsync(btot, 0, 256 * sizeof(int), stream);
    bhist<<<geb, 256, 0, stream>>>(edst, btot, e);
    bscan<<<1, 256, 0, stream>>>(btot, bbase, bcursor, rowptr, nb, n, e);
    build_a<<<geb, 256, 0, stream>>>(esrc, edst, ewt, bcursor, rec2, e, nb);
    build_b<<<nb, 256, 0, stream>>>(rec2, bbase, rowptr, rec, n);

    // conv1: x1 = tanh(A(feat@W1)) -> X1 ; s2 = x1@W2 -> S_b
    gemm_fin<<<(n + BR - 1) / BR, 256, 0, stream>>>(feat, W1, S_a, n);
    agg_fused<32, 16, 1, false><<<gn32, 256, 0, stream>>>(S_a, rec, rowptr, W2, nullptr, X1, S_b, nullptr, n);
    // conv2: x2 = tanh(A s2) -> X2 ; s3 = x2@W3 -> S_a
    agg_fused<16, 16, 1, false><<<gn16, 256, 0, stream>>>(S_b, rec, rowptr, W3, nullptr, X2, S_a, nullptr, n);
    // conv3: z = tanh(A s3) -> zout ; pred = softmax(z) ; s4 = z@W4 -> S_b
    agg_fused<16, 16, 1, true><<<gn16, 256, 0, stream>>>(S_a, rec, rowptr, W4, nullptr, zout, S_b, pred, n);
    // conv4: z2 = tanh(A s4) + x2 -> S_a
    agg_fused<16, 16, 2, false><<<gn16, 256, 0, stream>>>(S_b, rec, rowptr, nullptr, X2, S_a, nullptr, nullptr, n);
    // conv5: z1 = tanh((A z2)@W5) + x1 -> S_b
    agg_fused<16, 32, 3, false><<<gn16, 256, 0, stream>>>(S_a, rec, rowptr, W5, X1, S_b, nullptr, nullptr, n);
    // conv6: recon = sigmoid((A z1)@W6)
    agg_fused<32, 32, 4, false><<<gn32, 256, 0, stream>>>(S_b, rec, rowptr, nullptr, nullptr, S_a, nullptr, nullptr, n);
    gemm_fout<<<gn32, 256, 0, stream>>>(S_a, W6, recon, n);
}

// Round 6
// 446.134 us; speedup vs baseline: 2.1415x; 1.1144x over previous
//
#include <hip/hip_runtime.h>
#include <hip/hip_bf16.h>
#include <math.h>

#define FIN 512
#define NHID 32
#define LAT 16

// ---------------------------------------------------------------------------
// GEMM1: [n,512] @ [512,32] -> [n,32]. Register-blocked LDS GEMM (unchanged).
// ---------------------------------------------------------------------------
#define BR 128
#define KC 64
__global__ __launch_bounds__(256) void gemm_fin(const float* __restrict__ feat,
                                                const float* __restrict__ W,
                                                float* __restrict__ out, int n) {
    __shared__ float xT[KC][BR + 4];
    __shared__ float Wc[KC][NHID];
    const int tid = threadIdx.x;
    const int r0 = blockIdx.x * BR;
    const int rt = tid >> 3;
    const int ct = tid & 7;
    const int srow = tid >> 4;
    const int sc4 = tid & 15;
    float acc[4][4] = {{0.f}};

    for (int kc = 0; kc < FIN; kc += KC) {
        {
            const float4* wg = reinterpret_cast<const float4*>(W + kc * NHID);
            float4* wl = reinterpret_cast<float4*>(&Wc[0][0]);
            wl[tid] = wg[tid];
            wl[tid + 256] = wg[tid + 256];
        }
#pragma unroll
        for (int i = 0; i < 8; ++i) {
            int rr = srow + 16 * i;
            int r = r0 + rr;
            float4 v;
            if (r < n)
                v = *reinterpret_cast<const float4*>(feat + (size_t)r * FIN + kc + sc4 * 4);
            else
                v.x = v.y = v.z = v.w = 0.f;
            xT[sc4 * 4 + 0][rr] = v.x;
            xT[sc4 * 4 + 1][rr] = v.y;
            xT[sc4 * 4 + 2][rr] = v.z;
            xT[sc4 * 4 + 3][rr] = v.w;
        }
        __syncthreads();
#pragma unroll 4
        for (int k = 0; k < KC; ++k) {
            float4 xv = *reinterpret_cast<const float4*>(&xT[k][rt * 4]);
            float4 wv = *reinterpret_cast<const float4*>(&Wc[k][ct * 4]);
            acc[0][0] = fmaf(xv.x, wv.x, acc[0][0]);
            acc[0][1] = fmaf(xv.x, wv.y, acc[0][1]);
            acc[0][2] = fmaf(xv.x, wv.z, acc[0][2]);
            acc[0][3] = fmaf(xv.x, wv.w, acc[0][3]);
            acc[1][0] = fmaf(xv.y, wv.x, acc[1][0]);
            acc[1][1] = fmaf(xv.y, wv.y, acc[1][1]);
            acc[1][2] = fmaf(xv.y, wv.z, acc[1][2]);
            acc[1][3] = fmaf(xv.y, wv.w, acc[1][3]);
            acc[2][0] = fmaf(xv.z, wv.x, acc[2][0]);
            acc[2][1] = fmaf(xv.z, wv.y, acc[2][1]);
            acc[2][2] = fmaf(xv.z, wv.z, acc[2][2]);
            acc[2][3] = fmaf(xv.z, wv.w, acc[2][3]);
            acc[3][0] = fmaf(xv.w, wv.x, acc[3][0]);
            acc[3][1] = fmaf(xv.w, wv.y, acc[3][1]);
            acc[3][2] = fmaf(xv.w, wv.z, acc[3][2]);
            acc[3][3] = fmaf(xv.w, wv.w, acc[3][3]);
        }
        __syncthreads();
    }
#pragma unroll
    for (int i = 0; i < 4; ++i) {
        int r = r0 + rt * 4 + i;
        if (r < n) {
            float4 o;
            o.x = acc[i][0]; o.y = acc[i][1]; o.z = acc[i][2]; o.w = acc[i][3];
            *reinterpret_cast<float4*>(out + (size_t)r * NHID + ct * 4) = o;
        }
    }
}

// ---------------------------------------------------------------------------
// CSR build (unchanged from round 4 — verified dense-writeback design).
// ---------------------------------------------------------------------------
__global__ __launch_bounds__(256) void bhist(const int* __restrict__ dst,
                                             int* __restrict__ btot, int e) {
    __shared__ int h[256];
    const int tid = threadIdx.x;
    h[tid] = 0;
    __syncthreads();
    const int i0 = blockIdx.x * 4096;
#pragma unroll
    for (int k = 0; k < 16; ++k) {
        int j = i0 + k * 256 + tid;
        if (j < e) atomicAdd(&h[dst[j] >> 8], 1);
    }
    __syncthreads();
    if (h[tid]) atomicAdd(&btot[tid], h[tid]);
}

__global__ __launch_bounds__(256) void bscan(const int* __restrict__ btot,
                                             int* __restrict__ bbase,
                                             int* __restrict__ bcursor,
                                             int* __restrict__ rowptr,
                                             int nb, int n, int e) {
    __shared__ int sh[256];
    const int t = threadIdx.x;
    int v = (t < nb) ? btot[t] : 0;
    sh[t] = v;
    __syncthreads();
    for (int off = 1; off < 256; off <<= 1) {
        int x = (t >= off) ? sh[t - off] : 0;
        __syncthreads();
        sh[t] += x;
        __syncthreads();
    }
    int ex = sh[t] - v;
    if (t < nb) {
        bbase[t] = ex;
        bcursor[t] = ex;
    }
    if (t == 0) {
        bbase[nb] = e;
        rowptr[n] = e;
    }
}

__global__ __launch_bounds__(256) void build_a(const int* __restrict__ src,
                                               const int* __restrict__ dst,
                                               const float* __restrict__ w,
                                               int* __restrict__ bcursor,
                                               unsigned long long* __restrict__ rec2,
                                               int e, int nb) {
    __shared__ int cnt[256];
    __shared__ int gb[256];
    const int tid = threadIdx.x;
    const int i0 = blockIdx.x * 4096;
    cnt[tid] = 0;
    __syncthreads();
    unsigned long long rc[16];
    int rkbk[16];
#pragma unroll
    for (int k = 0; k < 16; ++k) {
        int j = i0 + k * 256 + tid;
        rkbk[k] = -1;
        if (j < e) {
            int d = dst[j];
            int b = d >> 8;
            int rk = atomicAdd(&cnt[b], 1);
            rkbk[k] = (rk << 8) | b;
            rc[k] = ((unsigned long long)__float_as_uint(w[j]) << 32) |
                    ((unsigned)d << 16) | (unsigned)src[j];
        }
    }
    __syncthreads();
    if (tid < nb && cnt[tid] > 0) gb[tid] = atomicAdd(&bcursor[tid], cnt[tid]);
    __syncthreads();
#pragma unroll
    for (int k = 0; k < 16; ++k) {
        if (rkbk[k] >= 0) {
            int b = rkbk[k] & 255;
            int rk = rkbk[k] >> 8;
            rec2[gb[b] + rk] = rc[k];
        }
    }
}

__global__ __launch_bounds__(256) void build_b(const unsigned long long* __restrict__ rec2,
                                               const int* __restrict__ bbase,
                                               int* __restrict__ rowptr,
                                               unsigned long long* __restrict__ rec,
                                               int n) {
    __shared__ int cnt[256];
    __shared__ int cur[256];
    const int t = threadIdx.x;
    const int b = blockIdx.x;
    const int lo = bbase[b];
    const int hi = bbase[b + 1];
    cnt[t] = 0;
    __syncthreads();
    for (int i = lo + t; i < hi; i += 256)
        atomicAdd(&cnt[((unsigned)rec2[i] >> 16) & 255], 1);
    __syncthreads();
    int v = cnt[t];
    cur[t] = v;
    __syncthreads();
    for (int off = 1; off < 256; off <<= 1) {
        int x = (t >= off) ? cur[t - off] : 0;
        __syncthreads();
        cur[t] += x;
        __syncthreads();
    }
    int ex = cur[t] - v;
    int node = b * 256 + t;
    if (node < n) rowptr[node] = lo + ex;
    __syncthreads();
    cur[t] = ex;
    __syncthreads();
    for (int i = lo + t; i < hi; i += 256) {
        unsigned long long r = rec2[i];
        unsigned lo32 = (unsigned)r;
        int ln = (lo32 >> 16) & 255;
        int p = atomicAdd(&cur[ln], 1);
        rec[lo + p] = (r & 0xffffffff00000000ull) | (lo32 & 0xffffu);
    }
}

// ---------------------------------------------------------------------------
// CSR aggregation with fused epilogues (unchanged).
// ---------------------------------------------------------------------------
template <int D, int C, int MODE, bool SMAX>
__global__ __launch_bounds__(256) void agg_fused(const float* __restrict__ s,
                                                 const unsigned long long* __restrict__ rec,
                                                 const int* __restrict__ rowptr,
                                                 const float* __restrict__ Wn,
                                                 const float* __restrict__ res,
                                                 float* __restrict__ out0,
                                                 float* __restrict__ out1,
                                                 float* __restrict__ pred, int n) {
    __shared__ float wl[(MODE == 1 || MODE == 3) ? D * C : 1];
    if (MODE == 1 || MODE == 3) {
        for (int i = threadIdx.x; i < D * C; i += 256) wl[i] = Wn[i];
        __syncthreads();
    }
    constexpr int NPB = 256 / D;
    const int node = blockIdx.x * NPB + threadIdx.x / D;
    const int c = threadIdx.x % D;
    float acc = 0.f;
    if (node < n) {
        int i = rowptr[node];
        const int end = rowptr[node + 1];
        for (; i + 1 < end; i += 2) {
            unsigned long long r0 = rec[i];
            unsigned long long r1 = rec[i + 1];
            int s0 = (int)(r0 & 0xffffffffu);
            int s1 = (int)(r1 & 0xffffffffu);
            float w0 = __uint_as_float((unsigned)(r0 >> 32));
            float w1 = __uint_as_float((unsigned)(r1 >> 32));
            float v0 = s[(size_t)s0 * D + c];
            float v1 = s[(size_t)s1 * D + c];
            acc = fmaf(v0, w0, acc);
            acc = fmaf(v1, w1, acc);
        }
        if (i < end) {
            unsigned long long r0 = rec[i];
            int s0 = (int)(r0 & 0xffffffffu);
            float w0 = __uint_as_float((unsigned)(r0 >> 32));
            acc = fmaf(s[(size_t)s0 * D + c], w0, acc);
        }
    }
    if (MODE == 1) {
        float v = tanhf(acc);
        if (node < n) out0[(size_t)node * D + c] = v;
        if (SMAX) {
            float m = v;
#pragma unroll
            for (int mk = 8; mk >= 1; mk >>= 1) m = fmaxf(m, __shfl_xor(m, mk, 16));
            float ev = expf(v - m);
            float sum = ev;
#pragma unroll
            for (int mk = 8; mk >= 1; mk >>= 1) sum += __shfl_xor(sum, mk, 16);
            if (node < n) pred[(size_t)node * 16 + c] = ev / sum;
        }
        int cc = c & (C - 1);
        float g = 0.f;
#pragma unroll
        for (int k = 0; k < D; ++k) g = fmaf(__shfl(v, k, D), wl[k * C + cc], g);
        if (node < n && c < C) out1[(size_t)node * C + c] = g;
    } else if (MODE == 2) {
        if (node < n) out0[(size_t)node * D + c] = tanhf(acc) + res[(size_t)node * D + c];
    } else if (MODE == 3) {
        float g0 = 0.f, g1 = 0.f;
#pragma unroll
        for (int k = 0; k < 16; ++k) {
            float vk = __shfl(acc, k, 16);
            g0 = fmaf(vk, wl[k * 32 + c], g0);
            g1 = fmaf(vk, wl[k * 32 + c + 16], g1);
        }
        if (node < n) {
            out0[(size_t)node * 32 + c] = tanhf(g0) + res[(size_t)node * 32 + c];
            out0[(size_t)node * 32 + c + 16] = tanhf(g1) + res[(size_t)node * 32 + c + 16];
        }
    } else {  // MODE 4
        if (node < n) out0[(size_t)node * D + c] = acc;
    }
}

// ---------------------------------------------------------------------------
// GEMM6: [n,32] @ [32,512] -> sigmoid -> [n,512]. REWRITTEN: persistent
// blocks stage W6 ONCE (staging 400MB -> 32MB) and grid-stride over 32-row
// tiles with 4x4 register blocking (LDS reads/output cut 4x vs float2 loop).
// ---------------------------------------------------------------------------
#define FT_R 32
__global__ __launch_bounds__(256) void gemm_fout(const float* __restrict__ a,
                                                 const float* __restrict__ W,
                                                 float* __restrict__ out, int n,
                                                 int ntiles) {
    __shared__ float wl[NHID * FIN];     // 64 KB
    __shared__ float aT[NHID][FT_R + 1]; // 32 x 33 = 4.2 KB
    {
        const float4* w4 = reinterpret_cast<const float4*>(W);
        float4* wl4 = reinterpret_cast<float4*>(wl);
        for (int i = threadIdx.x; i < NHID * FIN / 4; i += 256) wl4[i] = w4[i];
    }
    const int rt = threadIdx.x >> 5;  // 0..7  (4 rows each)
    const int ct = threadIdx.x & 31;  // 0..31 (4 cols each within 128-chunk)
    const int srr = threadIdx.x >> 3; // staging: row 0..31
    const int sk4 = threadIdx.x & 7;  // staging: float4 0..7

    for (int tile = blockIdx.x; tile < ntiles; tile += gridDim.x) {
        const int r0 = tile * FT_R;
        __syncthreads();  // aT readers from previous tile done; wl staged (1st iter)
        {
            int r = r0 + srr;
            float4 v;
            if (r < n)
                v = *reinterpret_cast<const float4*>(a + (size_t)r * NHID + sk4 * 4);
            else
                v.x = v.y = v.z = v.w = 0.f;
            aT[sk4 * 4 + 0][srr] = v.x;
            aT[sk4 * 4 + 1][srr] = v.y;
            aT[sk4 * 4 + 2][srr] = v.z;
            aT[sk4 * 4 + 3][srr] = v.w;
        }
        __syncthreads();
#pragma unroll
        for (int cc = 0; cc < 4; ++cc) {  // col chunks of 128
            float acc[4][4] = {{0.f}};
#pragma unroll 8
            for (int k = 0; k < NHID; ++k) {
                float4 av = *reinterpret_cast<const float4*>(&aT[k][rt * 4]);
                float4 wv = *reinterpret_cast<const float4*>(&wl[k * FIN + cc * 128 + ct * 4]);
                acc[0][0] = fmaf(av.x, wv.x, acc[0][0]);
                acc[0][1] = fmaf(av.x, wv.y, acc[0][1]);
                acc[0][2] = fmaf(av.x, wv.z, acc[0][2]);
                acc[0][3] = fmaf(av.x, wv.w, acc[0][3]);
                acc[1][0] = fmaf(av.y, wv.x, acc[1][0]);
                acc[1][1] = fmaf(av.y, wv.y, acc[1][1]);
                acc[1][2] = fmaf(av.y, wv.z, acc[1][2]);
                acc[1][3] = fmaf(av.y, wv.w, acc[1][3]);
                acc[2][0] = fmaf(av.z, wv.x, acc[2][0]);
                acc[2][1] = fmaf(av.z, wv.y, acc[2][1]);
                acc[2][2] = fmaf(av.z, wv.z, acc[2][2]);
                acc[2][3] = fmaf(av.z, wv.w, acc[2][3]);
                acc[3][0] = fmaf(av.w, wv.x, acc[3][0]);
                acc[3][1] = fmaf(av.w, wv.y, acc[3][1]);
                acc[3][2] = fmaf(av.w, wv.z, acc[3][2]);
                acc[3][3] = fmaf(av.w, wv.w, acc[3][3]);
            }
#pragma unroll
            for (int i = 0; i < 4; ++i) {
                int r = r0 + rt * 4 + i;
                if (r < n) {
                    float4 o;
                    o.x = 1.f / (1.f + expf(-acc[i][0]));
                    o.y = 1.f / (1.f + expf(-acc[i][1]));
                    o.z = 1.f / (1.f + expf(-acc[i][2]));
                    o.w = 1.f / (1.f + expf(-acc[i][3]));
                    *reinterpret_cast<float4*>(out + (size_t)r * FIN + cc * 128 + ct * 4) = o;
                }
            }
        }
    }
}

extern "C" void kernel_launch(void* const* d_in, const int* in_sizes, int n_in,
                              void* d_out, int out_size, void* d_ws, size_t ws_size,
                              hipStream_t stream) {
    const float* feat = (const float*)d_in[0];
    const int* esrc = (const int*)d_in[1];
    const int* edst = (const int*)d_in[2];
    const float* ewt = (const float*)d_in[3];
    const float* W1 = (const float*)d_in[4];
    const float* W2 = (const float*)d_in[5];
    const float* W3 = (const float*)d_in[6];
    const float* W4 = (const float*)d_in[7];
    const float* W5 = (const float*)d_in[8];
    const float* W6 = (const float*)d_in[9];
    const int n = in_sizes[0] / FIN;
    const int e = in_sizes[1];
    const int nb = (n + 255) >> 8;

    float* out = (float*)d_out;
    float* recon = out;                   // [n,512]
    float* zout = out + (size_t)n * FIN;  // [n,16]
    float* pred = zout + (size_t)n * 16;  // [n,16]

    char* wsb = (char*)d_ws;
    unsigned long long* rec = (unsigned long long*)wsb;  // e * 8B
    int* rowptr = (int*)(wsb + (size_t)e * 8);           // n+1
    int* btot = rowptr + n + 1;                          // 256
    int* bbase = btot + 256;                             // nb+1
    int* bcursor = bbase + nb + 1;                       // nb
    size_t foff = ((size_t)(bcursor + nb - (int*)wsb) + 3) & ~(size_t)3;
    float* S_a = (float*)wsb + foff;    // n*32
    float* S_b = S_a + (size_t)n * 32;  // n*32
    float* X1 = S_b + (size_t)n * 32;   // n*32 (x1)
    float* X2 = X1 + (size_t)n * 32;    // n*16 (x2)
    unsigned long long* rec2 = (unsigned long long*)S_a;  // e*8B alias

    const int geb = (e + 4095) / 4096;
    const int gn32 = (n + 7) / 8;
    const int gn16 = (n + 15) / 16;
    const int ntiles = (n + FT_R - 1) / FT_R;

    // ---- CSR build ----
    hipMemsetAsync(btot, 0, 256 * sizeof(int), stream);
    bhist<<<geb, 256, 0, stream>>>(edst, btot, e);
    bscan<<<1, 256, 0, stream>>>(btot, bbase, bcursor, rowptr, nb, n, e);
    build_a<<<geb, 256, 0, stream>>>(esrc, edst, ewt, bcursor, rec2, e, nb);
    build_b<<<nb, 256, 0, stream>>>(rec2, bbase, rowptr, rec, n);

    // conv1: x1 = tanh(A(feat@W1)) -> X1 ; s2 = x1@W2 -> S_b
    gemm_fin<<<(n + BR - 1) / BR, 256, 0, stream>>>(feat, W1, S_a, n);
    agg_fused<32, 16, 1, false><<<gn32, 256, 0, stream>>>(S_a, rec, rowptr, W2, nullptr, X1, S_b, nullptr, n);
    // conv2: x2 = tanh(A s2) -> X2 ; s3 = x2@W3 -> S_a
    agg_fused<16, 16, 1, false><<<gn16, 256, 0, stream>>>(S_b, rec, rowptr, W3, nullptr, X2, S_a, nullptr, n);
    // conv3: z = tanh(A s3) -> zout ; pred = softmax(z) ; s4 = z@W4 -> S_b
    agg_fused<16, 16, 1, true><<<gn16, 256, 0, stream>>>(S_a, rec, rowptr, W4, nullptr, zout, S_b, pred, n);
    // conv4: z2 = tanh(A s4) + x2 -> S_a
    agg_fused<16, 16, 2, false><<<gn16, 256, 0, stream>>>(S_b, rec, rowptr, nullptr, X2, S_a, nullptr, nullptr, n);
    // conv5: z1 = tanh((A z2)@W5) + x1 -> S_b
    agg_fused<16, 32, 3, false><<<gn16, 256, 0, stream>>>(S_a, rec, rowptr, W5, X1, S_b, nullptr, nullptr, n);
    // conv6: recon = sigmoid((A z1)@W6)
    agg_fused<32, 32, 4, false><<<gn32, 256, 0, stream>>>(S_b, rec, rowptr, nullptr, nullptr, S_a, nullptr, nullptr, n);
    gemm_fout<<<512, 256, 0, stream>>>(S_a, W6, recon, n, ntiles);
}

// Round 7
// 428.589 us; speedup vs baseline: 2.2292x; 1.0409x over previous
//
#include <hip/hip_runtime.h>
#include <hip/hip_bf16.h>
#include <math.h>

#define FIN 512
#define NHID 32
#define LAT 16

// ---------------------------------------------------------------------------
// GEMM1: [n,512] @ [512,32] -> [n,32]. K-split x2 (block = 128 rows x 256 K),
// grid 2*ntile (782) for ~3 blocks/CU. xT stored with XOR group swizzle
// (group = (rr>>2) ^ ((k>>2)&7), LD=128): staging writes 2-way (free),
// compute b128 reads conflict-free, 16B alignment kept. Partial sums to
// out0/out1, reduced by add2.
// ---------------------------------------------------------------------------
#define BR 128
#define KC 64
__global__ __launch_bounds__(256) void gemm_fin(const float* __restrict__ feat,
                                                const float* __restrict__ W,
                                                float* __restrict__ out0,
                                                float* __restrict__ out1,
                                                int n, int ntile) {
    __shared__ float xT[KC][BR];    // 32 KB, swizzled
    __shared__ float Wc[KC][NHID];  // 8 KB
    const int tid = threadIdx.x;
    const int tile = blockIdx.x % ntile;
    const int khalf = blockIdx.x / ntile;
    const int r0 = tile * BR;
    const int k0 = khalf * 256;
    float* __restrict__ out = khalf ? out1 : out0;
    const int rt = tid >> 3;    // 0..31 row-group (4 rows)
    const int ct = tid & 7;     // 0..7  col-group (4 cols)
    const int srow = tid >> 4;  // 0..15 staging row base
    const int sc4 = tid & 15;   // 0..15 staging k-float4
    float acc[4][4] = {{0.f}};

    for (int kc = 0; kc < 256; kc += KC) {
        {   // stage W chunk [64][32] = 512 float4
            const float4* wg = reinterpret_cast<const float4*>(W + (k0 + kc) * NHID);
            float4* wl = reinterpret_cast<float4*>(&Wc[0][0]);
            wl[tid] = wg[tid];
            wl[tid + 256] = wg[tid + 256];
        }
#pragma unroll
        for (int i = 0; i < 8; ++i) {
            int rr = srow + 16 * i;
            int r = r0 + rr;
            float4 v;
            if (r < n)
                v = *reinterpret_cast<const float4*>(feat + (size_t)r * FIN + k0 + kc + sc4 * 4);
            else
                v.x = v.y = v.z = v.w = 0.f;
            // k_local = sc4*4+j  ->  (k_local>>2)&7 = sc4&7
            int gs = ((rr >> 2) ^ (sc4 & 7)) * 4 + (rr & 3);
            xT[sc4 * 4 + 0][gs] = v.x;
            xT[sc4 * 4 + 1][gs] = v.y;
            xT[sc4 * 4 + 2][gs] = v.z;
            xT[sc4 * 4 + 3][gs] = v.w;
        }
        __syncthreads();
#pragma unroll 4
        for (int k = 0; k < KC; ++k) {
            int sw = (rt ^ ((k >> 2) & 7)) * 4;
            float4 xv = *reinterpret_cast<const float4*>(&xT[k][sw]);
            float4 wv = *reinterpret_cast<const float4*>(&Wc[k][ct * 4]);
            acc[0][0] = fmaf(xv.x, wv.x, acc[0][0]);
            acc[0][1] = fmaf(xv.x, wv.y, acc[0][1]);
            acc[0][2] = fmaf(xv.x, wv.z, acc[0][2]);
            acc[0][3] = fmaf(xv.x, wv.w, acc[0][3]);
            acc[1][0] = fmaf(xv.y, wv.x, acc[1][0]);
            acc[1][1] = fmaf(xv.y, wv.y, acc[1][1]);
            acc[1][2] = fmaf(xv.y, wv.z, acc[1][2]);
            acc[1][3] = fmaf(xv.y, wv.w, acc[1][3]);
            acc[2][0] = fmaf(xv.z, wv.x, acc[2][0]);
            acc[2][1] = fmaf(xv.z, wv.y, acc[2][1]);
            acc[2][2] = fmaf(xv.z, wv.z, acc[2][2]);
            acc[2][3] = fmaf(xv.z, wv.w, acc[2][3]);
            acc[3][0] = fmaf(xv.w, wv.x, acc[3][0]);
            acc[3][1] = fmaf(xv.w, wv.y, acc[3][1]);
            acc[3][2] = fmaf(xv.w, wv.z, acc[3][2]);
            acc[3][3] = fmaf(xv.w, wv.w, acc[3][3]);
        }
        __syncthreads();
    }
#pragma unroll
    for (int i = 0; i < 4; ++i) {
        int r = r0 + rt * 4 + i;
        if (r < n) {
            float4 o;
            o.x = acc[i][0]; o.y = acc[i][1]; o.z = acc[i][2]; o.w = acc[i][3];
            *reinterpret_cast<float4*>(out + (size_t)r * NHID + ct * 4) = o;
        }
    }
}

// a += b (float4), for the K-split reduction.
__global__ __launch_bounds__(256) void add2(float* __restrict__ a,
                                            const float* __restrict__ b, int n4) {
    int i = blockIdx.x * 256 + threadIdx.x;
    if (i < n4) {
        float4 va = reinterpret_cast<float4*>(a)[i];
        float4 vb = reinterpret_cast<const float4*>(b)[i];
        va.x += vb.x; va.y += vb.y; va.z += vb.z; va.w += vb.w;
        reinterpret_cast<float4*>(a)[i] = va;
    }
}

// ---------------------------------------------------------------------------
// CSR build (unchanged — verified dense-writeback design).
// ---------------------------------------------------------------------------
__global__ __launch_bounds__(256) void bhist(const int* __restrict__ dst,
                                             int* __restrict__ btot, int e) {
    __shared__ int h[256];
    const int tid = threadIdx.x;
    h[tid] = 0;
    __syncthreads();
    const int i0 = blockIdx.x * 4096;
#pragma unroll
    for (int k = 0; k < 16; ++k) {
        int j = i0 + k * 256 + tid;
        if (j < e) atomicAdd(&h[dst[j] >> 8], 1);
    }
    __syncthreads();
    if (h[tid]) atomicAdd(&btot[tid], h[tid]);
}

__global__ __launch_bounds__(256) void bscan(const int* __restrict__ btot,
                                             int* __restrict__ bbase,
                                             int* __restrict__ bcursor,
                                             int* __restrict__ rowptr,
                                             int nb, int n, int e) {
    __shared__ int sh[256];
    const int t = threadIdx.x;
    int v = (t < nb) ? btot[t] : 0;
    sh[t] = v;
    __syncthreads();
    for (int off = 1; off < 256; off <<= 1) {
        int x = (t >= off) ? sh[t - off] : 0;
        __syncthreads();
        sh[t] += x;
        __syncthreads();
    }
    int ex = sh[t] - v;
    if (t < nb) {
        bbase[t] = ex;
        bcursor[t] = ex;
    }
    if (t == 0) {
        bbase[nb] = e;
        rowptr[n] = e;
    }
}

__global__ __launch_bounds__(256) void build_a(const int* __restrict__ src,
                                               const int* __restrict__ dst,
                                               const float* __restrict__ w,
                                               int* __restrict__ bcursor,
                                               unsigned long long* __restrict__ rec2,
                                               int e, int nb) {
    __shared__ int cnt[256];
    __shared__ int gb[256];
    const int tid = threadIdx.x;
    const int i0 = blockIdx.x * 4096;
    cnt[tid] = 0;
    __syncthreads();
    unsigned long long rc[16];
    int rkbk[16];
#pragma unroll
    for (int k = 0; k < 16; ++k) {
        int j = i0 + k * 256 + tid;
        rkbk[k] = -1;
        if (j < e) {
            int d = dst[j];
            int b = d >> 8;
            int rk = atomicAdd(&cnt[b], 1);
            rkbk[k] = (rk << 8) | b;
            rc[k] = ((unsigned long long)__float_as_uint(w[j]) << 32) |
                    ((unsigned)d << 16) | (unsigned)src[j];
        }
    }
    __syncthreads();
    if (tid < nb && cnt[tid] > 0) gb[tid] = atomicAdd(&bcursor[tid], cnt[tid]);
    __syncthreads();
#pragma unroll
    for (int k = 0; k < 16; ++k) {
        if (rkbk[k] >= 0) {
            int b = rkbk[k] & 255;
            int rk = rkbk[k] >> 8;
            rec2[gb[b] + rk] = rc[k];
        }
    }
}

__global__ __launch_bounds__(256) void build_b(const unsigned long long* __restrict__ rec2,
                                               const int* __restrict__ bbase,
                                               int* __restrict__ rowptr,
                                               unsigned long long* __restrict__ rec,
                                               int n) {
    __shared__ int cnt[256];
    __shared__ int cur[256];
    const int t = threadIdx.x;
    const int b = blockIdx.x;
    const int lo = bbase[b];
    const int hi = bbase[b + 1];
    cnt[t] = 0;
    __syncthreads();
    for (int i = lo + t; i < hi; i += 256)
        atomicAdd(&cnt[((unsigned)rec2[i] >> 16) & 255], 1);
    __syncthreads();
    int v = cnt[t];
    cur[t] = v;
    __syncthreads();
    for (int off = 1; off < 256; off <<= 1) {
        int x = (t >= off) ? cur[t - off] : 0;
        __syncthreads();
        cur[t] += x;
        __syncthreads();
    }
    int ex = cur[t] - v;
    int node = b * 256 + t;
    if (node < n) rowptr[node] = lo + ex;
    __syncthreads();
    cur[t] = ex;
    __syncthreads();
    for (int i = lo + t; i < hi; i += 256) {
        unsigned long long r = rec2[i];
        unsigned lo32 = (unsigned)r;
        int ln = (lo32 >> 16) & 255;
        int p = atomicAdd(&cur[ln], 1);
        rec[lo + p] = (r & 0xffffffff00000000ull) | (lo32 & 0xffffu);
    }
}

// ---------------------------------------------------------------------------
// CSR aggregation with fused epilogues (unchanged).
// ---------------------------------------------------------------------------
template <int D, int C, int MODE, bool SMAX>
__global__ __launch_bounds__(256) void agg_fused(const float* __restrict__ s,
                                                 const unsigned long long* __restrict__ rec,
                                                 const int* __restrict__ rowptr,
                                                 const float* __restrict__ Wn,
                                                 const float* __restrict__ res,
                                                 float* __restrict__ out0,
                                                 float* __restrict__ out1,
                                                 float* __restrict__ pred, int n) {
    __shared__ float wl[(MODE == 1 || MODE == 3) ? D * C : 1];
    if (MODE == 1 || MODE == 3) {
        for (int i = threadIdx.x; i < D * C; i += 256) wl[i] = Wn[i];
        __syncthreads();
    }
    constexpr int NPB = 256 / D;
    const int node = blockIdx.x * NPB + threadIdx.x / D;
    const int c = threadIdx.x % D;
    float acc = 0.f;
    if (node < n) {
        int i = rowptr[node];
        const int end = rowptr[node + 1];
        for (; i + 1 < end; i += 2) {
            unsigned long long r0 = rec[i];
            unsigned long long r1 = rec[i + 1];
            int s0 = (int)(r0 & 0xffffffffu);
            int s1 = (int)(r1 & 0xffffffffu);
            float w0 = __uint_as_float((unsigned)(r0 >> 32));
            float w1 = __uint_as_float((unsigned)(r1 >> 32));
            float v0 = s[(size_t)s0 * D + c];
            float v1 = s[(size_t)s1 * D + c];
            acc = fmaf(v0, w0, acc);
            acc = fmaf(v1, w1, acc);
        }
        if (i < end) {
            unsigned long long r0 = rec[i];
            int s0 = (int)(r0 & 0xffffffffu);
            float w0 = __uint_as_float((unsigned)(r0 >> 32));
            acc = fmaf(s[(size_t)s0 * D + c], w0, acc);
        }
    }
    if (MODE == 1) {
        float v = tanhf(acc);
        if (node < n) out0[(size_t)node * D + c] = v;
        if (SMAX) {
            float m = v;
#pragma unroll
            for (int mk = 8; mk >= 1; mk >>= 1) m = fmaxf(m, __shfl_xor(m, mk, 16));
            float ev = expf(v - m);
            float sum = ev;
#pragma unroll
            for (int mk = 8; mk >= 1; mk >>= 1) sum += __shfl_xor(sum, mk, 16);
            if (node < n) pred[(size_t)node * 16 + c] = ev / sum;
        }
        int cc = c & (C - 1);
        float g = 0.f;
#pragma unroll
        for (int k = 0; k < D; ++k) g = fmaf(__shfl(v, k, D), wl[k * C + cc], g);
        if (node < n && c < C) out1[(size_t)node * C + c] = g;
    } else if (MODE == 2) {
        if (node < n) out0[(size_t)node * D + c] = tanhf(acc) + res[(size_t)node * D + c];
    } else if (MODE == 3) {
        float g0 = 0.f, g1 = 0.f;
#pragma unroll
        for (int k = 0; k < 16; ++k) {
            float vk = __shfl(acc, k, 16);
            g0 = fmaf(vk, wl[k * 32 + c], g0);
            g1 = fmaf(vk, wl[k * 32 + c + 16], g1);
        }
        if (node < n) {
            out0[(size_t)node * 32 + c] = tanhf(g0) + res[(size_t)node * 32 + c];
            out0[(size_t)node * 32 + c + 16] = tanhf(g1) + res[(size_t)node * 32 + c + 16];
        }
    } else {  // MODE 4
        if (node < n) out0[(size_t)node * D + c] = acc;
    }
}

// ---------------------------------------------------------------------------
// GEMM6: persistent blocks, W6 staged once, 4x4 register tiles (unchanged).
// ---------------------------------------------------------------------------
#define FT_R 32
__global__ __launch_bounds__(256) void gemm_fout(const float* __restrict__ a,
                                                 const float* __restrict__ W,
                                                 float* __restrict__ out, int n,
                                                 int ntiles) {
    __shared__ float wl[NHID * FIN];
    __shared__ float aT[NHID][FT_R + 1];
    {
        const float4* w4 = reinterpret_cast<const float4*>(W);
        float4* wl4 = reinterpret_cast<float4*>(wl);
        for (int i = threadIdx.x; i < NHID * FIN / 4; i += 256) wl4[i] = w4[i];
    }
    const int rt = threadIdx.x >> 5;
    const int ct = threadIdx.x & 31;
    const int srr = threadIdx.x >> 3;
    const int sk4 = threadIdx.x & 7;

    for (int tile = blockIdx.x; tile < ntiles; tile += gridDim.x) {
        const int r0 = tile * FT_R;
        __syncthreads();
        {
            int r = r0 + srr;
            float4 v;
            if (r < n)
                v = *reinterpret_cast<const float4*>(a + (size_t)r * NHID + sk4 * 4);
            else
                v.x = v.y = v.z = v.w = 0.f;
            aT[sk4 * 4 + 0][srr] = v.x;
            aT[sk4 * 4 + 1][srr] = v.y;
            aT[sk4 * 4 + 2][srr] = v.z;
            aT[sk4 * 4 + 3][srr] = v.w;
        }
        __syncthreads();
#pragma unroll
        for (int cc = 0; cc < 4; ++cc) {
            float acc[4][4] = {{0.f}};
#pragma unroll 8
            for (int k = 0; k < NHID; ++k) {
                float4 av = *reinterpret_cast<const float4*>(&aT[k][rt * 4]);
                float4 wv = *reinterpret_cast<const float4*>(&wl[k * FIN + cc * 128 + ct * 4]);
                acc[0][0] = fmaf(av.x, wv.x, acc[0][0]);
                acc[0][1] = fmaf(av.x, wv.y, acc[0][1]);
                acc[0][2] = fmaf(av.x, wv.z, acc[0][2]);
                acc[0][3] = fmaf(av.x, wv.w, acc[0][3]);
                acc[1][0] = fmaf(av.y, wv.x, acc[1][0]);
                acc[1][1] = fmaf(av.y, wv.y, acc[1][1]);
                acc[1][2] = fmaf(av.y, wv.z, acc[1][2]);
                acc[1][3] = fmaf(av.y, wv.w, acc[1][3]);
                acc[2][0] = fmaf(av.z, wv.x, acc[2][0]);
                acc[2][1] = fmaf(av.z, wv.y, acc[2][1]);
                acc[2][2] = fmaf(av.z, wv.z, acc[2][2]);
                acc[2][3] = fmaf(av.z, wv.w, acc[2][3]);
                acc[3][0] = fmaf(av.w, wv.x, acc[3][0]);
                acc[3][1] = fmaf(av.w, wv.y, acc[3][1]);
                acc[3][2] = fmaf(av.w, wv.z, acc[3][2]);
                acc[3][3] = fmaf(av.w, wv.w, acc[3][3]);
            }
#pragma unroll
            for (int i = 0; i < 4; ++i) {
                int r = r0 + rt * 4 + i;
                if (r < n) {
                    float4 o;
                    o.x = 1.f / (1.f + expf(-acc[i][0]));
                    o.y = 1.f / (1.f + expf(-acc[i][1]));
                    o.z = 1.f / (1.f + expf(-acc[i][2]));
                    o.w = 1.f / (1.f + expf(-acc[i][3]));
                    *reinterpret_cast<float4*>(out + (size_t)r * FIN + cc * 128 + ct * 4) = o;
                }
            }
        }
    }
}

extern "C" void kernel_launch(void* const* d_in, const int* in_sizes, int n_in,
                              void* d_out, int out_size, void* d_ws, size_t ws_size,
                              hipStream_t stream) {
    const float* feat = (const float*)d_in[0];
    const int* esrc = (const int*)d_in[1];
    const int* edst = (const int*)d_in[2];
    const float* ewt = (const float*)d_in[3];
    const float* W1 = (const float*)d_in[4];
    const float* W2 = (const float*)d_in[5];
    const float* W3 = (const float*)d_in[6];
    const float* W4 = (const float*)d_in[7];
    const float* W5 = (const float*)d_in[8];
    const float* W6 = (const float*)d_in[9];
    const int n = in_sizes[0] / FIN;
    const int e = in_sizes[1];
    const int nb = (n + 255) >> 8;

    float* out = (float*)d_out;
    float* recon = out;                   // [n,512]
    float* zout = out + (size_t)n * FIN;  // [n,16]
    float* pred = zout + (size_t)n * 16;  // [n,16]

    char* wsb = (char*)d_ws;
    unsigned long long* rec = (unsigned long long*)wsb;  // e * 8B
    int* rowptr = (int*)(wsb + (size_t)e * 8);           // n+1
    int* btot = rowptr + n + 1;                          // 256
    int* bbase = btot + 256;                             // nb+1
    int* bcursor = bbase + nb + 1;                       // nb
    size_t foff = ((size_t)(bcursor + nb - (int*)wsb) + 3) & ~(size_t)3;
    float* S_a = (float*)wsb + foff;    // n*32
    float* S_b = S_a + (size_t)n * 32;  // n*32
    float* X1 = S_b + (size_t)n * 32;   // n*32 (x1)
    float* X2 = X1 + (size_t)n * 32;    // n*16 (x2)
    float* G1 = X2 + (size_t)n * 16;    // n*32 (K-split partial)
    unsigned long long* rec2 = (unsigned long long*)S_a;  // e*8B alias (S_a+S_b)

    const int geb = (e + 4095) / 4096;
    const int gn32 = (n + 7) / 8;
    const int gn16 = (n + 15) / 16;
    const int ntile1 = (n + BR - 1) / BR;
    const int ntiles6 = (n + FT_R - 1) / FT_R;

    // ---- CSR build ----
    hipMemsetAsync(btot, 0, 256 * sizeof(int), stream);
    bhist<<<geb, 256, 0, stream>>>(edst, btot, e);
    bscan<<<1, 256, 0, stream>>>(btot, bbase, bcursor, rowptr, nb, n, e);
    build_a<<<geb, 256, 0, stream>>>(esrc, edst, ewt, bcursor, rec2, e, nb);
    build_b<<<nb, 256, 0, stream>>>(rec2, bbase, rowptr, rec, n);

    // conv1: s1 = feat@W1 (K-split partials -> S_a, G1; add2 -> S_a)
    gemm_fin<<<2 * ntile1, 256, 0, stream>>>(feat, W1, S_a, G1, n, ntile1);
    add2<<<(n * 32 / 4 + 255) / 256, 256, 0, stream>>>(S_a, G1, n * 32 / 4);
    // x1 = tanh(A s1) -> X1 ; s2 = x1@W2 -> S_b
    agg_fused<32, 16, 1, false><<<gn32, 256, 0, stream>>>(S_a, rec, rowptr, W2, nullptr, X1, S_b, nullptr, n);
    // conv2: x2 = tanh(A s2) -> X2 ; s3 = x2@W3 -> S_a
    agg_fused<16, 16, 1, false><<<gn16, 256, 0, stream>>>(S_b, rec, rowptr, W3, nullptr, X2, S_a, nullptr, n);
    // conv3: z = tanh(A s3) -> zout ; pred = softmax(z) ; s4 = z@W4 -> S_b
    agg_fused<16, 16, 1, true><<<gn16, 256, 0, stream>>>(S_a, rec, rowptr, W4, nullptr, zout, S_b, pred, n);
    // conv4: z2 = tanh(A s4) + x2 -> S_a
    agg_fused<16, 16, 2, false><<<gn16, 256, 0, stream>>>(S_b, rec, rowptr, nullptr, X2, S_a, nullptr, nullptr, n);
    // conv5: z1 = tanh((A z2)@W5) + x1 -> S_b
    agg_fused<16, 32, 3, false><<<gn16, 256, 0, stream>>>(S_a, rec, rowptr, W5, X1, S_b, nullptr, nullptr, n);
    // conv6: recon = sigmoid((A z1)@W6)
    agg_fused<32, 32, 4, false><<<gn32, 256, 0, stream>>>(S_b, rec, rowptr, nullptr, nullptr, S_a, nullptr, nullptr, n);
    gemm_fout<<<512, 256, 0, stream>>>(S_a, W6, recon, n, ntiles6);
}

// Round 8
// 351.340 us; speedup vs baseline: 2.7193x; 1.2199x over previous
//
#include <hip/hip_runtime.h>
#include <hip/hip_bf16.h>
#include <math.h>

#define FIN 512
#define NHID 32
#define LAT 16

// ---------------------------------------------------------------------------
// GEMM1: [n,512] @ [512,32] -> [n,32]. K-split x2, XOR-swizzled xT (unchanged).
// ---------------------------------------------------------------------------
#define BR 128
#define KC 64
__global__ __launch_bounds__(256) void gemm_fin(const float* __restrict__ feat,
                                                const float* __restrict__ W,
                                                float* __restrict__ out0,
                                                float* __restrict__ out1,
                                                int n, int ntile) {
    __shared__ float xT[KC][BR];    // 32 KB, swizzled
    __shared__ float Wc[KC][NHID];  // 8 KB
    const int tid = threadIdx.x;
    const int tile = blockIdx.x % ntile;
    const int khalf = blockIdx.x / ntile;
    const int r0 = tile * BR;
    const int k0 = khalf * 256;
    float* __restrict__ out = khalf ? out1 : out0;
    const int rt = tid >> 3;
    const int ct = tid & 7;
    const int srow = tid >> 4;
    const int sc4 = tid & 15;
    float acc[4][4] = {{0.f}};

    for (int kc = 0; kc < 256; kc += KC) {
        {
            const float4* wg = reinterpret_cast<const float4*>(W + (k0 + kc) * NHID);
            float4* wl = reinterpret_cast<float4*>(&Wc[0][0]);
            wl[tid] = wg[tid];
            wl[tid + 256] = wg[tid + 256];
        }
#pragma unroll
        for (int i = 0; i < 8; ++i) {
            int rr = srow + 16 * i;
            int r = r0 + rr;
            float4 v;
            if (r < n)
                v = *reinterpret_cast<const float4*>(feat + (size_t)r * FIN + k0 + kc + sc4 * 4);
            else
                v.x = v.y = v.z = v.w = 0.f;
            int gs = ((rr >> 2) ^ (sc4 & 7)) * 4 + (rr & 3);
            xT[sc4 * 4 + 0][gs] = v.x;
            xT[sc4 * 4 + 1][gs] = v.y;
            xT[sc4 * 4 + 2][gs] = v.z;
            xT[sc4 * 4 + 3][gs] = v.w;
        }
        __syncthreads();
#pragma unroll 4
        for (int k = 0; k < KC; ++k) {
            int sw = (rt ^ ((k >> 2) & 7)) * 4;
            float4 xv = *reinterpret_cast<const float4*>(&xT[k][sw]);
            float4 wv = *reinterpret_cast<const float4*>(&Wc[k][ct * 4]);
            acc[0][0] = fmaf(xv.x, wv.x, acc[0][0]);
            acc[0][1] = fmaf(xv.x, wv.y, acc[0][1]);
            acc[0][2] = fmaf(xv.x, wv.z, acc[0][2]);
            acc[0][3] = fmaf(xv.x, wv.w, acc[0][3]);
            acc[1][0] = fmaf(xv.y, wv.x, acc[1][0]);
            acc[1][1] = fmaf(xv.y, wv.y, acc[1][1]);
            acc[1][2] = fmaf(xv.y, wv.z, acc[1][2]);
            acc[1][3] = fmaf(xv.y, wv.w, acc[1][3]);
            acc[2][0] = fmaf(xv.z, wv.x, acc[2][0]);
            acc[2][1] = fmaf(xv.z, wv.y, acc[2][1]);
            acc[2][2] = fmaf(xv.z, wv.z, acc[2][2]);
            acc[2][3] = fmaf(xv.z, wv.w, acc[2][3]);
            acc[3][0] = fmaf(xv.w, wv.x, acc[3][0]);
            acc[3][1] = fmaf(xv.w, wv.y, acc[3][1]);
            acc[3][2] = fmaf(xv.w, wv.z, acc[3][2]);
            acc[3][3] = fmaf(xv.w, wv.w, acc[3][3]);
        }
        __syncthreads();
    }
#pragma unroll
    for (int i = 0; i < 4; ++i) {
        int r = r0 + rt * 4 + i;
        if (r < n) {
            float4 o;
            o.x = acc[i][0]; o.y = acc[i][1]; o.z = acc[i][2]; o.w = acc[i][3];
            *reinterpret_cast<float4*>(out + (size_t)r * NHID + ct * 4) = o;
        }
    }
}

// a += b (float4), for the K-split reduction.
__global__ __launch_bounds__(256) void add2(float* __restrict__ a,
                                            const float* __restrict__ b, int n4) {
    int i = blockIdx.x * 256 + threadIdx.x;
    if (i < n4) {
        float4 va = reinterpret_cast<float4*>(a)[i];
        float4 vb = reinterpret_cast<const float4*>(b)[i];
        va.x += vb.x; va.y += vb.y; va.z += vb.z; va.w += vb.w;
        reinterpret_cast<float4*>(a)[i] = va;
    }
}

// ---------------------------------------------------------------------------
// CSR build (unchanged — verified dense-writeback design).
// ---------------------------------------------------------------------------
__global__ __launch_bounds__(256) void bhist(const int* __restrict__ dst,
                                             int* __restrict__ btot, int e) {
    __shared__ int h[256];
    const int tid = threadIdx.x;
    h[tid] = 0;
    __syncthreads();
    const int i0 = blockIdx.x * 4096;
#pragma unroll
    for (int k = 0; k < 16; ++k) {
        int j = i0 + k * 256 + tid;
        if (j < e) atomicAdd(&h[dst[j] >> 8], 1);
    }
    __syncthreads();
    if (h[tid]) atomicAdd(&btot[tid], h[tid]);
}

__global__ __launch_bounds__(256) void bscan(const int* __restrict__ btot,
                                             int* __restrict__ bbase,
                                             int* __restrict__ bcursor,
                                             int* __restrict__ rowptr,
                                             int nb, int n, int e) {
    __shared__ int sh[256];
    const int t = threadIdx.x;
    int v = (t < nb) ? btot[t] : 0;
    sh[t] = v;
    __syncthreads();
    for (int off = 1; off < 256; off <<= 1) {
        int x = (t >= off) ? sh[t - off] : 0;
        __syncthreads();
        sh[t] += x;
        __syncthreads();
    }
    int ex = sh[t] - v;
    if (t < nb) {
        bbase[t] = ex;
        bcursor[t] = ex;
    }
    if (t == 0) {
        bbase[nb] = e;
        rowptr[n] = e;
    }
}

__global__ __launch_bounds__(256) void build_a(const int* __restrict__ src,
                                               const int* __restrict__ dst,
                                               const float* __restrict__ w,
                                               int* __restrict__ bcursor,
                                               unsigned long long* __restrict__ rec2,
                                               int e, int nb) {
    __shared__ int cnt[256];
    __shared__ int gb[256];
    const int tid = threadIdx.x;
    const int i0 = blockIdx.x * 4096;
    cnt[tid] = 0;
    __syncthreads();
    unsigned long long rc[16];
    int rkbk[16];
#pragma unroll
    for (int k = 0; k < 16; ++k) {
        int j = i0 + k * 256 + tid;
        rkbk[k] = -1;
        if (j < e) {
            int d = dst[j];
            int b = d >> 8;
            int rk = atomicAdd(&cnt[b], 1);
            rkbk[k] = (rk << 8) | b;
            rc[k] = ((unsigned long long)__float_as_uint(w[j]) << 32) |
                    ((unsigned)d << 16) | (unsigned)src[j];
        }
    }
    __syncthreads();
    if (tid < nb && cnt[tid] > 0) gb[tid] = atomicAdd(&bcursor[tid], cnt[tid]);
    __syncthreads();
#pragma unroll
    for (int k = 0; k < 16; ++k) {
        if (rkbk[k] >= 0) {
            int b = rkbk[k] & 255;
            int rk = rkbk[k] >> 8;
            rec2[gb[b] + rk] = rc[k];
        }
    }
}

__global__ __launch_bounds__(256) void build_b(const unsigned long long* __restrict__ rec2,
                                               const int* __restrict__ bbase,
                                               int* __restrict__ rowptr,
                                               unsigned long long* __restrict__ rec,
                                               int n) {
    __shared__ int cnt[256];
    __shared__ int cur[256];
    const int t = threadIdx.x;
    const int b = blockIdx.x;
    const int lo = bbase[b];
    const int hi = bbase[b + 1];
    cnt[t] = 0;
    __syncthreads();
    for (int i = lo + t; i < hi; i += 256)
        atomicAdd(&cnt[((unsigned)rec2[i] >> 16) & 255], 1);
    __syncthreads();
    int v = cnt[t];
    cur[t] = v;
    __syncthreads();
    for (int off = 1; off < 256; off <<= 1) {
        int x = (t >= off) ? cur[t - off] : 0;
        __syncthreads();
        cur[t] += x;
        __syncthreads();
    }
    int ex = cur[t] - v;
    int node = b * 256 + t;
    if (node < n) rowptr[node] = lo + ex;
    __syncthreads();
    cur[t] = ex;
    __syncthreads();
    for (int i = lo + t; i < hi; i += 256) {
        unsigned long long r = rec2[i];
        unsigned lo32 = (unsigned)r;
        int ln = (lo32 >> 16) & 255;
        int p = atomicAdd(&cur[ln], 1);
        rec[lo + p] = (r & 0xffffffff00000000ull) | (lo32 & 0xffffu);
    }
}

// ---------------------------------------------------------------------------
// CSR aggregation, fused epilogues. Edge loop unrolled x8: 8 independent rec
// loads (one L2 line) then 8 independent gathers in flight (was 2) — the
// aggs were gather-LATENCY-bound (VALUBusy 23%, 1.7 TB/s fill).
// ---------------------------------------------------------------------------
template <int D, int C, int MODE, bool SMAX>
__global__ __launch_bounds__(256) void agg_fused(const float* __restrict__ s,
                                                 const unsigned long long* __restrict__ rec,
                                                 const int* __restrict__ rowptr,
                                                 const float* __restrict__ Wn,
                                                 const float* __restrict__ res,
                                                 float* __restrict__ out0,
                                                 float* __restrict__ out1,
                                                 float* __restrict__ pred, int n) {
    __shared__ float wl[(MODE == 1 || MODE == 3) ? D * C : 1];
    if (MODE == 1 || MODE == 3) {
        for (int i = threadIdx.x; i < D * C; i += 256) wl[i] = Wn[i];
        __syncthreads();
    }
    constexpr int NPB = 256 / D;
    const int node = blockIdx.x * NPB + threadIdx.x / D;
    const int c = threadIdx.x % D;
    float acc = 0.f;
    if (node < n) {
        int i = rowptr[node];
        const int end = rowptr[node + 1];
        for (; i + 8 <= end; i += 8) {
            unsigned long long r0 = rec[i + 0];
            unsigned long long r1 = rec[i + 1];
            unsigned long long r2 = rec[i + 2];
            unsigned long long r3 = rec[i + 3];
            unsigned long long r4 = rec[i + 4];
            unsigned long long r5 = rec[i + 5];
            unsigned long long r6 = rec[i + 6];
            unsigned long long r7 = rec[i + 7];
            float v0 = s[(size_t)(unsigned)(r0 & 0xffffffffu) * D + c];
            float v1 = s[(size_t)(unsigned)(r1 & 0xffffffffu) * D + c];
            float v2 = s[(size_t)(unsigned)(r2 & 0xffffffffu) * D + c];
            float v3 = s[(size_t)(unsigned)(r3 & 0xffffffffu) * D + c];
            float v4 = s[(size_t)(unsigned)(r4 & 0xffffffffu) * D + c];
            float v5 = s[(size_t)(unsigned)(r5 & 0xffffffffu) * D + c];
            float v6 = s[(size_t)(unsigned)(r6 & 0xffffffffu) * D + c];
            float v7 = s[(size_t)(unsigned)(r7 & 0xffffffffu) * D + c];
            acc = fmaf(v0, __uint_as_float((unsigned)(r0 >> 32)), acc);
            acc = fmaf(v1, __uint_as_float((unsigned)(r1 >> 32)), acc);
            acc = fmaf(v2, __uint_as_float((unsigned)(r2 >> 32)), acc);
            acc = fmaf(v3, __uint_as_float((unsigned)(r3 >> 32)), acc);
            acc = fmaf(v4, __uint_as_float((unsigned)(r4 >> 32)), acc);
            acc = fmaf(v5, __uint_as_float((unsigned)(r5 >> 32)), acc);
            acc = fmaf(v6, __uint_as_float((unsigned)(r6 >> 32)), acc);
            acc = fmaf(v7, __uint_as_float((unsigned)(r7 >> 32)), acc);
        }
        for (; i + 1 < end; i += 2) {
            unsigned long long r0 = rec[i];
            unsigned long long r1 = rec[i + 1];
            float v0 = s[(size_t)(unsigned)(r0 & 0xffffffffu) * D + c];
            float v1 = s[(size_t)(unsigned)(r1 & 0xffffffffu) * D + c];
            acc = fmaf(v0, __uint_as_float((unsigned)(r0 >> 32)), acc);
            acc = fmaf(v1, __uint_as_float((unsigned)(r1 >> 32)), acc);
        }
        if (i < end) {
            unsigned long long r0 = rec[i];
            acc = fmaf(s[(size_t)(unsigned)(r0 & 0xffffffffu) * D + c],
                       __uint_as_float((unsigned)(r0 >> 32)), acc);
        }
    }
    if (MODE == 1) {
        float v = tanhf(acc);
        if (node < n) out0[(size_t)node * D + c] = v;
        if (SMAX) {
            float m = v;
#pragma unroll
            for (int mk = 8; mk >= 1; mk >>= 1) m = fmaxf(m, __shfl_xor(m, mk, 16));
            float ev = expf(v - m);
            float sum = ev;
#pragma unroll
            for (int mk = 8; mk >= 1; mk >>= 1) sum += __shfl_xor(sum, mk, 16);
            if (node < n) pred[(size_t)node * 16 + c] = ev / sum;
        }
        int cc = c & (C - 1);
        float g = 0.f;
#pragma unroll
        for (int k = 0; k < D; ++k) g = fmaf(__shfl(v, k, D), wl[k * C + cc], g);
        if (node < n && c < C) out1[(size_t)node * C + c] = g;
    } else if (MODE == 2) {
        if (node < n) out0[(size_t)node * D + c] = tanhf(acc) + res[(size_t)node * D + c];
    } else if (MODE == 3) {
        float g0 = 0.f, g1 = 0.f;
#pragma unroll
        for (int k = 0; k < 16; ++k) {
            float vk = __shfl(acc, k, 16);
            g0 = fmaf(vk, wl[k * 32 + c], g0);
            g1 = fmaf(vk, wl[k * 32 + c + 16], g1);
        }
        if (node < n) {
            out0[(size_t)node * 32 + c] = tanhf(g0) + res[(size_t)node * 32 + c];
            out0[(size_t)node * 32 + c + 16] = tanhf(g1) + res[(size_t)node * 32 + c + 16];
        }
    } else {  // MODE 4
        if (node < n) out0[(size_t)node * D + c] = acc;
    }
}

// ---------------------------------------------------------------------------
// GEMM6: persistent blocks, W6 staged once, 4x4 register tiles (unchanged).
// ---------------------------------------------------------------------------
#define FT_R 32
__global__ __launch_bounds__(256) void gemm_fout(const float* __restrict__ a,
                                                 const float* __restrict__ W,
                                                 float* __restrict__ out, int n,
                                                 int ntiles) {
    __shared__ float wl[NHID * FIN];
    __shared__ float aT[NHID][FT_R + 1];
    {
        const float4* w4 = reinterpret_cast<const float4*>(W);
        float4* wl4 = reinterpret_cast<float4*>(wl);
        for (int i = threadIdx.x; i < NHID * FIN / 4; i += 256) wl4[i] = w4[i];
    }
    const int rt = threadIdx.x >> 5;
    const int ct = threadIdx.x & 31;
    const int srr = threadIdx.x >> 3;
    const int sk4 = threadIdx.x & 7;

    for (int tile = blockIdx.x; tile < ntiles; tile += gridDim.x) {
        const int r0 = tile * FT_R;
        __syncthreads();
        {
            int r = r0 + srr;
            float4 v;
            if (r < n)
                v = *reinterpret_cast<const float4*>(a + (size_t)r * NHID + sk4 * 4);
            else
                v.x = v.y = v.z = v.w = 0.f;
            aT[sk4 * 4 + 0][srr] = v.x;
            aT[sk4 * 4 + 1][srr] = v.y;
            aT[sk4 * 4 + 2][srr] = v.z;
            aT[sk4 * 4 + 3][srr] = v.w;
        }
        __syncthreads();
#pragma unroll
        for (int cc = 0; cc < 4; ++cc) {
            float acc[4][4] = {{0.f}};
#pragma unroll 8
            for (int k = 0; k < NHID; ++k) {
                float4 av = *reinterpret_cast<const float4*>(&aT[k][rt * 4]);
                float4 wv = *reinterpret_cast<const float4*>(&wl[k * FIN + cc * 128 + ct * 4]);
                acc[0][0] = fmaf(av.x, wv.x, acc[0][0]);
                acc[0][1] = fmaf(av.x, wv.y, acc[0][1]);
                acc[0][2] = fmaf(av.x, wv.z, acc[0][2]);
                acc[0][3] = fmaf(av.x, wv.w, acc[0][3]);
                acc[1][0] = fmaf(av.y, wv.x, acc[1][0]);
                acc[1][1] = fmaf(av.y, wv.y, acc[1][1]);
                acc[1][2] = fmaf(av.y, wv.z, acc[1][2]);
                acc[1][3] = fmaf(av.y, wv.w, acc[1][3]);
                acc[2][0] = fmaf(av.z, wv.x, acc[2][0]);
                acc[2][1] = fmaf(av.z, wv.y, acc[2][1]);
                acc[2][2] = fmaf(av.z, wv.z, acc[2][2]);
                acc[2][3] = fmaf(av.z, wv.w, acc[2][3]);
                acc[3][0] = fmaf(av.w, wv.x, acc[3][0]);
                acc[3][1] = fmaf(av.w, wv.y, acc[3][1]);
                acc[3][2] = fmaf(av.w, wv.z, acc[3][2]);
                acc[3][3] = fmaf(av.w, wv.w, acc[3][3]);
            }
#pragma unroll
            for (int i = 0; i < 4; ++i) {
                int r = r0 + rt * 4 + i;
                if (r < n) {
                    float4 o;
                    o.x = 1.f / (1.f + expf(-acc[i][0]));
                    o.y = 1.f / (1.f + expf(-acc[i][1]));
                    o.z = 1.f / (1.f + expf(-acc[i][2]));
                    o.w = 1.f / (1.f + expf(-acc[i][3]));
                    *reinterpret_cast<float4*>(out + (size_t)r * FIN + cc * 128 + ct * 4) = o;
                }
            }
        }
    }
}

extern "C" void kernel_launch(void* const* d_in, const int* in_sizes, int n_in,
                              void* d_out, int out_size, void* d_ws, size_t ws_size,
                              hipStream_t stream) {
    const float* feat = (const float*)d_in[0];
    const int* esrc = (const int*)d_in[1];
    const int* edst = (const int*)d_in[2];
    const float* ewt = (const float*)d_in[3];
    const float* W1 = (const float*)d_in[4];
    const float* W2 = (const float*)d_in[5];
    const float* W3 = (const float*)d_in[6];
    const float* W4 = (const float*)d_in[7];
    const float* W5 = (const float*)d_in[8];
    const float* W6 = (const float*)d_in[9];
    const int n = in_sizes[0] / FIN;
    const int e = in_sizes[1];
    const int nb = (n + 255) >> 8;

    float* out = (float*)d_out;
    float* recon = out;                   // [n,512]
    float* zout = out + (size_t)n * FIN;  // [n,16]
    float* pred = zout + (size_t)n * 16;  // [n,16]

    char* wsb = (char*)d_ws;
    unsigned long long* rec = (unsigned long long*)wsb;  // e * 8B
    int* rowptr = (int*)(wsb + (size_t)e * 8);           // n+1
    int* btot = rowptr + n + 1;                          // 256
    int* bbase = btot + 256;                             // nb+1
    int* bcursor = bbase + nb + 1;                       // nb
    size_t foff = ((size_t)(bcursor + nb - (int*)wsb) + 3) & ~(size_t)3;
    float* S_a = (float*)wsb + foff;    // n*32
    float* S_b = S_a + (size_t)n * 32;  // n*32
    float* X1 = S_b + (size_t)n * 32;   // n*32 (x1)
    float* X2 = X1 + (size_t)n * 32;    // n*16 (x2)
    float* G1 = X2 + (size_t)n * 16;    // n*32 (K-split partial)
    unsigned long long* rec2 = (unsigned long long*)S_a;  // e*8B alias (S_a+S_b)

    const int geb = (e + 4095) / 4096;
    const int gn32 = (n + 7) / 8;
    const int gn16 = (n + 15) / 16;
    const int ntile1 = (n + BR - 1) / BR;
    const int ntiles6 = (n + FT_R - 1) / FT_R;

    // ---- CSR build ----
    hipMemsetAsync(btot, 0, 256 * sizeof(int), stream);
    bhist<<<geb, 256, 0, stream>>>(edst, btot, e);
    bscan<<<1, 256, 0, stream>>>(btot, bbase, bcursor, rowptr, nb, n, e);
    build_a<<<geb, 256, 0, stream>>>(esrc, edst, ewt, bcursor, rec2, e, nb);
    build_b<<<nb, 256, 0, stream>>>(rec2, bbase, rowptr, rec, n);

    // conv1: s1 = feat@W1 (K-split partials -> S_a, G1; add2 -> S_a)
    gemm_fin<<<2 * ntile1, 256, 0, stream>>>(feat, W1, S_a, G1, n, ntile1);
    add2<<<(n * 32 / 4 + 255) / 256, 256, 0, stream>>>(S_a, G1, n * 32 / 4);
    // x1 = tanh(A s1) -> X1 ; s2 = x1@W2 -> S_b
    agg_fused<32, 16, 1, false><<<gn32, 256, 0, stream>>>(S_a, rec, rowptr, W2, nullptr, X1, S_b, nullptr, n);
    // conv2: x2 = tanh(A s2) -> X2 ; s3 = x2@W3 -> S_a
    agg_fused<16, 16, 1, false><<<gn16, 256, 0, stream>>>(S_b, rec, rowptr, W3, nullptr, X2, S_a, nullptr, n);
    // conv3: z = tanh(A s3) -> zout ; pred = softmax(z) ; s4 = z@W4 -> S_b
    agg_fused<16, 16, 1, true><<<gn16, 256, 0, stream>>>(S_a, rec, rowptr, W4, nullptr, zout, S_b, pred, n);
    // conv4: z2 = tanh(A s4) + x2 -> S_a
    agg_fused<16, 16, 2, false><<<gn16, 256, 0, stream>>>(S_b, rec, rowptr, nullptr, X2, S_a, nullptr, nullptr, n);
    // conv5: z1 = tanh((A z2)@W5) + x1 -> S_b
    agg_fused<16, 32, 3, false><<<gn16, 256, 0, stream>>>(S_a, rec, rowptr, W5, X1, S_b, nullptr, nullptr, n);
    // conv6: recon = sigmoid((A z1)@W6)
    agg_fused<32, 32, 4, false><<<gn32, 256, 0, stream>>>(S_b, rec, rowptr, nullptr, nullptr, S_a, nullptr, nullptr, n);
    gemm_fout<<<512, 256, 0, stream>>>(S_a, W6, recon, n, ntiles6);
}

// Round 9
// 342.747 us; speedup vs baseline: 2.7875x; 1.0251x over previous
//
#include <hip/hip_runtime.h>
#include <hip/hip_bf16.h>
#include <math.h>

#define FIN 512
#define NHID 32
#define LAT 16

// ---------------------------------------------------------------------------
// GEMM1: [n,512] @ [512,32] -> [n,32]. K-split x2, XOR-swizzled xT (unchanged).
// ---------------------------------------------------------------------------
#define BR 128
#define KC 64
__global__ __launch_bounds__(256) void gemm_fin(const float* __restrict__ feat,
                                                const float* __restrict__ W,
                                                float* __restrict__ out0,
                                                float* __restrict__ out1,
                                                int n, int ntile) {
    __shared__ float xT[KC][BR];    // 32 KB, swizzled
    __shared__ float Wc[KC][NHID];  // 8 KB
    const int tid = threadIdx.x;
    const int tile = blockIdx.x % ntile;
    const int khalf = blockIdx.x / ntile;
    const int r0 = tile * BR;
    const int k0 = khalf * 256;
    float* __restrict__ out = khalf ? out1 : out0;
    const int rt = tid >> 3;
    const int ct = tid & 7;
    const int srow = tid >> 4;
    const int sc4 = tid & 15;
    float acc[4][4] = {{0.f}};

    for (int kc = 0; kc < 256; kc += KC) {
        {
            const float4* wg = reinterpret_cast<const float4*>(W + (k0 + kc) * NHID);
            float4* wl = reinterpret_cast<float4*>(&Wc[0][0]);
            wl[tid] = wg[tid];
            wl[tid + 256] = wg[tid + 256];
        }
#pragma unroll
        for (int i = 0; i < 8; ++i) {
            int rr = srow + 16 * i;
            int r = r0 + rr;
            float4 v;
            if (r < n)
                v = *reinterpret_cast<const float4*>(feat + (size_t)r * FIN + k0 + kc + sc4 * 4);
            else
                v.x = v.y = v.z = v.w = 0.f;
            int gs = ((rr >> 2) ^ (sc4 & 7)) * 4 + (rr & 3);
            xT[sc4 * 4 + 0][gs] = v.x;
            xT[sc4 * 4 + 1][gs] = v.y;
            xT[sc4 * 4 + 2][gs] = v.z;
            xT[sc4 * 4 + 3][gs] = v.w;
        }
        __syncthreads();
#pragma unroll 4
        for (int k = 0; k < KC; ++k) {
            int sw = (rt ^ ((k >> 2) & 7)) * 4;
            float4 xv = *reinterpret_cast<const float4*>(&xT[k][sw]);
            float4 wv = *reinterpret_cast<const float4*>(&Wc[k][ct * 4]);
            acc[0][0] = fmaf(xv.x, wv.x, acc[0][0]);
            acc[0][1] = fmaf(xv.x, wv.y, acc[0][1]);
            acc[0][2] = fmaf(xv.x, wv.z, acc[0][2]);
            acc[0][3] = fmaf(xv.x, wv.w, acc[0][3]);
            acc[1][0] = fmaf(xv.y, wv.x, acc[1][0]);
            acc[1][1] = fmaf(xv.y, wv.y, acc[1][1]);
            acc[1][2] = fmaf(xv.y, wv.z, acc[1][2]);
            acc[1][3] = fmaf(xv.y, wv.w, acc[1][3]);
            acc[2][0] = fmaf(xv.z, wv.x, acc[2][0]);
            acc[2][1] = fmaf(xv.z, wv.y, acc[2][1]);
            acc[2][2] = fmaf(xv.z, wv.z, acc[2][2]);
            acc[2][3] = fmaf(xv.z, wv.w, acc[2][3]);
            acc[3][0] = fmaf(xv.w, wv.x, acc[3][0]);
            acc[3][1] = fmaf(xv.w, wv.y, acc[3][1]);
            acc[3][2] = fmaf(xv.w, wv.z, acc[3][2]);
            acc[3][3] = fmaf(xv.w, wv.w, acc[3][3]);
        }
        __syncthreads();
    }
#pragma unroll
    for (int i = 0; i < 4; ++i) {
        int r = r0 + rt * 4 + i;
        if (r < n) {
            float4 o;
            o.x = acc[i][0]; o.y = acc[i][1]; o.z = acc[i][2]; o.w = acc[i][3];
            *reinterpret_cast<float4*>(out + (size_t)r * NHID + ct * 4) = o;
        }
    }
}

// a += b (float4), for the K-split reduction.
__global__ __launch_bounds__(256) void add2(float* __restrict__ a,
                                            const float* __restrict__ b, int n4) {
    int i = blockIdx.x * 256 + threadIdx.x;
    if (i < n4) {
        float4 va = reinterpret_cast<float4*>(a)[i];
        float4 vb = reinterpret_cast<const float4*>(b)[i];
        va.x += vb.x; va.y += vb.y; va.z += vb.z; va.w += vb.w;
        reinterpret_cast<float4*>(a)[i] = va;
    }
}

// ---------------------------------------------------------------------------
// CSR build (unchanged — verified dense-writeback design).
// ---------------------------------------------------------------------------
__global__ __launch_bounds__(256) void bhist(const int* __restrict__ dst,
                                             int* __restrict__ btot, int e) {
    __shared__ int h[256];
    const int tid = threadIdx.x;
    h[tid] = 0;
    __syncthreads();
    const int i0 = blockIdx.x * 4096;
#pragma unroll
    for (int k = 0; k < 16; ++k) {
        int j = i0 + k * 256 + tid;
        if (j < e) atomicAdd(&h[dst[j] >> 8], 1);
    }
    __syncthreads();
    if (h[tid]) atomicAdd(&btot[tid], h[tid]);
}

__global__ __launch_bounds__(256) void bscan(const int* __restrict__ btot,
                                             int* __restrict__ bbase,
                                             int* __restrict__ bcursor,
                                             int* __restrict__ rowptr,
                                             int nb, int n, int e) {
    __shared__ int sh[256];
    const int t = threadIdx.x;
    int v = (t < nb) ? btot[t] : 0;
    sh[t] = v;
    __syncthreads();
    for (int off = 1; off < 256; off <<= 1) {
        int x = (t >= off) ? sh[t - off] : 0;
        __syncthreads();
        sh[t] += x;
        __syncthreads();
    }
    int ex = sh[t] - v;
    if (t < nb) {
        bbase[t] = ex;
        bcursor[t] = ex;
    }
    if (t == 0) {
        bbase[nb] = e;
        rowptr[n] = e;
    }
}

__global__ __launch_bounds__(256) void build_a(const int* __restrict__ src,
                                               const int* __restrict__ dst,
                                               const float* __restrict__ w,
                                               int* __restrict__ bcursor,
                                               unsigned long long* __restrict__ rec2,
                                               int e, int nb) {
    __shared__ int cnt[256];
    __shared__ int gb[256];
    const int tid = threadIdx.x;
    const int i0 = blockIdx.x * 4096;
    cnt[tid] = 0;
    __syncthreads();
    unsigned long long rc[16];
    int rkbk[16];
#pragma unroll
    for (int k = 0; k < 16; ++k) {
        int j = i0 + k * 256 + tid;
        rkbk[k] = -1;
        if (j < e) {
            int d = dst[j];
            int b = d >> 8;
            int rk = atomicAdd(&cnt[b], 1);
            rkbk[k] = (rk << 8) | b;
            rc[k] = ((unsigned long long)__float_as_uint(w[j]) << 32) |
                    ((unsigned)d << 16) | (unsigned)src[j];
        }
    }
    __syncthreads();
    if (tid < nb && cnt[tid] > 0) gb[tid] = atomicAdd(&bcursor[tid], cnt[tid]);
    __syncthreads();
#pragma unroll
    for (int k = 0; k < 16; ++k) {
        if (rkbk[k] >= 0) {
            int b = rkbk[k] & 255;
            int rk = rkbk[k] >> 8;
            rec2[gb[b] + rk] = rc[k];
        }
    }
}

__global__ __launch_bounds__(256) void build_b(const unsigned long long* __restrict__ rec2,
                                               const int* __restrict__ bbase,
                                               int* __restrict__ rowptr,
                                               unsigned long long* __restrict__ rec,
                                               int n) {
    __shared__ int cnt[256];
    __shared__ int cur[256];
    const int t = threadIdx.x;
    const int b = blockIdx.x;
    const int lo = bbase[b];
    const int hi = bbase[b + 1];
    cnt[t] = 0;
    __syncthreads();
    for (int i = lo + t; i < hi; i += 256)
        atomicAdd(&cnt[((unsigned)rec2[i] >> 16) & 255], 1);
    __syncthreads();
    int v = cnt[t];
    cur[t] = v;
    __syncthreads();
    for (int off = 1; off < 256; off <<= 1) {
        int x = (t >= off) ? cur[t - off] : 0;
        __syncthreads();
        cur[t] += x;
        __syncthreads();
    }
    int ex = cur[t] - v;
    int node = b * 256 + t;
    if (node < n) rowptr[node] = lo + ex;
    __syncthreads();
    cur[t] = ex;
    __syncthreads();
    for (int i = lo + t; i < hi; i += 256) {
        unsigned long long r = rec2[i];
        unsigned lo32 = (unsigned)r;
        int ln = (lo32 >> 16) & 255;
        int p = atomicAdd(&cur[ln], 1);
        rec[lo + p] = (r & 0xffffffff00000000ull) | (lo32 & 0xffffu);
    }
}

// ---------------------------------------------------------------------------
// CSR aggregation, fused epilogues, 8x-unrolled gather loop (unchanged).
// ---------------------------------------------------------------------------
template <int D, int C, int MODE, bool SMAX>
__global__ __launch_bounds__(256) void agg_fused(const float* __restrict__ s,
                                                 const unsigned long long* __restrict__ rec,
                                                 const int* __restrict__ rowptr,
                                                 const float* __restrict__ Wn,
                                                 const float* __restrict__ res,
                                                 float* __restrict__ out0,
                                                 float* __restrict__ out1,
                                                 float* __restrict__ pred, int n) {
    __shared__ float wl[(MODE == 1 || MODE == 3) ? D * C : 1];
    if (MODE == 1 || MODE == 3) {
        for (int i = threadIdx.x; i < D * C; i += 256) wl[i] = Wn[i];
        __syncthreads();
    }
    constexpr int NPB = 256 / D;
    const int node = blockIdx.x * NPB + threadIdx.x / D;
    const int c = threadIdx.x % D;
    float acc = 0.f;
    if (node < n) {
        int i = rowptr[node];
        const int end = rowptr[node + 1];
        for (; i + 8 <= end; i += 8) {
            unsigned long long r0 = rec[i + 0];
            unsigned long long r1 = rec[i + 1];
            unsigned long long r2 = rec[i + 2];
            unsigned long long r3 = rec[i + 3];
            unsigned long long r4 = rec[i + 4];
            unsigned long long r5 = rec[i + 5];
            unsigned long long r6 = rec[i + 6];
            unsigned long long r7 = rec[i + 7];
            float v0 = s[(size_t)(unsigned)(r0 & 0xffffffffu) * D + c];
            float v1 = s[(size_t)(unsigned)(r1 & 0xffffffffu) * D + c];
            float v2 = s[(size_t)(unsigned)(r2 & 0xffffffffu) * D + c];
            float v3 = s[(size_t)(unsigned)(r3 & 0xffffffffu) * D + c];
            float v4 = s[(size_t)(unsigned)(r4 & 0xffffffffu) * D + c];
            float v5 = s[(size_t)(unsigned)(r5 & 0xffffffffu) * D + c];
            float v6 = s[(size_t)(unsigned)(r6 & 0xffffffffu) * D + c];
            float v7 = s[(size_t)(unsigned)(r7 & 0xffffffffu) * D + c];
            acc = fmaf(v0, __uint_as_float((unsigned)(r0 >> 32)), acc);
            acc = fmaf(v1, __uint_as_float((unsigned)(r1 >> 32)), acc);
            acc = fmaf(v2, __uint_as_float((unsigned)(r2 >> 32)), acc);
            acc = fmaf(v3, __uint_as_float((unsigned)(r3 >> 32)), acc);
            acc = fmaf(v4, __uint_as_float((unsigned)(r4 >> 32)), acc);
            acc = fmaf(v5, __uint_as_float((unsigned)(r5 >> 32)), acc);
            acc = fmaf(v6, __uint_as_float((unsigned)(r6 >> 32)), acc);
            acc = fmaf(v7, __uint_as_float((unsigned)(r7 >> 32)), acc);
        }
        for (; i + 1 < end; i += 2) {
            unsigned long long r0 = rec[i];
            unsigned long long r1 = rec[i + 1];
            float v0 = s[(size_t)(unsigned)(r0 & 0xffffffffu) * D + c];
            float v1 = s[(size_t)(unsigned)(r1 & 0xffffffffu) * D + c];
            acc = fmaf(v0, __uint_as_float((unsigned)(r0 >> 32)), acc);
            acc = fmaf(v1, __uint_as_float((unsigned)(r1 >> 32)), acc);
        }
        if (i < end) {
            unsigned long long r0 = rec[i];
            acc = fmaf(s[(size_t)(unsigned)(r0 & 0xffffffffu) * D + c],
                       __uint_as_float((unsigned)(r0 >> 32)), acc);
        }
    }
    if (MODE == 1) {
        float v = tanhf(acc);
        if (node < n) out0[(size_t)node * D + c] = v;
        if (SMAX) {
            float m = v;
#pragma unroll
            for (int mk = 8; mk >= 1; mk >>= 1) m = fmaxf(m, __shfl_xor(m, mk, 16));
            float ev = expf(v - m);
            float sum = ev;
#pragma unroll
            for (int mk = 8; mk >= 1; mk >>= 1) sum += __shfl_xor(sum, mk, 16);
            if (node < n) pred[(size_t)node * 16 + c] = ev / sum;
        }
        int cc = c & (C - 1);
        float g = 0.f;
#pragma unroll
        for (int k = 0; k < D; ++k) g = fmaf(__shfl(v, k, D), wl[k * C + cc], g);
        if (node < n && c < C) out1[(size_t)node * C + c] = g;
    } else if (MODE == 2) {
        if (node < n) out0[(size_t)node * D + c] = tanhf(acc) + res[(size_t)node * D + c];
    } else if (MODE == 3) {
        float g0 = 0.f, g1 = 0.f;
#pragma unroll
        for (int k = 0; k < 16; ++k) {
            float vk = __shfl(acc, k, 16);
            g0 = fmaf(vk, wl[k * 32 + c], g0);
            g1 = fmaf(vk, wl[k * 32 + c + 16], g1);
        }
        if (node < n) {
            out0[(size_t)node * 32 + c] = tanhf(g0) + res[(size_t)node * 32 + c];
            out0[(size_t)node * 32 + c + 16] = tanhf(g1) + res[(size_t)node * 32 + c + 16];
        }
    } else {  // MODE 4
        if (node < n) out0[(size_t)node * D + c] = acc;
    }
}

// ---------------------------------------------------------------------------
// GEMM6: [n,32] @ [32,512] -> sigmoid -> [n,512]. COLUMN-SPLIT persistent
// blocks: each block stages HALF of W6 (32 KB -> 36.5 KB LDS total ->
// 4 blocks/CU, was 2) and computes its 256-col half of each 32-row tile.
// Grid 1024 = 2 parts x 512 tile-walkers, exactly resident.
// ---------------------------------------------------------------------------
#define FT_R 32
__global__ __launch_bounds__(256) void gemm_fout(const float* __restrict__ a,
                                                 const float* __restrict__ W,
                                                 float* __restrict__ out, int n,
                                                 int ntiles) {
    __shared__ float wl[NHID * 256];     // 32 KB (one column half)
    __shared__ float aT[NHID][FT_R + 1]; // 4.2 KB
    const int part = blockIdx.x & 1;     // which 256-col half
    {
        // stage W[k][part*256 + j], j=0..255: 2048 float4, 8 per thread
        const float4* w4 = reinterpret_cast<const float4*>(W);
        float4* wl4 = reinterpret_cast<float4*>(wl);
#pragma unroll
        for (int i = threadIdx.x; i < NHID * 64; i += 256) {
            int k = i >> 6;       // 0..31
            int j = i & 63;       // float4 within half-row
            wl4[k * 64 + j] = w4[k * 128 + part * 64 + j];
        }
    }
    const int rt = threadIdx.x >> 5;   // 0..7 row group (4 rows)
    const int ct = threadIdx.x & 31;   // 0..31 col group (4 cols per cc-chunk)
    const int srr = threadIdx.x >> 3;  // staging row 0..31
    const int sk4 = threadIdx.x & 7;   // staging float4 0..7

    for (int tile = blockIdx.x >> 1; tile < ntiles; tile += gridDim.x >> 1) {
        const int r0 = tile * FT_R;
        __syncthreads();
        {
            int r = r0 + srr;
            float4 v;
            if (r < n)
                v = *reinterpret_cast<const float4*>(a + (size_t)r * NHID + sk4 * 4);
            else
                v.x = v.y = v.z = v.w = 0.f;
            aT[sk4 * 4 + 0][srr] = v.x;
            aT[sk4 * 4 + 1][srr] = v.y;
            aT[sk4 * 4 + 2][srr] = v.z;
            aT[sk4 * 4 + 3][srr] = v.w;
        }
        __syncthreads();
#pragma unroll
        for (int cc = 0; cc < 2; ++cc) {  // two 128-col chunks of this half
            float acc[4][4] = {{0.f}};
#pragma unroll 8
            for (int k = 0; k < NHID; ++k) {
                float4 av = *reinterpret_cast<const float4*>(&aT[k][rt * 4]);
                float4 wv = *reinterpret_cast<const float4*>(&wl[k * 256 + cc * 128 + ct * 4]);
                acc[0][0] = fmaf(av.x, wv.x, acc[0][0]);
                acc[0][1] = fmaf(av.x, wv.y, acc[0][1]);
                acc[0][2] = fmaf(av.x, wv.z, acc[0][2]);
                acc[0][3] = fmaf(av.x, wv.w, acc[0][3]);
                acc[1][0] = fmaf(av.y, wv.x, acc[1][0]);
                acc[1][1] = fmaf(av.y, wv.y, acc[1][1]);
                acc[1][2] = fmaf(av.y, wv.z, acc[1][2]);
                acc[1][3] = fmaf(av.y, wv.w, acc[1][3]);
                acc[2][0] = fmaf(av.z, wv.x, acc[2][0]);
                acc[2][1] = fmaf(av.z, wv.y, acc[2][1]);
                acc[2][2] = fmaf(av.z, wv.z, acc[2][2]);
                acc[2][3] = fmaf(av.z, wv.w, acc[2][3]);
                acc[3][0] = fmaf(av.w, wv.x, acc[3][0]);
                acc[3][1] = fmaf(av.w, wv.y, acc[3][1]);
                acc[3][2] = fmaf(av.w, wv.z, acc[3][2]);
                acc[3][3] = fmaf(av.w, wv.w, acc[3][3]);
            }
#pragma unroll
            for (int i = 0; i < 4; ++i) {
                int r = r0 + rt * 4 + i;
                if (r < n) {
                    float4 o;
                    o.x = 1.f / (1.f + expf(-acc[i][0]));
                    o.y = 1.f / (1.f + expf(-acc[i][1]));
                    o.z = 1.f / (1.f + expf(-acc[i][2]));
                    o.w = 1.f / (1.f + expf(-acc[i][3]));
                    *reinterpret_cast<float4*>(out + (size_t)r * FIN + part * 256 + cc * 128 + ct * 4) = o;
                }
            }
        }
    }
}

extern "C" void kernel_launch(void* const* d_in, const int* in_sizes, int n_in,
                              void* d_out, int out_size, void* d_ws, size_t ws_size,
                              hipStream_t stream) {
    const float* feat = (const float*)d_in[0];
    const int* esrc = (const int*)d_in[1];
    const int* edst = (const int*)d_in[2];
    const float* ewt = (const float*)d_in[3];
    const float* W1 = (const float*)d_in[4];
    const float* W2 = (const float*)d_in[5];
    const float* W3 = (const float*)d_in[6];
    const float* W4 = (const float*)d_in[7];
    const float* W5 = (const float*)d_in[8];
    const float* W6 = (const float*)d_in[9];
    const int n = in_sizes[0] / FIN;
    const int e = in_sizes[1];
    const int nb = (n + 255) >> 8;

    float* out = (float*)d_out;
    float* recon = out;                   // [n,512]
    float* zout = out + (size_t)n * FIN;  // [n,16]
    float* pred = zout + (size_t)n * 16;  // [n,16]

    char* wsb = (char*)d_ws;
    unsigned long long* rec = (unsigned long long*)wsb;  // e * 8B
    int* rowptr = (int*)(wsb + (size_t)e * 8);           // n+1
    int* btot = rowptr + n + 1;                          // 256
    int* bbase = btot + 256;                             // nb+1
    int* bcursor = bbase + nb + 1;                       // nb
    size_t foff = ((size_t)(bcursor + nb - (int*)wsb) + 3) & ~(size_t)3;
    float* S_a = (float*)wsb + foff;    // n*32
    float* S_b = S_a + (size_t)n * 32;  // n*32
    float* X1 = S_b + (size_t)n * 32;   // n*32 (x1)
    float* X2 = X1 + (size_t)n * 32;    // n*16 (x2)
    float* G1 = X2 + (size_t)n * 16;    // n*32 (K-split partial)
    unsigned long long* rec2 = (unsigned long long*)S_a;  // e*8B alias (S_a+S_b)

    const int geb = (e + 4095) / 4096;
    const int gn32 = (n + 7) / 8;
    const int gn16 = (n + 15) / 16;
    const int ntile1 = (n + BR - 1) / BR;
    const int ntiles6 = (n + FT_R - 1) / FT_R;

    // ---- CSR build ----
    hipMemsetAsync(btot, 0, 256 * sizeof(int), stream);
    bhist<<<geb, 256, 0, stream>>>(edst, btot, e);
    bscan<<<1, 256, 0, stream>>>(btot, bbase, bcursor, rowptr, nb, n, e);
    build_a<<<geb, 256, 0, stream>>>(esrc, edst, ewt, bcursor, rec2, e, nb);
    build_b<<<nb, 256, 0, stream>>>(rec2, bbase, rowptr, rec, n);

    // conv1: s1 = feat@W1 (K-split partials -> S_a, G1; add2 -> S_a)
    gemm_fin<<<2 * ntile1, 256, 0, stream>>>(feat, W1, S_a, G1, n, ntile1);
    add2<<<(n * 32 / 4 + 255) / 256, 256, 0, stream>>>(S_a, G1, n * 32 / 4);
    // x1 = tanh(A s1) -> X1 ; s2 = x1@W2 -> S_b
    agg_fused<32, 16, 1, false><<<gn32, 256, 0, stream>>>(S_a, rec, rowptr, W2, nullptr, X1, S_b, nullptr, n);
    // conv2: x2 = tanh(A s2) -> X2 ; s3 = x2@W3 -> S_a
    agg_fused<16, 16, 1, false><<<gn16, 256, 0, stream>>>(S_b, rec, rowptr, W3, nullptr, X2, S_a, nullptr, n);
    // conv3: z = tanh(A s3) -> zout ; pred = softmax(z) ; s4 = z@W4 -> S_b
    agg_fused<16, 16, 1, true><<<gn16, 256, 0, stream>>>(S_a, rec, rowptr, W4, nullptr, zout, S_b, pred, n);
    // conv4: z2 = tanh(A s4) + x2 -> S_a
    agg_fused<16, 16, 2, false><<<gn16, 256, 0, stream>>>(S_b, rec, rowptr, nullptr, X2, S_a, nullptr, nullptr, n);
    // conv5: z1 = tanh((A z2)@W5) + x1 -> S_b
    agg_fused<16, 32, 3, false><<<gn16, 256, 0, stream>>>(S_a, rec, rowptr, W5, X1, S_b, nullptr, nullptr, n);
    // conv6: recon = sigmoid((A z1)@W6)
    agg_fused<32, 32, 4, false><<<gn32, 256, 0, stream>>>(S_b, rec, rowptr, nullptr, nullptr, S_a, nullptr, nullptr, n);
    gemm_fout<<<1024, 256, 0, stream>>>(S_a, W6, recon, n, ntiles6);
}

// Round 10
// 320.066 us; speedup vs baseline: 2.9850x; 1.0709x over previous
//
#include <hip/hip_runtime.h>
#include <hip/hip_bf16.h>
#include <math.h>

#define FIN 512
#define NHID 32
#define LAT 16

// ---------------------------------------------------------------------------
// GEMM1: [n,512] @ [512,32] -> [n,32]. K-split x2, XOR-swizzled xT (unchanged).
// ---------------------------------------------------------------------------
#define BR 128
#define KC 64
__global__ __launch_bounds__(256) void gemm_fin(const float* __restrict__ feat,
                                                const float* __restrict__ W,
                                                float* __restrict__ out0,
                                                float* __restrict__ out1,
                                                int n, int ntile) {
    __shared__ float xT[KC][BR];    // 32 KB, swizzled
    __shared__ float Wc[KC][NHID];  // 8 KB
    const int tid = threadIdx.x;
    const int tile = blockIdx.x % ntile;
    const int khalf = blockIdx.x / ntile;
    const int r0 = tile * BR;
    const int k0 = khalf * 256;
    float* __restrict__ out = khalf ? out1 : out0;
    const int rt = tid >> 3;
    const int ct = tid & 7;
    const int srow = tid >> 4;
    const int sc4 = tid & 15;
    float acc[4][4] = {{0.f}};

    for (int kc = 0; kc < 256; kc += KC) {
        {
            const float4* wg = reinterpret_cast<const float4*>(W + (k0 + kc) * NHID);
            float4* wl = reinterpret_cast<float4*>(&Wc[0][0]);
            wl[tid] = wg[tid];
            wl[tid + 256] = wg[tid + 256];
        }
#pragma unroll
        for (int i = 0; i < 8; ++i) {
            int rr = srow + 16 * i;
            int r = r0 + rr;
            float4 v;
            if (r < n)
                v = *reinterpret_cast<const float4*>(feat + (size_t)r * FIN + k0 + kc + sc4 * 4);
            else
                v.x = v.y = v.z = v.w = 0.f;
            int gs = ((rr >> 2) ^ (sc4 & 7)) * 4 + (rr & 3);
            xT[sc4 * 4 + 0][gs] = v.x;
            xT[sc4 * 4 + 1][gs] = v.y;
            xT[sc4 * 4 + 2][gs] = v.z;
            xT[sc4 * 4 + 3][gs] = v.w;
        }
        __syncthreads();
#pragma unroll 4
        for (int k = 0; k < KC; ++k) {
            int sw = (rt ^ ((k >> 2) & 7)) * 4;
            float4 xv = *reinterpret_cast<const float4*>(&xT[k][sw]);
            float4 wv = *reinterpret_cast<const float4*>(&Wc[k][ct * 4]);
            acc[0][0] = fmaf(xv.x, wv.x, acc[0][0]);
            acc[0][1] = fmaf(xv.x, wv.y, acc[0][1]);
            acc[0][2] = fmaf(xv.x, wv.z, acc[0][2]);
            acc[0][3] = fmaf(xv.x, wv.w, acc[0][3]);
            acc[1][0] = fmaf(xv.y, wv.x, acc[1][0]);
            acc[1][1] = fmaf(xv.y, wv.y, acc[1][1]);
            acc[1][2] = fmaf(xv.y, wv.z, acc[1][2]);
            acc[1][3] = fmaf(xv.y, wv.w, acc[1][3]);
            acc[2][0] = fmaf(xv.z, wv.x, acc[2][0]);
            acc[2][1] = fmaf(xv.z, wv.y, acc[2][1]);
            acc[2][2] = fmaf(xv.z, wv.z, acc[2][2]);
            acc[2][3] = fmaf(xv.z, wv.w, acc[2][3]);
            acc[3][0] = fmaf(xv.w, wv.x, acc[3][0]);
            acc[3][1] = fmaf(xv.w, wv.y, acc[3][1]);
            acc[3][2] = fmaf(xv.w, wv.z, acc[3][2]);
            acc[3][3] = fmaf(xv.w, wv.w, acc[3][3]);
        }
        __syncthreads();
    }
#pragma unroll
    for (int i = 0; i < 4; ++i) {
        int r = r0 + rt * 4 + i;
        if (r < n) {
            float4 o;
            o.x = acc[i][0]; o.y = acc[i][1]; o.z = acc[i][2]; o.w = acc[i][3];
            *reinterpret_cast<float4*>(out + (size_t)r * NHID + ct * 4) = o;
        }
    }
}

// a += b (float4), for the K-split reduction.
__global__ __launch_bounds__(256) void add2(float* __restrict__ a,
                                            const float* __restrict__ b, int n4) {
    int i = blockIdx.x * 256 + threadIdx.x;
    if (i < n4) {
        float4 va = reinterpret_cast<float4*>(a)[i];
        float4 vb = reinterpret_cast<const float4*>(b)[i];
        va.x += vb.x; va.y += vb.y; va.z += vb.z; va.w += vb.w;
        reinterpret_cast<float4*>(a)[i] = va;
    }
}

// ---------------------------------------------------------------------------
// CSR build (unchanged — verified dense-writeback design).
// ---------------------------------------------------------------------------
__global__ __launch_bounds__(256) void bhist(const int* __restrict__ dst,
                                             int* __restrict__ btot, int e) {
    __shared__ int h[256];
    const int tid = threadIdx.x;
    h[tid] = 0;
    __syncthreads();
    const int i0 = blockIdx.x * 4096;
#pragma unroll
    for (int k = 0; k < 16; ++k) {
        int j = i0 + k * 256 + tid;
        if (j < e) atomicAdd(&h[dst[j] >> 8], 1);
    }
    __syncthreads();
    if (h[tid]) atomicAdd(&btot[tid], h[tid]);
}

__global__ __launch_bounds__(256) void bscan(const int* __restrict__ btot,
                                             int* __restrict__ bbase,
                                             int* __restrict__ bcursor,
                                             int* __restrict__ rowptr,
                                             int nb, int n, int e) {
    __shared__ int sh[256];
    const int t = threadIdx.x;
    int v = (t < nb) ? btot[t] : 0;
    sh[t] = v;
    __syncthreads();
    for (int off = 1; off < 256; off <<= 1) {
        int x = (t >= off) ? sh[t - off] : 0;
        __syncthreads();
        sh[t] += x;
        __syncthreads();
    }
    int ex = sh[t] - v;
    if (t < nb) {
        bbase[t] = ex;
        bcursor[t] = ex;
    }
    if (t == 0) {
        bbase[nb] = e;
        rowptr[n] = e;
    }
}

__global__ __launch_bounds__(256) void build_a(const int* __restrict__ src,
                                               const int* __restrict__ dst,
                                               const float* __restrict__ w,
                                               int* __restrict__ bcursor,
                                               unsigned long long* __restrict__ rec2,
                                               int e, int nb) {
    __shared__ int cnt[256];
    __shared__ int gb[256];
    const int tid = threadIdx.x;
    const int i0 = blockIdx.x * 4096;
    cnt[tid] = 0;
    __syncthreads();
    unsigned long long rc[16];
    int rkbk[16];
#pragma unroll
    for (int k = 0; k < 16; ++k) {
        int j = i0 + k * 256 + tid;
        rkbk[k] = -1;
        if (j < e) {
            int d = dst[j];
            int b = d >> 8;
            int rk = atomicAdd(&cnt[b], 1);
            rkbk[k] = (rk << 8) | b;
            rc[k] = ((unsigned long long)__float_as_uint(w[j]) << 32) |
                    ((unsigned)d << 16) | (unsigned)src[j];
        }
    }
    __syncthreads();
    if (tid < nb && cnt[tid] > 0) gb[tid] = atomicAdd(&bcursor[tid], cnt[tid]);
    __syncthreads();
#pragma unroll
    for (int k = 0; k < 16; ++k) {
        if (rkbk[k] >= 0) {
            int b = rkbk[k] & 255;
            int rk = rkbk[k] >> 8;
            rec2[gb[b] + rk] = rc[k];
        }
    }
}

__global__ __launch_bounds__(256) void build_b(const unsigned long long* __restrict__ rec2,
                                               const int* __restrict__ bbase,
                                               int* __restrict__ rowptr,
                                               unsigned long long* __restrict__ rec,
                                               int n) {
    __shared__ int cnt[256];
    __shared__ int cur[256];
    const int t = threadIdx.x;
    const int b = blockIdx.x;
    const int lo = bbase[b];
    const int hi = bbase[b + 1];
    cnt[t] = 0;
    __syncthreads();
    for (int i = lo + t; i < hi; i += 256)
        atomicAdd(&cnt[((unsigned)rec2[i] >> 16) & 255], 1);
    __syncthreads();
    int v = cnt[t];
    cur[t] = v;
    __syncthreads();
    for (int off = 1; off < 256; off <<= 1) {
        int x = (t >= off) ? cur[t - off] : 0;
        __syncthreads();
        cur[t] += x;
        __syncthreads();
    }
    int ex = cur[t] - v;
    int node = b * 256 + t;
    if (node < n) rowptr[node] = lo + ex;
    __syncthreads();
    cur[t] = ex;
    __syncthreads();
    for (int i = lo + t; i < hi; i += 256) {
        unsigned long long r = rec2[i];
        unsigned lo32 = (unsigned)r;
        int ln = (lo32 >> 16) & 255;
        int p = atomicAdd(&cur[ln], 1);
        rec[lo + p] = (r & 0xffffffff00000000ull) | (lo32 & 0xffffu);
    }
}

// ---------------------------------------------------------------------------
// CSR aggregation v2: D-lane group per node regrouped as 4 edge-streams x
// (D/4) col-chunk lanes. Each lane gathers a FLOAT4 of its stream's edge row
// -> 4x fewer load instructions, 16 edges in flight per group (was 8).
// Tail edges zero-padded (src=0, w=0: gathers node 0's hot line, adds 0).
// Stream-reduce via shfl_xor(CH, 2CH); epilogues on float4 lanes.
// ---------------------------------------------------------------------------
template <int D, int C, int MODE, bool SMAX>
__global__ __launch_bounds__(256) void agg_fused(const float* __restrict__ s,
                                                 const unsigned long long* __restrict__ rec,
                                                 const int* __restrict__ rowptr,
                                                 const float* __restrict__ Wn,
                                                 const float* __restrict__ res,
                                                 float* __restrict__ out0,
                                                 float* __restrict__ out1,
                                                 float* __restrict__ pred, int n) {
    constexpr int CH = D / 4;  // lanes per edge (col-chunks)
    __shared__ float wl[(MODE == 1 || MODE == 3) ? D * C : 1];
    if (MODE == 1 || MODE == 3) {
        for (int i = threadIdx.x; i < D * C; i += 256) wl[i] = Wn[i];
        __syncthreads();
    }
    constexpr int NPB = 256 / D;
    const int node = blockIdx.x * NPB + threadIdx.x / D;
    const int lane = threadIdx.x % D;
    const int q = lane & (CH - 1);  // col-chunk index
    const int st = lane / CH;       // stream 0..3
    float ax = 0.f, ay = 0.f, az = 0.f, aw = 0.f;
    if (node < n) {
        const float* sq = s + 4 * q;
        const int i0 = rowptr[node];
        const int end = rowptr[node + 1];
        for (int i = i0; i < end; i += 16) {
            const int e0 = i + st;
            unsigned long long r0 = (e0 < end) ? rec[e0] : 0ull;
            unsigned long long r1 = (e0 + 4 < end) ? rec[e0 + 4] : 0ull;
            unsigned long long r2 = (e0 + 8 < end) ? rec[e0 + 8] : 0ull;
            unsigned long long r3 = (e0 + 12 < end) ? rec[e0 + 12] : 0ull;
            float4 v0 = *reinterpret_cast<const float4*>(sq + (size_t)(unsigned)(r0 & 0xffffffffu) * D);
            float4 v1 = *reinterpret_cast<const float4*>(sq + (size_t)(unsigned)(r1 & 0xffffffffu) * D);
            float4 v2 = *reinterpret_cast<const float4*>(sq + (size_t)(unsigned)(r2 & 0xffffffffu) * D);
            float4 v3 = *reinterpret_cast<const float4*>(sq + (size_t)(unsigned)(r3 & 0xffffffffu) * D);
            float w0 = __uint_as_float((unsigned)(r0 >> 32));
            float w1 = __uint_as_float((unsigned)(r1 >> 32));
            float w2 = __uint_as_float((unsigned)(r2 >> 32));
            float w3 = __uint_as_float((unsigned)(r3 >> 32));
            ax = fmaf(v0.x, w0, ax); ay = fmaf(v0.y, w0, ay);
            az = fmaf(v0.z, w0, az); aw = fmaf(v0.w, w0, aw);
            ax = fmaf(v1.x, w1, ax); ay = fmaf(v1.y, w1, ay);
            az = fmaf(v1.z, w1, az); aw = fmaf(v1.w, w1, aw);
            ax = fmaf(v2.x, w2, ax); ay = fmaf(v2.y, w2, ay);
            az = fmaf(v2.z, w2, az); aw = fmaf(v2.w, w2, aw);
            ax = fmaf(v3.x, w3, ax); ay = fmaf(v3.y, w3, ay);
            az = fmaf(v3.z, w3, az); aw = fmaf(v3.w, w3, aw);
        }
    }
    // stream reduction: sum over the 4 streams (bits CH, 2*CH of lane id)
    ax += __shfl_xor(ax, CH, D);  ax += __shfl_xor(ax, 2 * CH, D);
    ay += __shfl_xor(ay, CH, D);  ay += __shfl_xor(ay, 2 * CH, D);
    az += __shfl_xor(az, CH, D);  az += __shfl_xor(az, 2 * CH, D);
    aw += __shfl_xor(aw, CH, D);  aw += __shfl_xor(aw, 2 * CH, D);

    if (MODE == 1) {
        float vx = tanhf(ax), vy = tanhf(ay), vz = tanhf(az), vw = tanhf(aw);
        if (node < n && st == 0) {
            float4 o; o.x = vx; o.y = vy; o.z = vz; o.w = vw;
            *reinterpret_cast<float4*>(out0 + (size_t)node * D + 4 * q) = o;
        }
        if (SMAX) {  // D == 16: softmax over the 16 cols
            float m = fmaxf(fmaxf(vx, vy), fmaxf(vz, vw));
            m = fmaxf(m, __shfl_xor(m, 1, 16));
            m = fmaxf(m, __shfl_xor(m, 2, 16));
            float ex = expf(vx - m), ey = expf(vy - m), ez = expf(vz - m), ew = expf(vw - m);
            float sm = ex + ey + ez + ew;
            sm += __shfl_xor(sm, 1, 16);
            sm += __shfl_xor(sm, 2, 16);
            float inv = 1.f / sm;
            if (node < n && st == 0) {
                float4 o; o.x = ex * inv; o.y = ey * inv; o.z = ez * inv; o.w = ew * inv;
                *reinterpret_cast<float4*>(pred + (size_t)node * 16 + 4 * q) = o;
            }
        }
        // next-layer gemm: out1[node][cc] = sum_k v_k * Wn[k][cc]
        const int cc = lane & (C - 1);
        float g = 0.f;
#pragma unroll
        for (int k = 0; k < D; ++k) {
            float comp = ((k & 3) == 0) ? vx : ((k & 3) == 1) ? vy : ((k & 3) == 2) ? vz : vw;
            float vk = __shfl(comp, k >> 2, D);
            g = fmaf(vk, wl[k * C + cc], g);
        }
        if (node < n && lane < C) out1[(size_t)node * C + cc] = g;
    } else if (MODE == 2) {
        if (node < n && st == 0) {
            float4 rv = *reinterpret_cast<const float4*>(res + (size_t)node * D + 4 * q);
            float4 o;
            o.x = tanhf(ax) + rv.x; o.y = tanhf(ay) + rv.y;
            o.z = tanhf(az) + rv.z; o.w = tanhf(aw) + rv.w;
            *reinterpret_cast<float4*>(out0 + (size_t)node * D + 4 * q) = o;
        }
    } else if (MODE == 3) {  // D=16, C=32: out = tanh(accRow @ Wn) + res
        float g0 = 0.f, g1 = 0.f;
#pragma unroll
        for (int k = 0; k < 16; ++k) {
            float comp = ((k & 3) == 0) ? ax : ((k & 3) == 1) ? ay : ((k & 3) == 2) ? az : aw;
            float vk = __shfl(comp, k >> 2, 16);
            g0 = fmaf(vk, wl[k * 32 + lane], g0);
            g1 = fmaf(vk, wl[k * 32 + lane + 16], g1);
        }
        if (node < n) {
            out0[(size_t)node * 32 + lane] = tanhf(g0) + res[(size_t)node * 32 + lane];
            out0[(size_t)node * 32 + lane + 16] = tanhf(g1) + res[(size_t)node * 32 + lane + 16];
        }
    } else {  // MODE 4
        if (node < n && st == 0) {
            float4 o; o.x = ax; o.y = ay; o.z = az; o.w = aw;
            *reinterpret_cast<float4*>(out0 + (size_t)node * D + 4 * q) = o;
        }
    }
}

// ---------------------------------------------------------------------------
// GEMM6: column-split persistent blocks (unchanged from round 8).
// ---------------------------------------------------------------------------
#define FT_R 32
__global__ __launch_bounds__(256) void gemm_fout(const float* __restrict__ a,
                                                 const float* __restrict__ W,
                                                 float* __restrict__ out, int n,
                                                 int ntiles) {
    __shared__ float wl[NHID * 256];     // 32 KB (one column half)
    __shared__ float aT[NHID][FT_R + 1]; // 4.2 KB
    const int part = blockIdx.x & 1;
    {
        const float4* w4 = reinterpret_cast<const float4*>(W);
        float4* wl4 = reinterpret_cast<float4*>(wl);
#pragma unroll
        for (int i = threadIdx.x; i < NHID * 64; i += 256) {
            int k = i >> 6;
            int j = i & 63;
            wl4[k * 64 + j] = w4[k * 128 + part * 64 + j];
        }
    }
    const int rt = threadIdx.x >> 5;
    const int ct = threadIdx.x & 31;
    const int srr = threadIdx.x >> 3;
    const int sk4 = threadIdx.x & 7;

    for (int tile = blockIdx.x >> 1; tile < ntiles; tile += gridDim.x >> 1) {
        const int r0 = tile * FT_R;
        __syncthreads();
        {
            int r = r0 + srr;
            float4 v;
            if (r < n)
                v = *reinterpret_cast<const float4*>(a + (size_t)r * NHID + sk4 * 4);
            else
                v.x = v.y = v.z = v.w = 0.f;
            aT[sk4 * 4 + 0][srr] = v.x;
            aT[sk4 * 4 + 1][srr] = v.y;
            aT[sk4 * 4 + 2][srr] = v.z;
            aT[sk4 * 4 + 3][srr] = v.w;
        }
        __syncthreads();
#pragma unroll
        for (int cc = 0; cc < 2; ++cc) {
            float acc[4][4] = {{0.f}};
#pragma unroll 8
            for (int k = 0; k < NHID; ++k) {
                float4 av = *reinterpret_cast<const float4*>(&aT[k][rt * 4]);
                float4 wv = *reinterpret_cast<const float4*>(&wl[k * 256 + cc * 128 + ct * 4]);
                acc[0][0] = fmaf(av.x, wv.x, acc[0][0]);
                acc[0][1] = fmaf(av.x, wv.y, acc[0][1]);
                acc[0][2] = fmaf(av.x, wv.z, acc[0][2]);
                acc[0][3] = fmaf(av.x, wv.w, acc[0][3]);
                acc[1][0] = fmaf(av.y, wv.x, acc[1][0]);
                acc[1][1] = fmaf(av.y, wv.y, acc[1][1]);
                acc[1][2] = fmaf(av.y, wv.z, acc[1][2]);
                acc[1][3] = fmaf(av.y, wv.w, acc[1][3]);
                acc[2][0] = fmaf(av.z, wv.x, acc[2][0]);
                acc[2][1] = fmaf(av.z, wv.y, acc[2][1]);
                acc[2][2] = fmaf(av.z, wv.z, acc[2][2]);
                acc[2][3] = fmaf(av.z, wv.w, acc[2][3]);
                acc[3][0] = fmaf(av.w, wv.x, acc[3][0]);
                acc[3][1] = fmaf(av.w, wv.y, acc[3][1]);
                acc[3][2] = fmaf(av.w, wv.z, acc[3][2]);
                acc[3][3] = fmaf(av.w, wv.w, acc[3][3]);
            }
#pragma unroll
            for (int i = 0; i < 4; ++i) {
                int r = r0 + rt * 4 + i;
                if (r < n) {
                    float4 o;
                    o.x = 1.f / (1.f + expf(-acc[i][0]));
                    o.y = 1.f / (1.f + expf(-acc[i][1]));
                    o.z = 1.f / (1.f + expf(-acc[i][2]));
                    o.w = 1.f / (1.f + expf(-acc[i][3]));
                    *reinterpret_cast<float4*>(out + (size_t)r * FIN + part * 256 + cc * 128 + ct * 4) = o;
                }
            }
        }
    }
}

extern "C" void kernel_launch(void* const* d_in, const int* in_sizes, int n_in,
                              void* d_out, int out_size, void* d_ws, size_t ws_size,
                              hipStream_t stream) {
    const float* feat = (const float*)d_in[0];
    const int* esrc = (const int*)d_in[1];
    const int* edst = (const int*)d_in[2];
    const float* ewt = (const float*)d_in[3];
    const float* W1 = (const float*)d_in[4];
    const float* W2 = (const float*)d_in[5];
    const float* W3 = (const float*)d_in[6];
    const float* W4 = (const float*)d_in[7];
    const float* W5 = (const float*)d_in[8];
    const float* W6 = (const float*)d_in[9];
    const int n = in_sizes[0] / FIN;
    const int e = in_sizes[1];
    const int nb = (n + 255) >> 8;

    float* out = (float*)d_out;
    float* recon = out;                   // [n,512]
    float* zout = out + (size_t)n * FIN;  // [n,16]
    float* pred = zout + (size_t)n * 16;  // [n,16]

    char* wsb = (char*)d_ws;
    unsigned long long* rec = (unsigned long long*)wsb;  // e * 8B
    int* rowptr = (int*)(wsb + (size_t)e * 8);           // n+1
    int* btot = rowptr + n + 1;                          // 256
    int* bbase = btot + 256;                             // nb+1
    int* bcursor = bbase + nb + 1;                       // nb
    size_t foff = ((size_t)(bcursor + nb - (int*)wsb) + 3) & ~(size_t)3;
    float* S_a = (float*)wsb + foff;    // n*32
    float* S_b = S_a + (size_t)n * 32;  // n*32
    float* X1 = S_b + (size_t)n * 32;   // n*32 (x1)
    float* X2 = X1 + (size_t)n * 32;    // n*16 (x2)
    float* G1 = X2 + (size_t)n * 16;    // n*32 (K-split partial)
    unsigned long long* rec2 = (unsigned long long*)S_a;  // e*8B alias (S_a+S_b)

    const int geb = (e + 4095) / 4096;
    const int gn32 = (n + 7) / 8;
    const int gn16 = (n + 15) / 16;
    const int ntile1 = (n + BR - 1) / BR;
    const int ntiles6 = (n + FT_R - 1) / FT_R;

    // ---- CSR build ----
    hipMemsetAsync(btot, 0, 256 * sizeof(int), stream);
    bhist<<<geb, 256, 0, stream>>>(edst, btot, e);
    bscan<<<1, 256, 0, stream>>>(btot, bbase, bcursor, rowptr, nb, n, e);
    build_a<<<geb, 256, 0, stream>>>(esrc, edst, ewt, bcursor, rec2, e, nb);
    build_b<<<nb, 256, 0, stream>>>(rec2, bbase, rowptr, rec, n);

    // conv1: s1 = feat@W1 (K-split partials -> S_a, G1; add2 -> S_a)
    gemm_fin<<<2 * ntile1, 256, 0, stream>>>(feat, W1, S_a, G1, n, ntile1);
    add2<<<(n * 32 / 4 + 255) / 256, 256, 0, stream>>>(S_a, G1, n * 32 / 4);
    // x1 = tanh(A s1) -> X1 ; s2 = x1@W2 -> S_b
    agg_fused<32, 16, 1, false><<<gn32, 256, 0, stream>>>(S_a, rec, rowptr, W2, nullptr, X1, S_b, nullptr, n);
    // conv2: x2 = tanh(A s2) -> X2 ; s3 = x2@W3 -> S_a
    agg_fused<16, 16, 1, false><<<gn16, 256, 0, stream>>>(S_b, rec, rowptr, W3, nullptr, X2, S_a, nullptr, n);
    // conv3: z = tanh(A s3) -> zout ; pred = softmax(z) ; s4 = z@W4 -> S_b
    agg_fused<16, 16, 1, true><<<gn16, 256, 0, stream>>>(S_a, rec, rowptr, W4, nullptr, zout, S_b, pred, n);
    // conv4: z2 = tanh(A s4) + x2 -> S_a
    agg_fused<16, 16, 2, false><<<gn16, 256, 0, stream>>>(S_b, rec, rowptr, nullptr, X2, S_a, nullptr, nullptr, n);
    // conv5: z1 = tanh((A z2)@W5) + x1 -> S_b
    agg_fused<16, 32, 3, false><<<gn16, 256, 0, stream>>>(S_a, rec, rowptr, W5, X1, S_b, nullptr, nullptr, n);
    // conv6: recon = sigmoid((A z1)@W6)
    agg_fused<32, 32, 4, false><<<gn32, 256, 0, stream>>>(S_b, rec, rowptr, nullptr, nullptr, S_a, nullptr, nullptr, n);
    gemm_fout<<<1024, 256, 0, stream>>>(S_a, W6, recon, n, ntiles6);
}

// Round 11
// 304.921 us; speedup vs baseline: 3.1333x; 1.0497x over previous
//
#include <hip/hip_runtime.h>
#include <hip/hip_bf16.h>
#include <math.h>

#define FIN 512
#define NHID 32
#define LAT 16
#define BCAP 16384  // records per 256-node bucket (mean 8192, sigma ~90)

// ---------------------------------------------------------------------------
// GEMM1: [n,512] @ [512,32] -> [n,32]. K-split x2, XOR-swizzled xT (unchanged).
// ---------------------------------------------------------------------------
#define BR 128
#define KC 64
__global__ __launch_bounds__(256) void gemm_fin(const float* __restrict__ feat,
                                                const float* __restrict__ W,
                                                float* __restrict__ out0,
                                                float* __restrict__ out1,
                                                int n, int ntile) {
    __shared__ float xT[KC][BR];    // 32 KB, swizzled
    __shared__ float Wc[KC][NHID];  // 8 KB
    const int tid = threadIdx.x;
    const int tile = blockIdx.x % ntile;
    const int khalf = blockIdx.x / ntile;
    const int r0 = tile * BR;
    const int k0 = khalf * 256;
    float* __restrict__ out = khalf ? out1 : out0;
    const int rt = tid >> 3;
    const int ct = tid & 7;
    const int srow = tid >> 4;
    const int sc4 = tid & 15;
    float acc[4][4] = {{0.f}};

    for (int kc = 0; kc < 256; kc += KC) {
        {
            const float4* wg = reinterpret_cast<const float4*>(W + (k0 + kc) * NHID);
            float4* wl = reinterpret_cast<float4*>(&Wc[0][0]);
            wl[tid] = wg[tid];
            wl[tid + 256] = wg[tid + 256];
        }
#pragma unroll
        for (int i = 0; i < 8; ++i) {
            int rr = srow + 16 * i;
            int r = r0 + rr;
            float4 v;
            if (r < n)
                v = *reinterpret_cast<const float4*>(feat + (size_t)r * FIN + k0 + kc + sc4 * 4);
            else
                v.x = v.y = v.z = v.w = 0.f;
            int gs = ((rr >> 2) ^ (sc4 & 7)) * 4 + (rr & 3);
            xT[sc4 * 4 + 0][gs] = v.x;
            xT[sc4 * 4 + 1][gs] = v.y;
            xT[sc4 * 4 + 2][gs] = v.z;
            xT[sc4 * 4 + 3][gs] = v.w;
        }
        __syncthreads();
#pragma unroll 4
        for (int k = 0; k < KC; ++k) {
            int sw = (rt ^ ((k >> 2) & 7)) * 4;
            float4 xv = *reinterpret_cast<const float4*>(&xT[k][sw]);
            float4 wv = *reinterpret_cast<const float4*>(&Wc[k][ct * 4]);
            acc[0][0] = fmaf(xv.x, wv.x, acc[0][0]);
            acc[0][1] = fmaf(xv.x, wv.y, acc[0][1]);
            acc[0][2] = fmaf(xv.x, wv.z, acc[0][2]);
            acc[0][3] = fmaf(xv.x, wv.w, acc[0][3]);
            acc[1][0] = fmaf(xv.y, wv.x, acc[1][0]);
            acc[1][1] = fmaf(xv.y, wv.y, acc[1][1]);
            acc[1][2] = fmaf(xv.y, wv.z, acc[1][2]);
            acc[1][3] = fmaf(xv.y, wv.w, acc[1][3]);
            acc[2][0] = fmaf(xv.z, wv.x, acc[2][0]);
            acc[2][1] = fmaf(xv.z, wv.y, acc[2][1]);
            acc[2][2] = fmaf(xv.z, wv.z, acc[2][2]);
            acc[2][3] = fmaf(xv.z, wv.w, acc[2][3]);
            acc[3][0] = fmaf(xv.w, wv.x, acc[3][0]);
            acc[3][1] = fmaf(xv.w, wv.y, acc[3][1]);
            acc[3][2] = fmaf(xv.w, wv.z, acc[3][2]);
            acc[3][3] = fmaf(xv.w, wv.w, acc[3][3]);
        }
        __syncthreads();
    }
#pragma unroll
    for (int i = 0; i < 4; ++i) {
        int r = r0 + rt * 4 + i;
        if (r < n) {
            float4 o;
            o.x = acc[i][0]; o.y = acc[i][1]; o.z = acc[i][2]; o.w = acc[i][3];
            *reinterpret_cast<float4*>(out + (size_t)r * NHID + ct * 4) = o;
        }
    }
}

// a += b (float4), for the K-split reduction.
__global__ __launch_bounds__(256) void add2(float* __restrict__ a,
                                            const float* __restrict__ b, int n4) {
    int i = blockIdx.x * 256 + threadIdx.x;
    if (i < n4) {
        float4 va = reinterpret_cast<float4*>(a)[i];
        float4 vb = reinterpret_cast<const float4*>(b)[i];
        va.x += vb.x; va.y += vb.y; va.z += vb.z; va.w += vb.w;
        reinterpret_cast<float4*>(a)[i] = va;
    }
}

// ---------------------------------------------------------------------------
// CSR build, fixed-capacity buckets: bucket b (256 dst nodes) owns region
// [b*BCAP, (b+1)*BCAP) in rec2/rec. No histogram/scan kernels needed —
// bases are compile-time-shaped; gaps are fine since aggs read (start,end)
// per node from rp2.
// ---------------------------------------------------------------------------
__global__ __launch_bounds__(256) void binit(int* __restrict__ bcursor, int nb) {
    int t = threadIdx.x;
    if (t < nb) bcursor[t] = t * BCAP;
}

// build_a: chunk of 4096 edges/block. LDS-count per bucket, ONE global
// atomicAdd per (block,bucket) to reserve a contiguous run, then write runs.
// Record: (w:32 | dst:16 | src:16), n < 65536.
__global__ __launch_bounds__(256) void build_a(const int* __restrict__ src,
                                               const int* __restrict__ dst,
                                               const float* __restrict__ w,
                                               int* __restrict__ bcursor,
                                               unsigned long long* __restrict__ rec2,
                                               int e, int nb) {
    __shared__ int cnt[256];
    __shared__ int gb[256];
    const int tid = threadIdx.x;
    const int i0 = blockIdx.x * 4096;
    cnt[tid] = 0;
    __syncthreads();
    unsigned long long rc[16];
    int rkbk[16];
#pragma unroll
    for (int k = 0; k < 16; ++k) {
        int j = i0 + k * 256 + tid;
        rkbk[k] = -1;
        if (j < e) {
            int d = dst[j];
            int b = d >> 8;
            int rk = atomicAdd(&cnt[b], 1);
            rkbk[k] = (rk << 8) | b;
            rc[k] = ((unsigned long long)__float_as_uint(w[j]) << 32) |
                    ((unsigned)d << 16) | (unsigned)src[j];
        }
    }
    __syncthreads();
    if (tid < nb && cnt[tid] > 0) gb[tid] = atomicAdd(&bcursor[tid], cnt[tid]);
    __syncthreads();
#pragma unroll
    for (int k = 0; k < 16; ++k) {
        if (rkbk[k] >= 0) {
            int b = rkbk[k] & 255;
            int rk = rkbk[k] >> 8;
            rec2[gb[b] + rk] = rc[k];
        }
    }
}

// build_b: one block owns one bucket. LDS node-histogram -> LDS scan ->
// rp2 (start,end) written directly -> LDS-cursor scatter to final CSR.
__global__ __launch_bounds__(256) void build_b(const unsigned long long* __restrict__ rec2,
                                               const int* __restrict__ bcursor,
                                               int2* __restrict__ rp2,
                                               unsigned long long* __restrict__ rec,
                                               int n) {
    __shared__ int cnt[256];
    __shared__ int cur[256];
    const int t = threadIdx.x;
    const int b = blockIdx.x;
    const int lo = b * BCAP;
    const int hi = bcursor[b];
    cnt[t] = 0;
    __syncthreads();
    for (int i = lo + t; i < hi; i += 256)
        atomicAdd(&cnt[((unsigned)rec2[i] >> 16) & 255], 1);
    __syncthreads();
    int v = cnt[t];
    cur[t] = v;
    __syncthreads();
    for (int off = 1; off < 256; off <<= 1) {
        int x = (t >= off) ? cur[t - off] : 0;
        __syncthreads();
        cur[t] += x;
        __syncthreads();
    }
    int ex = cur[t] - v;
    int node = b * 256 + t;
    if (node < n) {
        int2 se; se.x = lo + ex; se.y = lo + ex + v;
        rp2[node] = se;
    }
    __syncthreads();
    cur[t] = ex;
    __syncthreads();
    for (int i = lo + t; i < hi; i += 256) {
        unsigned long long r = rec2[i];
        unsigned lo32 = (unsigned)r;
        int ln = (lo32 >> 16) & 255;
        int p = atomicAdd(&cur[ln], 1);
        rec[lo + p] = (r & 0xffffffff00000000ull) | (lo32 & 0xffffu);
    }
}

// ---------------------------------------------------------------------------
// Gather helper: NE edges of one stream (stride 4 records), optional
// predication. Fully unrolled -> static indexing (registers, no scratch).
// ---------------------------------------------------------------------------
template <int NE, bool PRED, int D>
__device__ __forceinline__ void gath(const float* __restrict__ sq,
                                     const unsigned long long* __restrict__ rec,
                                     int e0, int end,
                                     float& ax, float& ay, float& az, float& aw) {
    unsigned long long r[NE];
#pragma unroll
    for (int j = 0; j < NE; ++j)
        r[j] = (!PRED || (e0 + 4 * j < end)) ? rec[e0 + 4 * j] : 0ull;
    float4 v[NE];
#pragma unroll
    for (int j = 0; j < NE; ++j)
        v[j] = *reinterpret_cast<const float4*>(sq + (size_t)(unsigned)(r[j] & 0xffffffffu) * D);
#pragma unroll
    for (int j = 0; j < NE; ++j) {
        float w = __uint_as_float((unsigned)(r[j] >> 32));
        ax = fmaf(v[j].x, w, ax); ay = fmaf(v[j].y, w, ay);
        az = fmaf(v[j].z, w, az); aw = fmaf(v[j].w, w, aw);
    }
}

// ---------------------------------------------------------------------------
// CSR aggregation v3: 4 edge-streams x (D/4) col-chunk lanes, float4 gathers.
// Main loop: UNPREDICATED 32-edge blocks (8-deep/stream, 32 edges in flight,
// zero compares); then one unpredicated 16-block; then predicated 16-tail.
// ---------------------------------------------------------------------------
template <int D, int C, int MODE, bool SMAX>
__global__ __launch_bounds__(256) void agg_fused(const float* __restrict__ s,
                                                 const unsigned long long* __restrict__ rec,
                                                 const int2* __restrict__ rp2,
                                                 const float* __restrict__ Wn,
                                                 const float* __restrict__ res,
                                                 float* __restrict__ out0,
                                                 float* __restrict__ out1,
                                                 float* __restrict__ pred, int n) {
    constexpr int CH = D / 4;  // lanes per edge (col-chunks)
    __shared__ float wl[(MODE == 1 || MODE == 3) ? D * C : 1];
    if (MODE == 1 || MODE == 3) {
        for (int i = threadIdx.x; i < D * C; i += 256) wl[i] = Wn[i];
        __syncthreads();
    }
    constexpr int NPB = 256 / D;
    const int node = blockIdx.x * NPB + threadIdx.x / D;
    const int lane = threadIdx.x % D;
    const int q = lane & (CH - 1);  // col-chunk index
    const int st = lane / CH;       // stream 0..3
    float ax = 0.f, ay = 0.f, az = 0.f, aw = 0.f;
    if (node < n) {
        const float* sq = s + 4 * q;
        int2 se = rp2[node];
        int i = se.x;
        const int end = se.y;
        for (; i + 32 <= end; i += 32)
            gath<8, false, D>(sq, rec, i + st, end, ax, ay, az, aw);
        if (i + 16 <= end) {
            gath<4, false, D>(sq, rec, i + st, end, ax, ay, az, aw);
            i += 16;
        }
        if (i < end)
            gath<4, true, D>(sq, rec, i + st, end, ax, ay, az, aw);
    }
    // stream reduction: sum over the 4 streams (bits CH, 2*CH of lane id)
    ax += __shfl_xor(ax, CH, D);  ax += __shfl_xor(ax, 2 * CH, D);
    ay += __shfl_xor(ay, CH, D);  ay += __shfl_xor(ay, 2 * CH, D);
    az += __shfl_xor(az, CH, D);  az += __shfl_xor(az, 2 * CH, D);
    aw += __shfl_xor(aw, CH, D);  aw += __shfl_xor(aw, 2 * CH, D);

    if (MODE == 1) {
        float vx = tanhf(ax), vy = tanhf(ay), vz = tanhf(az), vw = tanhf(aw);
        if (node < n && st == 0) {
            float4 o; o.x = vx; o.y = vy; o.z = vz; o.w = vw;
            *reinterpret_cast<float4*>(out0 + (size_t)node * D + 4 * q) = o;
        }
        if (SMAX) {  // D == 16: softmax over the 16 cols
            float m = fmaxf(fmaxf(vx, vy), fmaxf(vz, vw));
            m = fmaxf(m, __shfl_xor(m, 1, 16));
            m = fmaxf(m, __shfl_xor(m, 2, 16));
            float ex = expf(vx - m), ey = expf(vy - m), ez = expf(vz - m), ew = expf(vw - m);
            float sm = ex + ey + ez + ew;
            sm += __shfl_xor(sm, 1, 16);
            sm += __shfl_xor(sm, 2, 16);
            float inv = 1.f / sm;
            if (node < n && st == 0) {
                float4 o; o.x = ex * inv; o.y = ey * inv; o.z = ez * inv; o.w = ew * inv;
                *reinterpret_cast<float4*>(pred + (size_t)node * 16 + 4 * q) = o;
            }
        }
        // next-layer gemm: out1[node][cc] = sum_k v_k * Wn[k][cc]
        const int cc = lane & (C - 1);
        float g = 0.f;
#pragma unroll
        for (int k = 0; k < D; ++k) {
            float comp = ((k & 3) == 0) ? vx : ((k & 3) == 1) ? vy : ((k & 3) == 2) ? vz : vw;
            float vk = __shfl(comp, k >> 2, D);
            g = fmaf(vk, wl[k * C + cc], g);
        }
        if (node < n && lane < C) out1[(size_t)node * C + cc] = g;
    } else if (MODE == 2) {
        if (node < n && st == 0) {
            float4 rv = *reinterpret_cast<const float4*>(res + (size_t)node * D + 4 * q);
            float4 o;
            o.x = tanhf(ax) + rv.x; o.y = tanhf(ay) + rv.y;
            o.z = tanhf(az) + rv.z; o.w = tanhf(aw) + rv.w;
            *reinterpret_cast<float4*>(out0 + (size_t)node * D + 4 * q) = o;
        }
    } else if (MODE == 3) {  // D=16, C=32: out = tanh(accRow @ Wn) + res
        float g0 = 0.f, g1 = 0.f;
#pragma unroll
        for (int k = 0; k < 16; ++k) {
            float comp = ((k & 3) == 0) ? ax : ((k & 3) == 1) ? ay : ((k & 3) == 2) ? az : aw;
            float vk = __shfl(comp, k >> 2, 16);
            g0 = fmaf(vk, wl[k * 32 + lane], g0);
            g1 = fmaf(vk, wl[k * 32 + lane + 16], g1);
        }
        if (node < n) {
            out0[(size_t)node * 32 + lane] = tanhf(g0) + res[(size_t)node * 32 + lane];
            out0[(size_t)node * 32 + lane + 16] = tanhf(g1) + res[(size_t)node * 32 + lane + 16];
        }
    } else {  // MODE 4
        if (node < n && st == 0) {
            float4 o; o.x = ax; o.y = ay; o.z = az; o.w = aw;
            *reinterpret_cast<float4*>(out0 + (size_t)node * D + 4 * q) = o;
        }
    }
}

// ---------------------------------------------------------------------------
// GEMM6: column-split persistent blocks (unchanged from round 8).
// ---------------------------------------------------------------------------
#define FT_R 32
__global__ __launch_bounds__(256) void gemm_fout(const float* __restrict__ a,
                                                 const float* __restrict__ W,
                                                 float* __restrict__ out, int n,
                                                 int ntiles) {
    __shared__ float wl[NHID * 256];     // 32 KB (one column half)
    __shared__ float aT[NHID][FT_R + 1]; // 4.2 KB
    const int part = blockIdx.x & 1;
    {
        const float4* w4 = reinterpret_cast<const float4*>(W);
        float4* wl4 = reinterpret_cast<float4*>(wl);
#pragma unroll
        for (int i = threadIdx.x; i < NHID * 64; i += 256) {
            int k = i >> 6;
            int j = i & 63;
            wl4[k * 64 + j] = w4[k * 128 + part * 64 + j];
        }
    }
    const int rt = threadIdx.x >> 5;
    const int ct = threadIdx.x & 31;
    const int srr = threadIdx.x >> 3;
    const int sk4 = threadIdx.x & 7;

    for (int tile = blockIdx.x >> 1; tile < ntiles; tile += gridDim.x >> 1) {
        const int r0 = tile * FT_R;
        __syncthreads();
        {
            int r = r0 + srr;
            float4 v;
            if (r < n)
                v = *reinterpret_cast<const float4*>(a + (size_t)r * NHID + sk4 * 4);
            else
                v.x = v.y = v.z = v.w = 0.f;
            aT[sk4 * 4 + 0][srr] = v.x;
            aT[sk4 * 4 + 1][srr] = v.y;
            aT[sk4 * 4 + 2][srr] = v.z;
            aT[sk4 * 4 + 3][srr] = v.w;
        }
        __syncthreads();
#pragma unroll
        for (int cc = 0; cc < 2; ++cc) {
            float acc[4][4] = {{0.f}};
#pragma unroll 8
            for (int k = 0; k < NHID; ++k) {
                float4 av = *reinterpret_cast<const float4*>(&aT[k][rt * 4]);
                float4 wv = *reinterpret_cast<const float4*>(&wl[k * 256 + cc * 128 + ct * 4]);
                acc[0][0] = fmaf(av.x, wv.x, acc[0][0]);
                acc[0][1] = fmaf(av.x, wv.y, acc[0][1]);
                acc[0][2] = fmaf(av.x, wv.z, acc[0][2]);
                acc[0][3] = fmaf(av.x, wv.w, acc[0][3]);
                acc[1][0] = fmaf(av.y, wv.x, acc[1][0]);
                acc[1][1] = fmaf(av.y, wv.y, acc[1][1]);
                acc[1][2] = fmaf(av.y, wv.z, acc[1][2]);
                acc[1][3] = fmaf(av.y, wv.w, acc[1][3]);
                acc[2][0] = fmaf(av.z, wv.x, acc[2][0]);
                acc[2][1] = fmaf(av.z, wv.y, acc[2][1]);
                acc[2][2] = fmaf(av.z, wv.z, acc[2][2]);
                acc[2][3] = fmaf(av.z, wv.w, acc[2][3]);
                acc[3][0] = fmaf(av.w, wv.x, acc[3][0]);
                acc[3][1] = fmaf(av.w, wv.y, acc[3][1]);
                acc[3][2] = fmaf(av.w, wv.z, acc[3][2]);
                acc[3][3] = fmaf(av.w, wv.w, acc[3][3]);
            }
#pragma unroll
            for (int i = 0; i < 4; ++i) {
                int r = r0 + rt * 4 + i;
                if (r < n) {
                    float4 o;
                    o.x = 1.f / (1.f + expf(-acc[i][0]));
                    o.y = 1.f / (1.f + expf(-acc[i][1]));
                    o.z = 1.f / (1.f + expf(-acc[i][2]));
                    o.w = 1.f / (1.f + expf(-acc[i][3]));
                    *reinterpret_cast<float4*>(out + (size_t)r * FIN + part * 256 + cc * 128 + ct * 4) = o;
                }
            }
        }
    }
}

extern "C" void kernel_launch(void* const* d_in, const int* in_sizes, int n_in,
                              void* d_out, int out_size, void* d_ws, size_t ws_size,
                              hipStream_t stream) {
    const float* feat = (const float*)d_in[0];
    const int* esrc = (const int*)d_in[1];
    const int* edst = (const int*)d_in[2];
    const float* ewt = (const float*)d_in[3];
    const float* W1 = (const float*)d_in[4];
    const float* W2 = (const float*)d_in[5];
    const float* W3 = (const float*)d_in[6];
    const float* W4 = (const float*)d_in[7];
    const float* W5 = (const float*)d_in[8];
    const float* W6 = (const float*)d_in[9];
    const int n = in_sizes[0] / FIN;
    const int e = in_sizes[1];
    const int nb = (n + 255) >> 8;  // 196 buckets of 256 nodes

    float* out = (float*)d_out;
    float* recon = out;                   // [n,512]
    float* zout = out + (size_t)n * FIN;  // [n,16]
    float* pred = zout + (size_t)n * 16;  // [n,16]

    // Workspace (~81 MB of ~425 MB available):
    // rec | rec2 | rp2 | bcursor | float buffers
    char* wsb = (char*)d_ws;
    const size_t captot = (size_t)nb * BCAP;
    unsigned long long* rec = (unsigned long long*)wsb;   // captot * 8B
    unsigned long long* rec2 = rec + captot;              // captot * 8B
    int2* rp2 = (int2*)(rec2 + captot);                   // n * 8B
    int* bcursor = (int*)(rp2 + n);                       // nb
    size_t ioff = (size_t)((bcursor + nb) - (int*)wsb);
    ioff = (ioff + 3) & ~(size_t)3;
    float* S_a = (float*)wsb + ioff;    // n*32
    float* S_b = S_a + (size_t)n * 32;  // n*32
    float* X1 = S_b + (size_t)n * 32;   // n*32 (x1)
    float* X2 = X1 + (size_t)n * 32;    // n*16 (x2)
    float* G1 = X2 + (size_t)n * 16;    // n*32 (K-split partial)

    const int geb = (e + 4095) / 4096;
    const int gn32 = (n + 7) / 8;
    const int gn16 = (n + 15) / 16;
    const int ntile1 = (n + BR - 1) / BR;
    const int ntiles6 = (n + FT_R - 1) / FT_R;

    // ---- CSR build (no histogram/scan: fixed-capacity buckets) ----
    binit<<<1, 256, 0, stream>>>(bcursor, nb);
    build_a<<<geb, 256, 0, stream>>>(esrc, edst, ewt, bcursor, rec2, e, nb);
    build_b<<<nb, 256, 0, stream>>>(rec2, bcursor, rp2, rec, n);

    // conv1: s1 = feat@W1 (K-split partials -> S_a, G1; add2 -> S_a)
    gemm_fin<<<2 * ntile1, 256, 0, stream>>>(feat, W1, S_a, G1, n, ntile1);
    add2<<<(n * 32 / 4 + 255) / 256, 256, 0, stream>>>(S_a, G1, n * 32 / 4);
    // x1 = tanh(A s1) -> X1 ; s2 = x1@W2 -> S_b
    agg_fused<32, 16, 1, false><<<gn32, 256, 0, stream>>>(S_a, rec, rp2, W2, nullptr, X1, S_b, nullptr, n);
    // conv2: x2 = tanh(A s2) -> X2 ; s3 = x2@W3 -> S_a
    agg_fused<16, 16, 1, false><<<gn16, 256, 0, stream>>>(S_b, rec, rp2, W3, nullptr, X2, S_a, nullptr, n);
    // conv3: z = tanh(A s3) -> zout ; pred = softmax(z) ; s4 = z@W4 -> S_b
    agg_fused<16, 16, 1, true><<<gn16, 256, 0, stream>>>(S_a, rec, rp2, W4, nullptr, zout, S_b, pred, n);
    // conv4: z2 = tanh(A s4) + x2 -> S_a
    agg_fused<16, 16, 2, false><<<gn16, 256, 0, stream>>>(S_b, rec, rp2, nullptr, X2, S_a, nullptr, nullptr, n);
    // conv5: z1 = tanh((A z2)@W5) + x1 -> S_b
    agg_fused<16, 32, 3, false><<<gn16, 256, 0, stream>>>(S_a, rec, rp2, W5, X1, S_b, nullptr, nullptr, n);
    // conv6: recon = sigmoid((A z1)@W6)
    agg_fused<32, 32, 4, false><<<gn32, 256, 0, stream>>>(S_b, rec, rp2, nullptr, nullptr, S_a, nullptr, nullptr, n);
    gemm_fout<<<1024, 256, 0, stream>>>(S_a, W6, recon, n, ntiles6);
}